// Round 1
// baseline (734.063 us; speedup 1.0000x reference)
//
#include <hip/hip_runtime.h>
#include <hip/hip_bf16.h>
#include <cstddef>

#define N_NODES 50000

// ---------------- CSR build ----------------

__global__ void count_kernel(const int* __restrict__ dst, int* __restrict__ deg, int E) {
    for (int e = blockIdx.x * blockDim.x + threadIdx.x; e < E; e += gridDim.x * blockDim.x)
        atomicAdd(&deg[dst[e]], 1);
}

__global__ void scan_kernel(const int* __restrict__ deg, int* __restrict__ rowptr,
                            float* __restrict__ inv_deg, int n) {
    __shared__ int sums[1024];
    int t = threadIdx.x;
    const int chunk = (n + 1023) / 1024;
    int start = t * chunk;
    int end = start + chunk; if (end > n) end = n;
    int s = 0;
    for (int i = start; i < end && i >= start; ++i) s += deg[i];
    sums[t] = s;
    __syncthreads();
    for (int off = 1; off < 1024; off <<= 1) {
        int v = (t >= off) ? sums[t - off] : 0;
        __syncthreads();
        sums[t] += v;
        __syncthreads();
    }
    int run = (t == 0) ? 0 : sums[t - 1];   // exclusive prefix
    for (int i = start; i < end && i >= start; ++i) {
        rowptr[i] = run;
        run += deg[i];
        int d = deg[i];
        inv_deg[i] = 1.0f / (float)(d > 1 ? d : 1);
    }
    if (t == 1023) rowptr[n] = run;  // t=1023's chunk is past n, run == total
}

__global__ void fill_kernel(const int* __restrict__ src, const int* __restrict__ dst,
                            const int* __restrict__ rowptr, int* __restrict__ cnt,
                            int* __restrict__ csr, int E) {
    for (int e = blockIdx.x * blockDim.x + threadIdx.x; e < E; e += gridDim.x * blockDim.x) {
        int d = dst[e];
        int p = rowptr[d] + atomicAdd(&cnt[d], 1);
        csr[p] = src[e];
    }
}

// ---------------- mean aggregation (gather over CSR), F=256 ----------------
// one wave per node, lane handles 4 contiguous floats
__global__ __launch_bounds__(256) void aggregate_kernel(
    const float* __restrict__ feat, const int* __restrict__ rowptr,
    const int* __restrict__ csr, const float* __restrict__ inv_deg,
    float* __restrict__ out) {
    int node = blockIdx.x * (blockDim.x >> 6) + (threadIdx.x >> 6);
    if (node >= N_NODES) return;
    int lane = threadIdx.x & 63;
    float4 acc = make_float4(0.f, 0.f, 0.f, 0.f);
    int beg = rowptr[node], end = rowptr[node + 1];
    for (int k = beg; k < end; ++k) {
        int j = csr[k];
        const float4 v = *reinterpret_cast<const float4*>(feat + (size_t)j * 256 + lane * 4);
        acc.x += v.x; acc.y += v.y; acc.z += v.z; acc.w += v.w;
    }
    float s = inv_deg[node];
    float4 r = make_float4(acc.x * s, acc.y * s, acc.z * s, acc.w * s);
    *reinterpret_cast<float4*>(out + (size_t)node * 256 + lane * 4) = r;
}

// ---------------- GEMM1: h = elu([agg | x] @ [W1l ; W1r] + b1) ----------------
// M=50000, N=256, combined K=512. Tile 64x64, BK=16, 256 thr, 4x4 per thread.
__global__ __launch_bounds__(256) void gemm1_kernel(
    const float* __restrict__ Aagg, const float* __restrict__ Ax,
    const float* __restrict__ Bl, const float* __restrict__ Br,
    const float* __restrict__ bias, float* __restrict__ H, int M) {
    __shared__ __align__(16) float As[16][68];  // [BK][BM+pad4] -> b128-aligned rows
    __shared__ __align__(16) float Bs[16][64];
    int tid = threadIdx.x;
    int bm = blockIdx.x, bn = blockIdx.y;
    int tx = tid & 15, ty = tid >> 4;
    int row0 = bm * 64;
    float acc[4][4] = {};
    int arow = tid >> 2;          // 0..63
    int acol = (tid & 3) * 4;     // 0,4,8,12
    int brow = tid >> 4;          // 0..15
    int bcol = (tid & 15) * 4;    // 0..60

    for (int k0 = 0; k0 < 512; k0 += 16) {
        const float* A = (k0 < 256) ? Aagg : Ax;
        const float* B = (k0 < 256) ? Bl : Br;
        int kl = k0 & 255;
        int gr = row0 + arow;
        float4 av = make_float4(0.f, 0.f, 0.f, 0.f);
        if (gr < M) av = *reinterpret_cast<const float4*>(A + (size_t)gr * 256 + kl + acol);
        As[acol + 0][arow] = av.x;
        As[acol + 1][arow] = av.y;
        As[acol + 2][arow] = av.z;
        As[acol + 3][arow] = av.w;
        float4 bv = *reinterpret_cast<const float4*>(B + (size_t)(kl + brow) * 256 + bn * 64 + bcol);
        *reinterpret_cast<float4*>(&Bs[brow][bcol]) = bv;
        __syncthreads();
        #pragma unroll
        for (int kk = 0; kk < 16; ++kk) {
            float a[4], b[4];
            #pragma unroll
            for (int i = 0; i < 4; ++i) a[i] = As[kk][ty * 4 + i];
            #pragma unroll
            for (int j = 0; j < 4; ++j) b[j] = Bs[kk][tx * 4 + j];
            #pragma unroll
            for (int i = 0; i < 4; ++i)
                #pragma unroll
                for (int j = 0; j < 4; ++j)
                    acc[i][j] += a[i] * b[j];
        }
        __syncthreads();
    }
    #pragma unroll
    for (int i = 0; i < 4; ++i) {
        int r = row0 + ty * 4 + i;
        if (r >= M) continue;
        float4 v;
        float* vp = &v.x;
        #pragma unroll
        for (int j = 0; j < 4; ++j) {
            int c = bn * 64 + tx * 4 + j;
            float t = acc[i][j] + bias[c];
            vp[j] = (t > 0.f) ? t : expm1f(t);
        }
        *reinterpret_cast<float4*>(H + (size_t)r * 256 + bn * 64 + tx * 4) = v;
    }
}

// ---------------- GEMM2: out = [agg2 | h] @ [W2l ; W2r] + b2 ----------------
// M=50000, N=40, combined K=512. Block: 64 rows, 256 thr (4 col-groups of 10).
__global__ __launch_bounds__(256) void gemm2_kernel(
    const float* __restrict__ Aagg, const float* __restrict__ Ah,
    const float* __restrict__ Wl, const float* __restrict__ Wr,
    const float* __restrict__ bias, float* __restrict__ out, int M) {
    __shared__ float As[64][33];
    __shared__ float Ws[32][40];
    int tid = threadIdx.x;
    int r = tid & 63, g = tid >> 6;      // g = col group (wave-uniform)
    int row0 = blockIdx.x * 64;
    float acc[10] = {};
    int lrow = tid >> 2;                 // 0..63 for A-tile load
    int lq = (tid & 3) * 8;              // 0,8,16,24

    for (int k0 = 0; k0 < 512; k0 += 32) {
        const float* A = (k0 < 256) ? Aagg : Ah;
        const float* W = (k0 < 256) ? Wl : Wr;
        int kl = k0 & 255;
        // A tile 64x32
        int gr = row0 + lrow;
        float4 a0 = make_float4(0.f,0.f,0.f,0.f), a1 = make_float4(0.f,0.f,0.f,0.f);
        if (gr < M) {
            a0 = *reinterpret_cast<const float4*>(A + (size_t)gr * 256 + kl + lq);
            a1 = *reinterpret_cast<const float4*>(A + (size_t)gr * 256 + kl + lq + 4);
        }
        As[lrow][lq + 0] = a0.x; As[lrow][lq + 1] = a0.y;
        As[lrow][lq + 2] = a0.z; As[lrow][lq + 3] = a0.w;
        As[lrow][lq + 4] = a1.x; As[lrow][lq + 5] = a1.y;
        As[lrow][lq + 6] = a1.z; As[lrow][lq + 7] = a1.w;
        // W tile 32x40 = 1280 floats, 5 per thread, coalesced
        #pragma unroll
        for (int m = 0; m < 5; ++m) {
            int idx = tid * 5 + m;
            Ws[idx / 40][idx % 40] = W[(size_t)(kl + idx / 40) * 40 + (idx % 40)];
        }
        __syncthreads();
        #pragma unroll
        for (int kk = 0; kk < 32; ++kk) {
            float a = As[r][kk];
            const float* wrow = &Ws[kk][g * 10];
            #pragma unroll
            for (int n = 0; n < 10; ++n) acc[n] += a * wrow[n];
        }
        __syncthreads();
    }
    int gr = row0 + r;
    if (gr < M) {
        #pragma unroll
        for (int n = 0; n < 10; ++n)
            out[(size_t)gr * 40 + g * 10 + n] = acc[n] + bias[g * 10 + n];
    }
}

// ---------------- launcher ----------------

extern "C" void kernel_launch(void* const* d_in, const int* in_sizes, int n_in,
                              void* d_out, int out_size, void* d_ws, size_t ws_size,
                              hipStream_t stream) {
    const float* x   = (const float*)d_in[0];
    const int*   ei  = (const int*)d_in[1];
    const float* W1l = (const float*)d_in[2];
    const float* b1  = (const float*)d_in[3];
    const float* W1r = (const float*)d_in[4];
    const float* W2l = (const float*)d_in[5];
    const float* b2  = (const float*)d_in[6];
    const float* W2r = (const float*)d_in[7];
    const float* Q   = (const float*)d_in[8];
    const int E = in_sizes[1] / 2;       // 800000
    const int N = N_NODES;
    const int* src = ei;
    const int* dst = ei + E;

    float* agg     = (float*)d_ws;                       // N*256
    float* h       = agg + (size_t)N * 256;              // N*256
    float* inv_deg = h + (size_t)N * 256;                // N
    int*   deg     = (int*)(inv_deg + N);                // N
    int*   cnt     = deg + N;                            // N
    int*   rowptr  = cnt + N;                            // N+1
    int*   csr     = rowptr + N + 1;                     // E

    float* out = (float*)d_out;

    // zero deg + cnt (contiguous)
    hipMemsetAsync(deg, 0, sizeof(int) * 2 * (size_t)N, stream);
    count_kernel<<<1024, 256, 0, stream>>>(dst, deg, E);
    scan_kernel<<<1, 1024, 0, stream>>>(deg, rowptr, inv_deg, N);
    fill_kernel<<<1024, 256, 0, stream>>>(src, dst, rowptr, cnt, csr, E);

    // layer 1
    aggregate_kernel<<<(N + 3) / 4, 256, 0, stream>>>(x, rowptr, csr, inv_deg, agg);
    gemm1_kernel<<<dim3((N + 63) / 64, 4), 256, 0, stream>>>(agg, x, W1l, W1r, b1, h, N);

    // layer 2
    aggregate_kernel<<<(N + 3) / 4, 256, 0, stream>>>(h, rowptr, csr, inv_deg, agg);
    gemm2_kernel<<<(N + 63) / 64, 256, 0, stream>>>(agg, h, W2l, W2r, b2, out, N);

    // Q pass-through
    hipMemcpyAsync(out + (size_t)N * 40, Q, sizeof(float) * (size_t)in_sizes[8],
                   hipMemcpyDeviceToDevice, stream);
}

// Round 2
// 465.445 us; speedup vs baseline: 1.5771x; 1.5771x over previous
//
#include <hip/hip_runtime.h>
#include <hip/hip_bf16.h>
#include <cstddef>

#define N_NODES 50000

typedef __attribute__((ext_vector_type(8))) short short8;
typedef __attribute__((ext_vector_type(4))) float floatx4;

__device__ inline unsigned short f2bf(float f) {
    union { float f; unsigned u; } v; v.f = f;
    unsigned r = v.u + 0x7fff + ((v.u >> 16) & 1);
    return (unsigned short)(r >> 16);
}
__device__ inline float bfbits_lo(unsigned u) {  // low 16 bits as bf16 -> f32
    union { unsigned u; float f; } v; v.u = u << 16; return v.f;
}
__device__ inline float bfbits_hi(unsigned u) {  // high 16 bits
    union { unsigned u; float f; } v; v.u = u & 0xffff0000u; return v.f;
}

// ---------------- CSR build ----------------

__global__ void count_kernel(const int* __restrict__ dst, int* __restrict__ deg, int E) {
    for (int e = blockIdx.x * blockDim.x + threadIdx.x; e < E; e += gridDim.x * blockDim.x)
        atomicAdd(&deg[dst[e]], 1);
}

__global__ void scan_kernel(const int* __restrict__ deg, int* __restrict__ rowptr,
                            float* __restrict__ inv_deg, int n) {
    __shared__ int sums[1024];
    int t = threadIdx.x;
    const int chunk = (n + 1023) / 1024;
    int start = t * chunk;
    int end = start + chunk; if (end > n) end = n;
    int s = 0;
    for (int i = start; i < end && i >= start; ++i) s += deg[i];
    sums[t] = s;
    __syncthreads();
    for (int off = 1; off < 1024; off <<= 1) {
        int v = (t >= off) ? sums[t - off] : 0;
        __syncthreads();
        sums[t] += v;
        __syncthreads();
    }
    int run = (t == 0) ? 0 : sums[t - 1];
    for (int i = start; i < end && i >= start; ++i) {
        rowptr[i] = run;
        run += deg[i];
        int d = deg[i];
        inv_deg[i] = 1.0f / (float)(d > 1 ? d : 1);
    }
    if (t == 1023) rowptr[n] = run;
}

__global__ void fill_kernel(const int* __restrict__ src, const int* __restrict__ dst,
                            const int* __restrict__ rowptr, int* __restrict__ cnt,
                            int* __restrict__ csr, int E) {
    for (int e = blockIdx.x * blockDim.x + threadIdx.x; e < E; e += gridDim.x * blockDim.x) {
        int d = dst[e];
        int p = rowptr[d] + atomicAdd(&cnt[d], 1);
        csr[p] = src[e];
    }
}

// ---------------- x -> bf16 into Abuf cols 256..511 ----------------
__global__ __launch_bounds__(256) void convert_x(const float* __restrict__ x,
                                                 unsigned short* __restrict__ Abuf,
                                                 int total8) {
    for (int i = blockIdx.x * blockDim.x + threadIdx.x; i < total8;
         i += gridDim.x * blockDim.x) {
        int row = i >> 5;          // 32 chunks of 8 per row
        int c8 = i & 31;
        const float4* xp = reinterpret_cast<const float4*>(x + (size_t)row * 256 + c8 * 8);
        float4 v0 = xp[0], v1 = xp[1];
        uint4 o;
        o.x = (unsigned)f2bf(v0.x) | ((unsigned)f2bf(v0.y) << 16);
        o.y = (unsigned)f2bf(v0.z) | ((unsigned)f2bf(v0.w) << 16);
        o.z = (unsigned)f2bf(v1.x) | ((unsigned)f2bf(v1.y) << 16);
        o.w = (unsigned)f2bf(v1.z) | ((unsigned)f2bf(v1.w) << 16);
        *reinterpret_cast<uint4*>(Abuf + (size_t)row * 512 + 256 + c8 * 8) = o;
    }
}

// ---------------- weight prep (transposed, bf16) ----------------
// B1t[n][k] n<256,k<512 : k<256 ? W1l[k][n] : W1r[k-256][n]
__global__ void prep_B1(const float* __restrict__ W1l, const float* __restrict__ W1r,
                        unsigned short* __restrict__ B1t) {
    int idx = blockIdx.x * blockDim.x + threadIdx.x;
    if (idx >= 256 * 512) return;
    int n = idx >> 9, k = idx & 511;
    float v = (k < 256) ? W1l[(size_t)k * 256 + n] : W1r[(size_t)(k - 256) * 256 + n];
    B1t[(size_t)n * 512 + k] = f2bf(v);
}
// B2t[n][k] n<80,k<256 : n<40 ? W2l[k][n] : W2r[k][n-40]
__global__ void prep_B2(const float* __restrict__ W2l, const float* __restrict__ W2r,
                        unsigned short* __restrict__ B2t) {
    int idx = blockIdx.x * blockDim.x + threadIdx.x;
    if (idx >= 80 * 256) return;
    int n = idx >> 8, k = idx & 255;
    float v = (n < 40) ? W2l[(size_t)k * 40 + n] : W2r[(size_t)k * 40 + (n - 40)];
    B2t[(size_t)n * 256 + k] = f2bf(v);
}

// ---------------- mean aggregation over bf16 features (256-d) ----------------
// reads Abuf cols 256..511 (x in bf16), writes Abuf cols 0..255 (agg in bf16)
__global__ __launch_bounds__(256) void aggregate1(
    const unsigned short* __restrict__ Abuf, const int* __restrict__ rowptr,
    const int* __restrict__ csr, const float* __restrict__ inv_deg,
    unsigned short* __restrict__ AbufOut, int N) {
    int node = blockIdx.x * 4 + (threadIdx.x >> 6);
    if (node >= N) return;
    int lane = threadIdx.x & 63;
    float a0 = 0.f, a1 = 0.f, a2 = 0.f, a3 = 0.f;
    int beg = rowptr[node], end = rowptr[node + 1];
    for (int k = beg; k < end; ++k) {
        int j = csr[k];
        uint2 v = *reinterpret_cast<const uint2*>(Abuf + (size_t)j * 512 + 256 + lane * 4);
        a0 += bfbits_lo(v.x); a1 += bfbits_hi(v.x);
        a2 += bfbits_lo(v.y); a3 += bfbits_hi(v.y);
    }
    float s = inv_deg[node];
    uint2 w;
    w.x = (unsigned)f2bf(a0 * s) | ((unsigned)f2bf(a1 * s) << 16);
    w.y = (unsigned)f2bf(a2 * s) | ((unsigned)f2bf(a3 * s) << 16);
    *reinterpret_cast<uint2*>(AbufOut + (size_t)node * 512 + lane * 4) = w;
}

// ---------------- GEMM1 (MFMA): h = elu(Abuf @ B1t^T + b1), bf16 out ----------------
// M=50000, K=512, N=256. Tile 128x128, BK=32, 4 waves, wave does 64x64.
__global__ __launch_bounds__(256) void gemm1_mfma(
    const unsigned short* __restrict__ Abuf,   // [M][512]
    const unsigned short* __restrict__ B1t,    // [256][512]
    const float* __restrict__ bias,            // [256]
    unsigned short* __restrict__ H,            // [M][256] bf16
    int M) {
    __shared__ unsigned short As[128][40];
    __shared__ unsigned short Bs[128][40];
    int tid = threadIdx.x;
    int row0 = blockIdx.x * 128;
    int bn = blockIdx.y;             // 0..1
    int wid = tid >> 6, lane = tid & 63;
    int wm = (wid >> 1) * 64, wn = (wid & 1) * 64;
    int fr = lane & 15, fq = lane >> 4;

    floatx4 acc[4][4] = {};

    int c0 = tid, c1 = tid + 256;
    int r0 = c0 >> 2, ko0 = (c0 & 3) * 8;
    int r1 = c1 >> 2, ko1 = (c1 & 3) * 8;

    for (int k0 = 0; k0 < 512; k0 += 32) {
        short8 av0 = {}, av1 = {};
        if (row0 + r0 < M)
            av0 = *reinterpret_cast<const short8*>(Abuf + (size_t)(row0 + r0) * 512 + k0 + ko0);
        if (row0 + r1 < M)
            av1 = *reinterpret_cast<const short8*>(Abuf + (size_t)(row0 + r1) * 512 + k0 + ko1);
        short8 bv0 = *reinterpret_cast<const short8*>(B1t + (size_t)(bn * 128 + r0) * 512 + k0 + ko0);
        short8 bv1 = *reinterpret_cast<const short8*>(B1t + (size_t)(bn * 128 + r1) * 512 + k0 + ko1);
        __syncthreads();
        *reinterpret_cast<short8*>(&As[r0][ko0]) = av0;
        *reinterpret_cast<short8*>(&As[r1][ko1]) = av1;
        *reinterpret_cast<short8*>(&Bs[r0][ko0]) = bv0;
        *reinterpret_cast<short8*>(&Bs[r1][ko1]) = bv1;
        __syncthreads();
        short8 af[4], bf[4];
        #pragma unroll
        for (int mi = 0; mi < 4; ++mi)
            af[mi] = *reinterpret_cast<const short8*>(&As[wm + mi * 16 + fr][fq * 8]);
        #pragma unroll
        for (int ni = 0; ni < 4; ++ni)
            bf[ni] = *reinterpret_cast<const short8*>(&Bs[wn + ni * 16 + fr][fq * 8]);
        #pragma unroll
        for (int mi = 0; mi < 4; ++mi)
            #pragma unroll
            for (int ni = 0; ni < 4; ++ni)
                acc[mi][ni] = __builtin_amdgcn_mfma_f32_16x16x32_bf16(af[mi], bf[ni], acc[mi][ni], 0, 0, 0);
    }
    #pragma unroll
    for (int ni = 0; ni < 4; ++ni) {
        int gcol = bn * 128 + wn + ni * 16 + fr;
        float bb = bias[gcol];
        #pragma unroll
        for (int mi = 0; mi < 4; ++mi) {
            #pragma unroll
            for (int r = 0; r < 4; ++r) {
                int grow = row0 + wm + mi * 16 + fq * 4 + r;
                if (grow < M) {
                    float t = acc[mi][ni][r] + bb;
                    t = (t > 0.f) ? t : expm1f(t);
                    H[(size_t)grow * 256 + gcol] = f2bf(t);
                }
            }
        }
    }
}

// ---------------- GEMM2 (MFMA): P = H @ B2t^T, fp32 out ----------------
// M=50000, K=256, N=80. Tile 128x80, BK=32, 4 waves, wave does 32x80.
__global__ __launch_bounds__(256) void gemm2_mfma(
    const unsigned short* __restrict__ Hb,   // [M][256]
    const unsigned short* __restrict__ B2t,  // [80][256]
    float* __restrict__ P,                   // [M][80]
    int M) {
    __shared__ unsigned short As[128][40];
    __shared__ unsigned short Bs[80][40];
    int tid = threadIdx.x;
    int row0 = blockIdx.x * 128;
    int wid = tid >> 6, lane = tid & 63;
    int wm = wid * 32;
    int fr = lane & 15, fq = lane >> 4;

    floatx4 acc[2][5] = {};

    int ar0 = tid >> 1;                 // 0..127 rows, 2 chunks of 8 each... no:
    // A tile: 128 rows x 32 k = 512 chunks of 8; thread handles chunks tid, tid+256
    int c0 = tid, c1 = tid + 256;
    int r0 = c0 >> 2, ko0 = (c0 & 3) * 8;
    int r1 = c1 >> 2, ko1 = (c1 & 3) * 8;
    // B tile: 80 rows x 32 k = 320 chunks; thread handles tid (<320 always for tid<256), tid+256 if tid<64
    int br0 = tid >> 2, bko0 = (tid & 3) * 8;
    int br1 = (tid + 256) >> 2, bko1 = ((tid + 256) & 3) * 8;

    (void)ar0;
    for (int k0 = 0; k0 < 256; k0 += 32) {
        short8 av0 = {}, av1 = {};
        if (row0 + r0 < M)
            av0 = *reinterpret_cast<const short8*>(Hb + (size_t)(row0 + r0) * 256 + k0 + ko0);
        if (row0 + r1 < M)
            av1 = *reinterpret_cast<const short8*>(Hb + (size_t)(row0 + r1) * 256 + k0 + ko1);
        short8 bv0 = {}, bv1 = {};
        if (br0 < 80)
            bv0 = *reinterpret_cast<const short8*>(B2t + (size_t)br0 * 256 + k0 + bko0);
        if (tid < 64)
            bv1 = *reinterpret_cast<const short8*>(B2t + (size_t)br1 * 256 + k0 + bko1);
        __syncthreads();
        *reinterpret_cast<short8*>(&As[r0][ko0]) = av0;
        *reinterpret_cast<short8*>(&As[r1][ko1]) = av1;
        if (br0 < 80) *reinterpret_cast<short8*>(&Bs[br0][bko0]) = bv0;
        if (tid < 64) *reinterpret_cast<short8*>(&Bs[br1][bko1]) = bv1;
        __syncthreads();
        short8 af[2], bf[5];
        #pragma unroll
        for (int mi = 0; mi < 2; ++mi)
            af[mi] = *reinterpret_cast<const short8*>(&As[wm + mi * 16 + fr][fq * 8]);
        #pragma unroll
        for (int ni = 0; ni < 5; ++ni)
            bf[ni] = *reinterpret_cast<const short8*>(&Bs[ni * 16 + fr][fq * 8]);
        #pragma unroll
        for (int mi = 0; mi < 2; ++mi)
            #pragma unroll
            for (int ni = 0; ni < 5; ++ni)
                acc[mi][ni] = __builtin_amdgcn_mfma_f32_16x16x32_bf16(af[mi], bf[ni], acc[mi][ni], 0, 0, 0);
    }
    #pragma unroll
    for (int mi = 0; mi < 2; ++mi) {
        #pragma unroll
        for (int r = 0; r < 4; ++r) {
            int grow = row0 + wm + mi * 16 + fq * 4 + r;
            if (grow < M) {
                #pragma unroll
                for (int ni = 0; ni < 5; ++ni)
                    P[(size_t)grow * 80 + ni * 16 + fr] = acc[mi][ni][r];
            }
        }
    }
}

// ---------------- final: out = mean_agg(P[:,0:40]) + P[:,40:80] + b2 ----------------
__global__ __launch_bounds__(256) void final_kernel(
    const float* __restrict__ P, const int* __restrict__ rowptr,
    const int* __restrict__ csr, const float* __restrict__ inv_deg,
    const float* __restrict__ b2, float* __restrict__ out, int N) {
    int node = blockIdx.x * 4 + (threadIdx.x >> 6);
    if (node >= N) return;
    int lane = threadIdx.x & 63;
    if (lane >= 40) return;
    float sum = 0.f;
    int beg = rowptr[node], end = rowptr[node + 1];
    for (int k = beg; k < end; ++k) {
        int j = csr[k];
        sum += P[(size_t)j * 80 + lane];
    }
    out[(size_t)node * 40 + lane] =
        sum * inv_deg[node] + P[(size_t)node * 80 + 40 + lane] + b2[lane];
}

// ---------------- launcher ----------------

extern "C" void kernel_launch(void* const* d_in, const int* in_sizes, int n_in,
                              void* d_out, int out_size, void* d_ws, size_t ws_size,
                              hipStream_t stream) {
    const float* x   = (const float*)d_in[0];
    const int*   ei  = (const int*)d_in[1];
    const float* W1l = (const float*)d_in[2];
    const float* b1  = (const float*)d_in[3];
    const float* W1r = (const float*)d_in[4];
    const float* W2l = (const float*)d_in[5];
    const float* b2  = (const float*)d_in[6];
    const float* W2r = (const float*)d_in[7];
    const float* Q   = (const float*)d_in[8];
    const int E = in_sizes[1] / 2;
    const int N = N_NODES;
    const int* src = ei;
    const int* dst = ei + E;

    unsigned short* Abuf = (unsigned short*)d_ws;            // [N][512] bf16
    unsigned short* h    = Abuf + (size_t)N * 512;           // [N][256] bf16
    unsigned short* B1t  = h + (size_t)N * 256;              // [256][512]
    unsigned short* B2t  = B1t + 256 * 512;                  // [80][256]
    float* P       = (float*)(B2t + 80 * 256);               // [N][80]
    float* inv_deg = P + (size_t)N * 80;                     // N
    int*   deg     = (int*)(inv_deg + N);                    // N
    int*   cnt     = deg + N;                                // N
    int*   rowptr  = cnt + N;                                // N+1
    int*   csr     = rowptr + N + 1;                         // E

    float* out = (float*)d_out;

    hipMemsetAsync(deg, 0, sizeof(int) * 2 * (size_t)N, stream);
    count_kernel<<<1024, 256, 0, stream>>>(dst, deg, E);
    scan_kernel<<<1, 1024, 0, stream>>>(deg, rowptr, inv_deg, N);
    fill_kernel<<<1024, 256, 0, stream>>>(src, dst, rowptr, cnt, csr, E);

    convert_x<<<2048, 256, 0, stream>>>(x, Abuf, N * 32);
    prep_B1<<<(256 * 512 + 255) / 256, 256, 0, stream>>>(W1l, W1r, B1t);
    prep_B2<<<(80 * 256 + 255) / 256, 256, 0, stream>>>(W2l, W2r, B2t);

    aggregate1<<<(N + 3) / 4, 256, 0, stream>>>(Abuf, rowptr, csr, inv_deg, Abuf, N);
    gemm1_mfma<<<dim3((N + 127) / 128, 2), 256, 0, stream>>>(Abuf, B1t, b1, h, N);
    gemm2_mfma<<<(N + 127) / 128, 256, 0, stream>>>(h, B2t, P, N);
    final_kernel<<<(N + 3) / 4, 256, 0, stream>>>(P, rowptr, csr, inv_deg, b2, out, N);

    hipMemcpyAsync(out + (size_t)N * 40, Q, sizeof(float) * (size_t)in_sizes[8],
                   hipMemcpyDeviceToDevice, stream);
}

// Round 3
// 369.397 us; speedup vs baseline: 1.9872x; 1.2600x over previous
//
#include <hip/hip_runtime.h>
#include <hip/hip_bf16.h>
#include <cstddef>

#define N_NODES 50000

typedef __attribute__((ext_vector_type(8))) short short8;
typedef __attribute__((ext_vector_type(4))) float floatx4;

__device__ inline unsigned short f2bf(float f) {
    union { float f; unsigned u; } v; v.f = f;
    unsigned r = v.u + 0x7fff + ((v.u >> 16) & 1);
    return (unsigned short)(r >> 16);
}
__device__ inline float bfbits_lo(unsigned u) {
    union { unsigned u; float f; } v; v.u = u << 16; return v.f;
}
__device__ inline float bfbits_hi(unsigned u) {
    union { unsigned u; float f; } v; v.u = u & 0xffff0000u; return v.f;
}

// ---------------- CSR build ----------------

__global__ void count_kernel(const int* __restrict__ dst, int* __restrict__ deg, int E) {
    for (int e = blockIdx.x * blockDim.x + threadIdx.x; e < E; e += gridDim.x * blockDim.x)
        atomicAdd(&deg[dst[e]], 1);
}

// hierarchical scan: scan1 (block sums) -> scan2 (scan sums) -> scan3 (rowptr)
__global__ __launch_bounds__(256) void scan1_kernel(const int* __restrict__ deg,
                                                    int* __restrict__ blocksums, int n) {
    __shared__ int s[256];
    int t = threadIdx.x;
    int i = blockIdx.x * 256 + t;
    s[t] = (i < n) ? deg[i] : 0;
    __syncthreads();
    for (int off = 128; off > 0; off >>= 1) {
        if (t < off) s[t] += s[t + off];
        __syncthreads();
    }
    if (t == 0) blocksums[blockIdx.x] = s[0];
}

__global__ __launch_bounds__(256) void scan2_kernel(const int* __restrict__ blocksums,
                                                    int* __restrict__ blockoff, int nb) {
    __shared__ int s[256];
    int t = threadIdx.x;
    s[t] = (t < nb) ? blocksums[t] : 0;
    __syncthreads();
    for (int off = 1; off < 256; off <<= 1) {
        int u = (t >= off) ? s[t - off] : 0;
        __syncthreads();
        s[t] += u;
        __syncthreads();
    }
    if (t < nb) blockoff[t] = (t == 0) ? 0 : s[t - 1];
}

__global__ __launch_bounds__(256) void scan3_kernel(const int* __restrict__ deg,
                                                    const int* __restrict__ blockoff,
                                                    int* __restrict__ rowptr,
                                                    float* __restrict__ inv_deg,
                                                    int n, int E) {
    __shared__ int s[256];
    int t = threadIdx.x;
    int i = blockIdx.x * 256 + t;
    int v = (i < n) ? deg[i] : 0;
    s[t] = v;
    __syncthreads();
    for (int off = 1; off < 256; off <<= 1) {
        int u = (t >= off) ? s[t - off] : 0;
        __syncthreads();
        s[t] += u;
        __syncthreads();
    }
    if (i < n) {
        rowptr[i] = s[t] - v + blockoff[blockIdx.x];   // exclusive prefix
        inv_deg[i] = 1.0f / (float)(v > 1 ? v : 1);
    }
    if (blockIdx.x == 0 && t == 0) rowptr[n] = E;
}

__global__ void fill_kernel(const int* __restrict__ src, const int* __restrict__ dst,
                            const int* __restrict__ rowptr, int* __restrict__ cnt,
                            int* __restrict__ csr, int E) {
    for (int e = blockIdx.x * blockDim.x + threadIdx.x; e < E; e += gridDim.x * blockDim.x) {
        int d = dst[e];
        int p = rowptr[d] + atomicAdd(&cnt[d], 1);
        csr[p] = src[e];
    }
}

// ---------------- x -> bf16 into Abuf cols 256..511 ----------------
__global__ __launch_bounds__(256) void convert_x(const float* __restrict__ x,
                                                 unsigned short* __restrict__ Abuf,
                                                 int total8) {
    for (int i = blockIdx.x * blockDim.x + threadIdx.x; i < total8;
         i += gridDim.x * blockDim.x) {
        int row = i >> 5;
        int c8 = i & 31;
        const float4* xp = reinterpret_cast<const float4*>(x + (size_t)row * 256 + c8 * 8);
        float4 v0 = xp[0], v1 = xp[1];
        uint4 o;
        o.x = (unsigned)f2bf(v0.x) | ((unsigned)f2bf(v0.y) << 16);
        o.y = (unsigned)f2bf(v0.z) | ((unsigned)f2bf(v0.w) << 16);
        o.z = (unsigned)f2bf(v1.x) | ((unsigned)f2bf(v1.y) << 16);
        o.w = (unsigned)f2bf(v1.z) | ((unsigned)f2bf(v1.w) << 16);
        *reinterpret_cast<uint4*>(Abuf + (size_t)row * 512 + 256 + c8 * 8) = o;
    }
}

// ---------------- weight prep (transposed, bf16) ----------------
__global__ void prep_B1(const float* __restrict__ W1l, const float* __restrict__ W1r,
                        unsigned short* __restrict__ B1t) {
    int idx = blockIdx.x * blockDim.x + threadIdx.x;
    if (idx >= 256 * 512) return;
    int n = idx >> 9, k = idx & 511;
    float v = (k < 256) ? W1l[(size_t)k * 256 + n] : W1r[(size_t)(k - 256) * 256 + n];
    B1t[(size_t)n * 512 + k] = f2bf(v);
}
__global__ void prep_B2(const float* __restrict__ W2l, const float* __restrict__ W2r,
                        unsigned short* __restrict__ B2t) {
    int idx = blockIdx.x * blockDim.x + threadIdx.x;
    if (idx >= 80 * 256) return;
    int n = idx >> 8, k = idx & 255;
    float v = (n < 40) ? W2l[(size_t)k * 40 + n] : W2r[(size_t)k * 40 + (n - 40)];
    B2t[(size_t)n * 256 + k] = f2bf(v);
}

// ---------------- mean aggregation over bf16 features (256-d) ----------------
__global__ __launch_bounds__(256) void aggregate1(
    const unsigned short* __restrict__ Abuf, const int* __restrict__ rowptr,
    const int* __restrict__ csr, const float* __restrict__ inv_deg,
    unsigned short* __restrict__ AbufOut, int N) {
    int node = blockIdx.x * 4 + (threadIdx.x >> 6);
    if (node >= N) return;
    int lane = threadIdx.x & 63;
    float a0 = 0.f, a1 = 0.f, a2 = 0.f, a3 = 0.f;
    int beg = rowptr[node], end = rowptr[node + 1];
    for (int k = beg; k < end; ++k) {
        int j = csr[k];
        uint2 v = *reinterpret_cast<const uint2*>(Abuf + (size_t)j * 512 + 256 + lane * 4);
        a0 += bfbits_lo(v.x); a1 += bfbits_hi(v.x);
        a2 += bfbits_lo(v.y); a3 += bfbits_hi(v.y);
    }
    float s = inv_deg[node];
    uint2 w;
    w.x = (unsigned)f2bf(a0 * s) | ((unsigned)f2bf(a1 * s) << 16);
    w.y = (unsigned)f2bf(a2 * s) | ((unsigned)f2bf(a3 * s) << 16);
    *reinterpret_cast<uint2*>(AbufOut + (size_t)node * 512 + lane * 4) = w;
}

// ---------------- GEMM1 (MFMA): h = elu(Abuf @ B1t^T + b1), bf16 out ----------------
__global__ __launch_bounds__(256) void gemm1_mfma(
    const unsigned short* __restrict__ Abuf,
    const unsigned short* __restrict__ B1t,
    const float* __restrict__ bias,
    unsigned short* __restrict__ H,
    int M) {
    __shared__ unsigned short As[128][40];
    __shared__ unsigned short Bs[128][40];
    int tid = threadIdx.x;
    int row0 = blockIdx.x * 128;
    int bn = blockIdx.y;
    int wid = tid >> 6, lane = tid & 63;
    int wm = (wid >> 1) * 64, wn = (wid & 1) * 64;
    int fr = lane & 15, fq = lane >> 4;

    floatx4 acc[4][4] = {};

    int c0 = tid, c1 = tid + 256;
    int r0 = c0 >> 2, ko0 = (c0 & 3) * 8;
    int r1 = c1 >> 2, ko1 = (c1 & 3) * 8;

    for (int k0 = 0; k0 < 512; k0 += 32) {
        short8 av0 = {}, av1 = {};
        if (row0 + r0 < M)
            av0 = *reinterpret_cast<const short8*>(Abuf + (size_t)(row0 + r0) * 512 + k0 + ko0);
        if (row0 + r1 < M)
            av1 = *reinterpret_cast<const short8*>(Abuf + (size_t)(row0 + r1) * 512 + k0 + ko1);
        short8 bv0 = *reinterpret_cast<const short8*>(B1t + (size_t)(bn * 128 + r0) * 512 + k0 + ko0);
        short8 bv1 = *reinterpret_cast<const short8*>(B1t + (size_t)(bn * 128 + r1) * 512 + k0 + ko1);
        __syncthreads();
        *reinterpret_cast<short8*>(&As[r0][ko0]) = av0;
        *reinterpret_cast<short8*>(&As[r1][ko1]) = av1;
        *reinterpret_cast<short8*>(&Bs[r0][ko0]) = bv0;
        *reinterpret_cast<short8*>(&Bs[r1][ko1]) = bv1;
        __syncthreads();
        short8 af[4], bf[4];
        #pragma unroll
        for (int mi = 0; mi < 4; ++mi)
            af[mi] = *reinterpret_cast<const short8*>(&As[wm + mi * 16 + fr][fq * 8]);
        #pragma unroll
        for (int ni = 0; ni < 4; ++ni)
            bf[ni] = *reinterpret_cast<const short8*>(&Bs[wn + ni * 16 + fr][fq * 8]);
        #pragma unroll
        for (int mi = 0; mi < 4; ++mi)
            #pragma unroll
            for (int ni = 0; ni < 4; ++ni)
                acc[mi][ni] = __builtin_amdgcn_mfma_f32_16x16x32_bf16(af[mi], bf[ni], acc[mi][ni], 0, 0, 0);
    }
    #pragma unroll
    for (int ni = 0; ni < 4; ++ni) {
        int gcol = bn * 128 + wn + ni * 16 + fr;
        float bb = bias[gcol];
        #pragma unroll
        for (int mi = 0; mi < 4; ++mi) {
            #pragma unroll
            for (int r = 0; r < 4; ++r) {
                int grow = row0 + wm + mi * 16 + fq * 4 + r;
                if (grow < M) {
                    float t = acc[mi][ni][r] + bb;
                    t = (t > 0.f) ? t : expm1f(t);
                    H[(size_t)grow * 256 + gcol] = f2bf(t);
                }
            }
        }
    }
}

// ---------------- GEMM2 (MFMA): P = H @ B2t^T, fp32 out ----------------
__global__ __launch_bounds__(256) void gemm2_mfma(
    const unsigned short* __restrict__ Hb,
    const unsigned short* __restrict__ B2t,
    float* __restrict__ P,
    int M) {
    __shared__ unsigned short As[128][40];
    __shared__ unsigned short Bs[80][40];
    int tid = threadIdx.x;
    int row0 = blockIdx.x * 128;
    int wid = tid >> 6, lane = tid & 63;
    int wm = wid * 32;
    int fr = lane & 15, fq = lane >> 4;

    floatx4 acc[2][5] = {};

    int c0 = tid, c1 = tid + 256;
    int r0 = c0 >> 2, ko0 = (c0 & 3) * 8;
    int r1 = c1 >> 2, ko1 = (c1 & 3) * 8;
    int br0 = tid >> 2, bko0 = (tid & 3) * 8;
    int br1 = (tid + 256) >> 2, bko1 = ((tid + 256) & 3) * 8;

    for (int k0 = 0; k0 < 256; k0 += 32) {
        short8 av0 = {}, av1 = {};
        if (row0 + r0 < M)
            av0 = *reinterpret_cast<const short8*>(Hb + (size_t)(row0 + r0) * 256 + k0 + ko0);
        if (row0 + r1 < M)
            av1 = *reinterpret_cast<const short8*>(Hb + (size_t)(row0 + r1) * 256 + k0 + ko1);
        short8 bv0 = {}, bv1 = {};
        if (br0 < 80)
            bv0 = *reinterpret_cast<const short8*>(B2t + (size_t)br0 * 256 + k0 + bko0);
        if (tid < 64)
            bv1 = *reinterpret_cast<const short8*>(B2t + (size_t)br1 * 256 + k0 + bko1);
        __syncthreads();
        *reinterpret_cast<short8*>(&As[r0][ko0]) = av0;
        *reinterpret_cast<short8*>(&As[r1][ko1]) = av1;
        if (br0 < 80) *reinterpret_cast<short8*>(&Bs[br0][bko0]) = bv0;
        if (tid < 64) *reinterpret_cast<short8*>(&Bs[br1][bko1]) = bv1;
        __syncthreads();
        short8 af[2], bf[5];
        #pragma unroll
        for (int mi = 0; mi < 2; ++mi)
            af[mi] = *reinterpret_cast<const short8*>(&As[wm + mi * 16 + fr][fq * 8]);
        #pragma unroll
        for (int ni = 0; ni < 5; ++ni)
            bf[ni] = *reinterpret_cast<const short8*>(&Bs[ni * 16 + fr][fq * 8]);
        #pragma unroll
        for (int mi = 0; mi < 2; ++mi)
            #pragma unroll
            for (int ni = 0; ni < 5; ++ni)
                acc[mi][ni] = __builtin_amdgcn_mfma_f32_16x16x32_bf16(af[mi], bf[ni], acc[mi][ni], 0, 0, 0);
    }
    #pragma unroll
    for (int mi = 0; mi < 2; ++mi) {
        #pragma unroll
        for (int r = 0; r < 4; ++r) {
            int grow = row0 + wm + mi * 16 + fq * 4 + r;
            if (grow < M) {
                #pragma unroll
                for (int ni = 0; ni < 5; ++ni)
                    P[(size_t)grow * 80 + ni * 16 + fr] = acc[mi][ni][r];
            }
        }
    }
}

// ---------------- final: out = mean_agg(P[:,0:40]) + P[:,40:80] + b2 ----------------
__global__ __launch_bounds__(256) void final_kernel(
    const float* __restrict__ P, const int* __restrict__ rowptr,
    const int* __restrict__ csr, const float* __restrict__ inv_deg,
    const float* __restrict__ b2, float* __restrict__ out, int N) {
    int node = blockIdx.x * 4 + (threadIdx.x >> 6);
    if (node >= N) return;
    int lane = threadIdx.x & 63;
    if (lane >= 40) return;
    float sum = 0.f;
    int beg = rowptr[node], end = rowptr[node + 1];
    for (int k = beg; k < end; ++k) {
        int j = csr[k];
        sum += P[(size_t)j * 80 + lane];
    }
    out[(size_t)node * 40 + lane] =
        sum * inv_deg[node] + P[(size_t)node * 80 + 40 + lane] + b2[lane];
}

// ---------------- launcher ----------------

extern "C" void kernel_launch(void* const* d_in, const int* in_sizes, int n_in,
                              void* d_out, int out_size, void* d_ws, size_t ws_size,
                              hipStream_t stream) {
    const float* x   = (const float*)d_in[0];
    const int*   ei  = (const int*)d_in[1];
    const float* W1l = (const float*)d_in[2];
    const float* b1  = (const float*)d_in[3];
    const float* W1r = (const float*)d_in[4];
    const float* W2l = (const float*)d_in[5];
    const float* b2  = (const float*)d_in[6];
    const float* W2r = (const float*)d_in[7];
    const float* Q   = (const float*)d_in[8];
    const int E = in_sizes[1] / 2;
    const int N = N_NODES;
    const int* src = ei;
    const int* dst = ei + E;
    const int NB = (N + 255) / 256;   // 196

    unsigned short* Abuf = (unsigned short*)d_ws;            // [N][512] bf16
    unsigned short* h    = Abuf + (size_t)N * 512;           // [N][256] bf16
    unsigned short* B1t  = h + (size_t)N * 256;              // [256][512]
    unsigned short* B2t  = B1t + 256 * 512;                  // [80][256]
    float* P       = (float*)(B2t + 80 * 256);               // [N][80]
    float* inv_deg = P + (size_t)N * 80;                     // N
    int*   deg     = (int*)(inv_deg + N);                    // N
    int*   cnt     = deg + N;                                // N
    int*   rowptr  = cnt + N;                                // N+1
    int*   blocksums = rowptr + N + 1;                       // NB
    int*   blockoff  = blocksums + NB;                       // NB
    int*   csr     = blockoff + NB;                          // E

    float* out = (float*)d_out;

    hipMemsetAsync(deg, 0, sizeof(int) * 2 * (size_t)N, stream);
    count_kernel<<<1024, 256, 0, stream>>>(dst, deg, E);
    scan1_kernel<<<NB, 256, 0, stream>>>(deg, blocksums, N);
    scan2_kernel<<<1, 256, 0, stream>>>(blocksums, blockoff, NB);
    scan3_kernel<<<NB, 256, 0, stream>>>(deg, blockoff, rowptr, inv_deg, N, E);
    fill_kernel<<<1024, 256, 0, stream>>>(src, dst, rowptr, cnt, csr, E);

    convert_x<<<2048, 256, 0, stream>>>(x, Abuf, N * 32);
    prep_B1<<<(256 * 512 + 255) / 256, 256, 0, stream>>>(W1l, W1r, B1t);
    prep_B2<<<(80 * 256 + 255) / 256, 256, 0, stream>>>(W2l, W2r, B2t);

    aggregate1<<<(N + 3) / 4, 256, 0, stream>>>(Abuf, rowptr, csr, inv_deg, Abuf, N);
    gemm1_mfma<<<dim3((N + 127) / 128, 2), 256, 0, stream>>>(Abuf, B1t, b1, h, N);
    gemm2_mfma<<<(N + 127) / 128, 256, 0, stream>>>(h, B2t, P, N);
    final_kernel<<<(N + 3) / 4, 256, 0, stream>>>(P, rowptr, csr, inv_deg, b2, out, N);

    hipMemcpyAsync(out + (size_t)N * 40, Q, sizeof(float) * (size_t)in_sizes[8],
                   hipMemcpyDeviceToDevice, stream);
}

// Round 4
// 298.736 us; speedup vs baseline: 2.4572x; 1.2365x over previous
//
#include <hip/hip_runtime.h>
#include <hip/hip_bf16.h>
#include <cstddef>

#define N_NODES 50000
#define M_PAD 50048   // 391 * 128

typedef __attribute__((ext_vector_type(8))) short short8;
typedef __attribute__((ext_vector_type(4))) float floatx4;

__device__ inline unsigned short f2bf(float f) {
    union { float f; unsigned u; } v; v.f = f;
    unsigned r = v.u + 0x7fff + ((v.u >> 16) & 1);
    return (unsigned short)(r >> 16);
}
__device__ inline float bfbits_lo(unsigned u) {
    union { unsigned u; float f; } v; v.u = u << 16; return v.f;
}
__device__ inline float bfbits_hi(unsigned u) {
    union { unsigned u; float f; } v; v.u = u & 0xffff0000u; return v.f;
}

__device__ inline void gload16(const void* g, void* l) {
    __builtin_amdgcn_global_load_lds(
        (const __attribute__((address_space(1))) unsigned int*)g,
        (__attribute__((address_space(3))) unsigned int*)l, 16, 0, 0);
}

// ---------------- CSR build ----------------

__global__ void count_kernel(const int* __restrict__ dst, int* __restrict__ deg, int E) {
    for (int e = blockIdx.x * blockDim.x + threadIdx.x; e < E; e += gridDim.x * blockDim.x)
        atomicAdd(&deg[dst[e]], 1);
}

__global__ __launch_bounds__(256) void scan1_kernel(const int* __restrict__ deg,
                                                    int* __restrict__ blocksums, int n) {
    __shared__ int s[256];
    int t = threadIdx.x;
    int i = blockIdx.x * 256 + t;
    s[t] = (i < n) ? deg[i] : 0;
    __syncthreads();
    for (int off = 128; off > 0; off >>= 1) {
        if (t < off) s[t] += s[t + off];
        __syncthreads();
    }
    if (t == 0) blocksums[blockIdx.x] = s[0];
}

__global__ __launch_bounds__(256) void scan2_kernel(const int* __restrict__ blocksums,
                                                    int* __restrict__ blockoff, int nb) {
    __shared__ int s[256];
    int t = threadIdx.x;
    s[t] = (t < nb) ? blocksums[t] : 0;
    __syncthreads();
    for (int off = 1; off < 256; off <<= 1) {
        int u = (t >= off) ? s[t - off] : 0;
        __syncthreads();
        s[t] += u;
        __syncthreads();
    }
    if (t < nb) blockoff[t] = (t == 0) ? 0 : s[t - 1];
}

__global__ __launch_bounds__(256) void scan3_kernel(const int* __restrict__ deg,
                                                    const int* __restrict__ blockoff,
                                                    int* __restrict__ rowptr,
                                                    float* __restrict__ inv_deg,
                                                    int n, int E) {
    __shared__ int s[256];
    int t = threadIdx.x;
    int i = blockIdx.x * 256 + t;
    int v = (i < n) ? deg[i] : 0;
    s[t] = v;
    __syncthreads();
    for (int off = 1; off < 256; off <<= 1) {
        int u = (t >= off) ? s[t - off] : 0;
        __syncthreads();
        s[t] += u;
        __syncthreads();
    }
    if (i < n) {
        rowptr[i] = s[t] - v + blockoff[blockIdx.x];
        inv_deg[i] = 1.0f / (float)(v > 1 ? v : 1);
    }
    if (blockIdx.x == 0 && t == 0) rowptr[n] = E;
}

__global__ void fill_kernel(const int* __restrict__ src, const int* __restrict__ dst,
                            const int* __restrict__ rowptr, int* __restrict__ cnt,
                            int* __restrict__ csr, int E) {
    for (int e = blockIdx.x * blockDim.x + threadIdx.x; e < E; e += gridDim.x * blockDim.x) {
        int d = dst[e];
        int p = rowptr[d] + atomicAdd(&cnt[d], 1);
        csr[p] = src[e];
    }
}

// ---------------- x -> bf16 into Abuf cols 256..511 ----------------
__global__ __launch_bounds__(256) void convert_x(const float* __restrict__ x,
                                                 unsigned short* __restrict__ Abuf,
                                                 int total8) {
    for (int i = blockIdx.x * blockDim.x + threadIdx.x; i < total8;
         i += gridDim.x * blockDim.x) {
        int row = i >> 5;
        int c8 = i & 31;
        const float4* xp = reinterpret_cast<const float4*>(x + (size_t)row * 256 + c8 * 8);
        float4 v0 = xp[0], v1 = xp[1];
        uint4 o;
        o.x = (unsigned)f2bf(v0.x) | ((unsigned)f2bf(v0.y) << 16);
        o.y = (unsigned)f2bf(v0.z) | ((unsigned)f2bf(v0.w) << 16);
        o.z = (unsigned)f2bf(v1.x) | ((unsigned)f2bf(v1.y) << 16);
        o.w = (unsigned)f2bf(v1.z) | ((unsigned)f2bf(v1.w) << 16);
        *reinterpret_cast<uint4*>(Abuf + (size_t)row * 512 + 256 + c8 * 8) = o;
    }
}

// ---------------- weight prep (transposed, bf16) ----------------
__global__ void prep_B1(const float* __restrict__ W1l, const float* __restrict__ W1r,
                        unsigned short* __restrict__ B1t) {
    int idx = blockIdx.x * blockDim.x + threadIdx.x;
    if (idx >= 256 * 512) return;
    int n = idx >> 9, k = idx & 511;
    float v = (k < 256) ? W1l[(size_t)k * 256 + n] : W1r[(size_t)(k - 256) * 256 + n];
    B1t[(size_t)n * 512 + k] = f2bf(v);
}
__global__ void prep_B2(const float* __restrict__ W2l, const float* __restrict__ W2r,
                        unsigned short* __restrict__ B2t) {
    int idx = blockIdx.x * blockDim.x + threadIdx.x;
    if (idx >= 80 * 256) return;
    int n = idx >> 8, k = idx & 255;
    float v = (n < 40) ? W2l[(size_t)k * 40 + n] : W2r[(size_t)k * 40 + (n - 40)];
    B2t[(size_t)n * 256 + k] = f2bf(v);
}

// ---------------- mean aggregation over bf16 features (256-d) ----------------
__global__ __launch_bounds__(256) void aggregate1(
    const unsigned short* __restrict__ Abuf, const int* __restrict__ rowptr,
    const int* __restrict__ csr, const float* __restrict__ inv_deg,
    unsigned short* __restrict__ AbufOut, int N) {
    int node = blockIdx.x * 4 + (threadIdx.x >> 6);
    if (node >= N) return;
    int lane = threadIdx.x & 63;
    float a0 = 0.f, a1 = 0.f, a2 = 0.f, a3 = 0.f;
    int beg = rowptr[node], end = rowptr[node + 1];
    int k = beg;
    int nn = end - beg;
    // 4-deep MLP unroll
    for (; k + 4 <= end; k += 4) {
        int j0 = csr[k], j1 = csr[k + 1], j2 = csr[k + 2], j3 = csr[k + 3];
        uint2 v0 = *reinterpret_cast<const uint2*>(Abuf + (size_t)j0 * 512 + 256 + lane * 4);
        uint2 v1 = *reinterpret_cast<const uint2*>(Abuf + (size_t)j1 * 512 + 256 + lane * 4);
        uint2 v2 = *reinterpret_cast<const uint2*>(Abuf + (size_t)j2 * 512 + 256 + lane * 4);
        uint2 v3 = *reinterpret_cast<const uint2*>(Abuf + (size_t)j3 * 512 + 256 + lane * 4);
        a0 += bfbits_lo(v0.x); a1 += bfbits_hi(v0.x); a2 += bfbits_lo(v0.y); a3 += bfbits_hi(v0.y);
        a0 += bfbits_lo(v1.x); a1 += bfbits_hi(v1.x); a2 += bfbits_lo(v1.y); a3 += bfbits_hi(v1.y);
        a0 += bfbits_lo(v2.x); a1 += bfbits_hi(v2.x); a2 += bfbits_lo(v2.y); a3 += bfbits_hi(v2.y);
        a0 += bfbits_lo(v3.x); a1 += bfbits_hi(v3.x); a2 += bfbits_lo(v3.y); a3 += bfbits_hi(v3.y);
    }
    for (; k < end; ++k) {
        int j = csr[k];
        uint2 v = *reinterpret_cast<const uint2*>(Abuf + (size_t)j * 512 + 256 + lane * 4);
        a0 += bfbits_lo(v.x); a1 += bfbits_hi(v.x);
        a2 += bfbits_lo(v.y); a3 += bfbits_hi(v.y);
    }
    (void)nn;
    float s = inv_deg[node];
    uint2 w;
    w.x = (unsigned)f2bf(a0 * s) | ((unsigned)f2bf(a1 * s) << 16);
    w.y = (unsigned)f2bf(a2 * s) | ((unsigned)f2bf(a3 * s) << 16);
    *reinterpret_cast<uint2*>(AbufOut + (size_t)node * 512 + lane * 4) = w;
}

// ---------------- GEMM1 (MFMA, m97-style): h = elu(Abuf @ B1t^T + b1) ----------------
// M_PAD x 512 @ 512 x 128(panel), tile 128x128, BK=32, 4 waves, global_load_lds,
// pre-swizzled source (chunk ^= row&3) so frag ds_read_b128 is 2-way (free).
__global__ __launch_bounds__(256) void gemm1_mfma(
    const unsigned short* __restrict__ Abuf,   // [M_PAD][512]
    const unsigned short* __restrict__ B1t,    // [256][512]
    const float* __restrict__ bias,            // [256]
    unsigned short* __restrict__ H,            // [M_PAD][256] bf16
    int M) {
    __shared__ unsigned short As[2][128 * 32];
    __shared__ unsigned short Bs[2][128 * 32];
    int tid = threadIdx.x;
    int row0 = blockIdx.x * 128;
    int bn = blockIdx.y;
    int wid = tid >> 6, lane = tid & 63;
    int wm = (wid >> 1) * 64, wn = (wid & 1) * 64;
    int fr = lane & 15, fq = lane >> 4;

    // staging: issue q covers tile rows q*16..q*16+15; lane l -> row q*16+(l>>2),
    // LDS chunk (l&3), global chunk (l&3)^((l>>2)&3)  [swizzle both sides]
    int lrow = lane >> 2;
    int lchunk = ((lane & 3) ^ (lrow & 3)) * 8;
    int q0 = wid, q1 = wid + 4;
    const unsigned short* gA0 = Abuf + (size_t)(row0 + q0 * 16 + lrow) * 512 + lchunk;
    const unsigned short* gA1 = Abuf + (size_t)(row0 + q1 * 16 + lrow) * 512 + lchunk;
    const unsigned short* gB0 = B1t + (size_t)(bn * 128 + q0 * 16 + lrow) * 512 + lchunk;
    const unsigned short* gB1 = B1t + (size_t)(bn * 128 + q1 * 16 + lrow) * 512 + lchunk;

    floatx4 acc[4][4] = {};
    int achunk = (fq ^ (fr & 3)) * 8;   // frag read: row&3 == fr&3

    #define STAGE(buf, k0)                                   \
        gload16(gA0 + (k0), &As[buf][q0 * 512]);             \
        gload16(gA1 + (k0), &As[buf][q1 * 512]);             \
        gload16(gB0 + (k0), &Bs[buf][q0 * 512]);             \
        gload16(gB1 + (k0), &Bs[buf][q1 * 512]);

    #define COMPUTE(buf)                                                                     \
        {                                                                                    \
            short8 af[4], bfr[4];                                                            \
            _Pragma("unroll")                                                                \
            for (int mi = 0; mi < 4; ++mi)                                                   \
                af[mi] = *reinterpret_cast<const short8*>(                                   \
                    &As[buf][(wm + mi * 16 + fr) * 32 + achunk]);                            \
            _Pragma("unroll")                                                                \
            for (int ni = 0; ni < 4; ++ni)                                                   \
                bfr[ni] = *reinterpret_cast<const short8*>(                                  \
                    &Bs[buf][(wn + ni * 16 + fr) * 32 + achunk]);                            \
            _Pragma("unroll")                                                                \
            for (int mi = 0; mi < 4; ++mi)                                                   \
                _Pragma("unroll")                                                            \
                for (int ni = 0; ni < 4; ++ni)                                               \
                    acc[mi][ni] = __builtin_amdgcn_mfma_f32_16x16x32_bf16(                   \
                        af[mi], bfr[ni], acc[mi][ni], 0, 0, 0);                              \
        }

    STAGE(0, 0);
    __syncthreads();
    int cur = 0;
    for (int t = 0; t < 15; ++t) {
        STAGE(cur ^ 1, (t + 1) * 32);   // prefetch next tile (stays in flight over compute)
        COMPUTE(cur);
        __syncthreads();                // drains vmcnt -> next tile ready
        cur ^= 1;
    }
    COMPUTE(cur);
    #undef STAGE
    #undef COMPUTE

    #pragma unroll
    for (int ni = 0; ni < 4; ++ni) {
        int gcol = bn * 128 + wn + ni * 16 + fr;
        float bb = bias[gcol];
        #pragma unroll
        for (int mi = 0; mi < 4; ++mi) {
            #pragma unroll
            for (int r = 0; r < 4; ++r) {
                int grow = row0 + wm + mi * 16 + fq * 4 + r;
                if (grow < M) {
                    float t = acc[mi][ni][r] + bb;
                    t = (t > 0.f) ? t : expm1f(t);
                    H[(size_t)grow * 256 + gcol] = f2bf(t);
                }
            }
        }
    }
}

// ---------------- GEMM2 (MFMA): P = H @ B2t^T, fp32 out ----------------
__global__ __launch_bounds__(256) void gemm2_mfma(
    const unsigned short* __restrict__ Hb,
    const unsigned short* __restrict__ B2t,
    float* __restrict__ P,
    int M) {
    __shared__ unsigned short As[128][40];
    __shared__ unsigned short Bs[80][40];
    int tid = threadIdx.x;
    int row0 = blockIdx.x * 128;
    int wid = tid >> 6, lane = tid & 63;
    int wm = wid * 32;
    int fr = lane & 15, fq = lane >> 4;

    floatx4 acc[2][5] = {};

    int c0 = tid, c1 = tid + 256;
    int r0 = c0 >> 2, ko0 = (c0 & 3) * 8;
    int r1 = c1 >> 2, ko1 = (c1 & 3) * 8;
    int br0 = tid >> 2, bko0 = (tid & 3) * 8;
    int br1 = (tid + 256) >> 2, bko1 = ((tid + 256) & 3) * 8;

    for (int k0 = 0; k0 < 256; k0 += 32) {
        short8 av0 = {}, av1 = {};
        if (row0 + r0 < M)
            av0 = *reinterpret_cast<const short8*>(Hb + (size_t)(row0 + r0) * 256 + k0 + ko0);
        if (row0 + r1 < M)
            av1 = *reinterpret_cast<const short8*>(Hb + (size_t)(row0 + r1) * 256 + k0 + ko1);
        short8 bv0 = {}, bv1 = {};
        if (br0 < 80)
            bv0 = *reinterpret_cast<const short8*>(B2t + (size_t)br0 * 256 + k0 + bko0);
        if (tid < 64)
            bv1 = *reinterpret_cast<const short8*>(B2t + (size_t)br1 * 256 + k0 + bko1);
        __syncthreads();
        *reinterpret_cast<short8*>(&As[r0][ko0]) = av0;
        *reinterpret_cast<short8*>(&As[r1][ko1]) = av1;
        if (br0 < 80) *reinterpret_cast<short8*>(&Bs[br0][bko0]) = bv0;
        if (tid < 64) *reinterpret_cast<short8*>(&Bs[br1][bko1]) = bv1;
        __syncthreads();
        short8 af[2], bf[5];
        #pragma unroll
        for (int mi = 0; mi < 2; ++mi)
            af[mi] = *reinterpret_cast<const short8*>(&As[wm + mi * 16 + fr][fq * 8]);
        #pragma unroll
        for (int ni = 0; ni < 5; ++ni)
            bf[ni] = *reinterpret_cast<const short8*>(&Bs[ni * 16 + fr][fq * 8]);
        #pragma unroll
        for (int mi = 0; mi < 2; ++mi)
            #pragma unroll
            for (int ni = 0; ni < 5; ++ni)
                acc[mi][ni] = __builtin_amdgcn_mfma_f32_16x16x32_bf16(af[mi], bf[ni], acc[mi][ni], 0, 0, 0);
        __syncthreads();
    }
    #pragma unroll
    for (int mi = 0; mi < 2; ++mi) {
        #pragma unroll
        for (int r = 0; r < 4; ++r) {
            int grow = row0 + wm + mi * 16 + fq * 4 + r;
            if (grow < M) {
                #pragma unroll
                for (int ni = 0; ni < 5; ++ni)
                    P[(size_t)grow * 80 + ni * 16 + fr] = acc[mi][ni][r];
            }
        }
    }
}

// ---------------- final: out = mean_agg(P[:,0:40]) + P[:,40:80] + b2 ----------------
__global__ __launch_bounds__(256) void final_kernel(
    const float* __restrict__ P, const int* __restrict__ rowptr,
    const int* __restrict__ csr, const float* __restrict__ inv_deg,
    const float* __restrict__ b2, float* __restrict__ out, int N) {
    int node = blockIdx.x * 4 + (threadIdx.x >> 6);
    if (node >= N) return;
    int lane = threadIdx.x & 63;
    if (lane >= 40) return;
    float sum = 0.f;
    int beg = rowptr[node], end = rowptr[node + 1];
    int k = beg;
    for (; k + 4 <= end; k += 4) {
        int j0 = csr[k], j1 = csr[k + 1], j2 = csr[k + 2], j3 = csr[k + 3];
        float s0 = P[(size_t)j0 * 80 + lane];
        float s1 = P[(size_t)j1 * 80 + lane];
        float s2 = P[(size_t)j2 * 80 + lane];
        float s3 = P[(size_t)j3 * 80 + lane];
        sum += (s0 + s1) + (s2 + s3);
    }
    for (; k < end; ++k)
        sum += P[(size_t)csr[k] * 80 + lane];
    out[(size_t)node * 40 + lane] =
        sum * inv_deg[node] + P[(size_t)node * 80 + 40 + lane] + b2[lane];
}

// ---------------- launcher ----------------

extern "C" void kernel_launch(void* const* d_in, const int* in_sizes, int n_in,
                              void* d_out, int out_size, void* d_ws, size_t ws_size,
                              hipStream_t stream) {
    const float* x   = (const float*)d_in[0];
    const int*   ei  = (const int*)d_in[1];
    const float* W1l = (const float*)d_in[2];
    const float* b1  = (const float*)d_in[3];
    const float* W1r = (const float*)d_in[4];
    const float* W2l = (const float*)d_in[5];
    const float* b2  = (const float*)d_in[6];
    const float* W2r = (const float*)d_in[7];
    const float* Q   = (const float*)d_in[8];
    const int E = in_sizes[1] / 2;
    const int N = N_NODES;
    const int* src = ei;
    const int* dst = ei + E;
    const int NB = (N + 255) / 256;

    unsigned short* Abuf = (unsigned short*)d_ws;            // [M_PAD][512] bf16
    unsigned short* h    = Abuf + (size_t)M_PAD * 512;       // [M_PAD][256] bf16
    unsigned short* B1t  = h + (size_t)M_PAD * 256;          // [256][512]
    unsigned short* B2t  = B1t + 256 * 512;                  // [80][256]
    float* P       = (float*)(B2t + 80 * 256);               // [N][80]
    float* inv_deg = P + (size_t)N * 80;                     // N
    int*   deg     = (int*)(inv_deg + N);                    // N
    int*   cnt     = deg + N;                                // N
    int*   rowptr  = cnt + N;                                // N+1
    int*   blocksums = rowptr + N + 1;                       // NB
    int*   blockoff  = blocksums + NB;                       // NB
    int*   csr     = blockoff + NB;                          // E

    float* out = (float*)d_out;

    hipMemsetAsync(deg, 0, sizeof(int) * 2 * (size_t)N, stream);
    count_kernel<<<1024, 256, 0, stream>>>(dst, deg, E);
    scan1_kernel<<<NB, 256, 0, stream>>>(deg, blocksums, N);
    scan2_kernel<<<1, 256, 0, stream>>>(blocksums, blockoff, NB);
    scan3_kernel<<<NB, 256, 0, stream>>>(deg, blockoff, rowptr, inv_deg, N, E);
    fill_kernel<<<1024, 256, 0, stream>>>(src, dst, rowptr, cnt, csr, E);

    convert_x<<<2048, 256, 0, stream>>>(x, Abuf, N * 32);
    prep_B1<<<(256 * 512 + 255) / 256, 256, 0, stream>>>(W1l, W1r, B1t);
    prep_B2<<<(80 * 256 + 255) / 256, 256, 0, stream>>>(W2l, W2r, B2t);

    aggregate1<<<(N + 3) / 4, 256, 0, stream>>>(Abuf, rowptr, csr, inv_deg, Abuf, N);
    gemm1_mfma<<<dim3(M_PAD / 128, 2), 256, 0, stream>>>(Abuf, B1t, b1, h, N);
    gemm2_mfma<<<M_PAD / 128, 256, 0, stream>>>(h, B2t, P, N);
    final_kernel<<<(N + 3) / 4, 256, 0, stream>>>(P, rowptr, csr, inv_deg, b2, out, N);

    hipMemcpyAsync(out + (size_t)N * 40, Q, sizeof(float) * (size_t)in_sizes[8],
                   hipMemcpyDeviceToDevice, stream);
}

// Round 5
// 293.213 us; speedup vs baseline: 2.5035x; 1.0188x over previous
//
#include <hip/hip_runtime.h>
#include <hip/hip_bf16.h>
#include <cstddef>

#define N_NODES 50000
#define M_PAD 50048   // 391 * 128 (also multiple of 64)

typedef __attribute__((ext_vector_type(8))) short short8;
typedef __attribute__((ext_vector_type(4))) float floatx4;

__device__ inline unsigned short f2bf(float f) {
    union { float f; unsigned u; } v; v.f = f;
    unsigned r = v.u + 0x7fff + ((v.u >> 16) & 1);
    return (unsigned short)(r >> 16);
}
__device__ inline float bfbits_lo(unsigned u) {
    union { unsigned u; float f; } v; v.u = u << 16; return v.f;
}
__device__ inline float bfbits_hi(unsigned u) {
    union { unsigned u; float f; } v; v.u = u & 0xffff0000u; return v.f;
}

__device__ inline void gload16(const void* g, void* l) {
    __builtin_amdgcn_global_load_lds(
        (const __attribute__((address_space(1))) unsigned int*)g,
        (__attribute__((address_space(3))) unsigned int*)l, 16, 0, 0);
}

// ---------------- CSR build ----------------

__global__ void count_kernel(const int* __restrict__ dst, int* __restrict__ deg, int E) {
    for (int e = blockIdx.x * blockDim.x + threadIdx.x; e < E; e += gridDim.x * blockDim.x)
        atomicAdd(&deg[dst[e]], 1);
}

__global__ __launch_bounds__(256) void scan1_kernel(const int* __restrict__ deg,
                                                    int* __restrict__ blocksums, int n) {
    __shared__ int s[256];
    int t = threadIdx.x;
    int i = blockIdx.x * 256 + t;
    s[t] = (i < n) ? deg[i] : 0;
    __syncthreads();
    for (int off = 128; off > 0; off >>= 1) {
        if (t < off) s[t] += s[t + off];
        __syncthreads();
    }
    if (t == 0) blocksums[blockIdx.x] = s[0];
}

__global__ __launch_bounds__(256) void scan2_kernel(const int* __restrict__ blocksums,
                                                    int* __restrict__ blockoff, int nb) {
    __shared__ int s[256];
    int t = threadIdx.x;
    s[t] = (t < nb) ? blocksums[t] : 0;
    __syncthreads();
    for (int off = 1; off < 256; off <<= 1) {
        int u = (t >= off) ? s[t - off] : 0;
        __syncthreads();
        s[t] += u;
        __syncthreads();
    }
    if (t < nb) blockoff[t] = (t == 0) ? 0 : s[t - 1];
}

__global__ __launch_bounds__(256) void scan3_kernel(const int* __restrict__ deg,
                                                    const int* __restrict__ blockoff,
                                                    int* __restrict__ rowptr,
                                                    float* __restrict__ inv_deg,
                                                    int n, int E) {
    __shared__ int s[256];
    int t = threadIdx.x;
    int i = blockIdx.x * 256 + t;
    int v = (i < n) ? deg[i] : 0;
    s[t] = v;
    __syncthreads();
    for (int off = 1; off < 256; off <<= 1) {
        int u = (t >= off) ? s[t - off] : 0;
        __syncthreads();
        s[t] += u;
        __syncthreads();
    }
    if (i < n) {
        rowptr[i] = s[t] - v + blockoff[blockIdx.x];
        inv_deg[i] = 1.0f / (float)(v > 1 ? v : 1);
    }
    if (blockIdx.x == 0 && t == 0) rowptr[n] = E;
}

__global__ void fill_kernel(const int* __restrict__ src, const int* __restrict__ dst,
                            const int* __restrict__ rowptr, int* __restrict__ cnt,
                            int* __restrict__ csr, int E) {
    for (int e = blockIdx.x * blockDim.x + threadIdx.x; e < E; e += gridDim.x * blockDim.x) {
        int d = dst[e];
        int p = rowptr[d] + atomicAdd(&cnt[d], 1);
        csr[p] = src[e];
    }
}

// ---------------- x -> bf16 into Abuf cols 256..511 ----------------
__global__ __launch_bounds__(256) void convert_x(const float* __restrict__ x,
                                                 unsigned short* __restrict__ Abuf,
                                                 int total8) {
    for (int i = blockIdx.x * blockDim.x + threadIdx.x; i < total8;
         i += gridDim.x * blockDim.x) {
        int row = i >> 5;
        int c8 = i & 31;
        const float4* xp = reinterpret_cast<const float4*>(x + (size_t)row * 256 + c8 * 8);
        float4 v0 = xp[0], v1 = xp[1];
        uint4 o;
        o.x = (unsigned)f2bf(v0.x) | ((unsigned)f2bf(v0.y) << 16);
        o.y = (unsigned)f2bf(v0.z) | ((unsigned)f2bf(v0.w) << 16);
        o.z = (unsigned)f2bf(v1.x) | ((unsigned)f2bf(v1.y) << 16);
        o.w = (unsigned)f2bf(v1.z) | ((unsigned)f2bf(v1.w) << 16);
        *reinterpret_cast<uint4*>(Abuf + (size_t)row * 512 + 256 + c8 * 8) = o;
    }
}

// ---------------- weight prep (transposed, bf16) ----------------
__global__ void prep_B1(const float* __restrict__ W1l, const float* __restrict__ W1r,
                        unsigned short* __restrict__ B1t) {
    int idx = blockIdx.x * blockDim.x + threadIdx.x;
    if (idx >= 256 * 512) return;
    int n = idx >> 9, k = idx & 511;
    float v = (k < 256) ? W1l[(size_t)k * 256 + n] : W1r[(size_t)(k - 256) * 256 + n];
    B1t[(size_t)n * 512 + k] = f2bf(v);
}
__global__ void prep_B2(const float* __restrict__ W2l, const float* __restrict__ W2r,
                        unsigned short* __restrict__ B2t) {
    int idx = blockIdx.x * blockDim.x + threadIdx.x;
    if (idx >= 80 * 256) return;
    int n = idx >> 8, k = idx & 255;
    float v = (n < 40) ? W2l[(size_t)k * 40 + n] : W2r[(size_t)k * 40 + (n - 40)];
    B2t[(size_t)n * 256 + k] = f2bf(v);
}

// ---------------- mean aggregation over bf16 features (256-d) ----------------
__global__ __launch_bounds__(256) void aggregate1(
    const unsigned short* __restrict__ Abuf, const int* __restrict__ rowptr,
    const int* __restrict__ csr, const float* __restrict__ inv_deg,
    unsigned short* __restrict__ AbufOut, int N) {
    int node = blockIdx.x * 4 + (threadIdx.x >> 6);
    if (node >= N) return;
    int lane = threadIdx.x & 63;
    float a0 = 0.f, a1 = 0.f, a2 = 0.f, a3 = 0.f;
    int beg = rowptr[node], end = rowptr[node + 1];
    int k = beg;
    for (; k + 4 <= end; k += 4) {
        int j0 = csr[k], j1 = csr[k + 1], j2 = csr[k + 2], j3 = csr[k + 3];
        uint2 v0 = *reinterpret_cast<const uint2*>(Abuf + (size_t)j0 * 512 + 256 + lane * 4);
        uint2 v1 = *reinterpret_cast<const uint2*>(Abuf + (size_t)j1 * 512 + 256 + lane * 4);
        uint2 v2 = *reinterpret_cast<const uint2*>(Abuf + (size_t)j2 * 512 + 256 + lane * 4);
        uint2 v3 = *reinterpret_cast<const uint2*>(Abuf + (size_t)j3 * 512 + 256 + lane * 4);
        a0 += bfbits_lo(v0.x); a1 += bfbits_hi(v0.x); a2 += bfbits_lo(v0.y); a3 += bfbits_hi(v0.y);
        a0 += bfbits_lo(v1.x); a1 += bfbits_hi(v1.x); a2 += bfbits_lo(v1.y); a3 += bfbits_hi(v1.y);
        a0 += bfbits_lo(v2.x); a1 += bfbits_hi(v2.x); a2 += bfbits_lo(v2.y); a3 += bfbits_hi(v2.y);
        a0 += bfbits_lo(v3.x); a1 += bfbits_hi(v3.x); a2 += bfbits_lo(v3.y); a3 += bfbits_hi(v3.y);
    }
    for (; k < end; ++k) {
        int j = csr[k];
        uint2 v = *reinterpret_cast<const uint2*>(Abuf + (size_t)j * 512 + 256 + lane * 4);
        a0 += bfbits_lo(v.x); a1 += bfbits_hi(v.x);
        a2 += bfbits_lo(v.y); a3 += bfbits_hi(v.y);
    }
    float s = inv_deg[node];
    uint2 w;
    w.x = (unsigned)f2bf(a0 * s) | ((unsigned)f2bf(a1 * s) << 16);
    w.y = (unsigned)f2bf(a2 * s) | ((unsigned)f2bf(a3 * s) << 16);
    *reinterpret_cast<uint2*>(AbufOut + (size_t)node * 512 + lane * 4) = w;
}

// ---------------- GEMM1 (MFMA): h = elu(Abuf @ B1t^T + b1) ----------------
// BM=64, BN=64, BK=64; grid (M_PAD/64, 4) = 3128 blocks for TLP.
// global_load_lds staging, XOR swizzle (16B chunk ^= row&7) both sides.
__global__ __launch_bounds__(256) void gemm1_mfma(
    const unsigned short* __restrict__ Abuf,   // [M_PAD][512]
    const unsigned short* __restrict__ B1t,    // [256][512]
    const float* __restrict__ bias,            // [256]
    unsigned short* __restrict__ H,            // [M_PAD][256] bf16
    int M) {
    __shared__ unsigned short As[2][64 * 64];
    __shared__ unsigned short Bs[2][64 * 64];
    int tid = threadIdx.x;
    int row0 = blockIdx.x * 64;
    int bn = blockIdx.y;                 // 0..3
    int wid = tid >> 6, lane = tid & 63;
    int wm = (wid >> 1) * 32, wn = (wid & 1) * 32;
    int fr = lane & 15, fq = lane >> 4;

    // staging: each wave issues 2 A + 2 B gload16; instr covers 8 rows x 128B.
    // lane l -> row +(l>>3), 16B-chunk (l&7) in LDS; global chunk (l&7)^(l>>3).
    int lrow8 = lane >> 3;               // 0..7
    int gco = ((lane & 7) ^ lrow8) * 8;  // pre-swizzled global elem offset
    int rA0 = wid * 16, rA1 = wid * 16 + 8;
    const unsigned short* gA0 = Abuf + (size_t)(row0 + rA0 + lrow8) * 512 + gco;
    const unsigned short* gA1 = Abuf + (size_t)(row0 + rA1 + lrow8) * 512 + gco;
    const unsigned short* gB0 = B1t + (size_t)(bn * 64 + rA0 + lrow8) * 512 + gco;
    const unsigned short* gB1 = B1t + (size_t)(bn * 64 + rA1 + lrow8) * 512 + gco;

    floatx4 acc[2][2] = {};

    #define STAGE(buf, k0)                               \
        gload16(gA0 + (k0), &As[buf][rA0 * 64]);         \
        gload16(gA1 + (k0), &As[buf][rA1 * 64]);         \
        gload16(gB0 + (k0), &Bs[buf][rA0 * 64]);         \
        gload16(gB1 + (k0), &Bs[buf][rA1 * 64]);

    // frag read: row elem-base row*64; chunk (kc*4+fq)^(fr&7); 2-way conflict (free)
    #define COMPUTE(buf)                                                                  \
        {                                                                                 \
            _Pragma("unroll")                                                             \
            for (int kc = 0; kc < 2; ++kc) {                                              \
                short8 af[2], bfr[2];                                                     \
                _Pragma("unroll")                                                         \
                for (int mi = 0; mi < 2; ++mi) {                                          \
                    int row = wm + mi * 16 + fr;                                          \
                    af[mi] = *reinterpret_cast<const short8*>(                            \
                        &As[buf][row * 64 + (((kc * 4 + fq) ^ (fr & 7)) * 8)]);           \
                }                                                                         \
                _Pragma("unroll")                                                         \
                for (int ni = 0; ni < 2; ++ni) {                                          \
                    int row = wn + ni * 16 + fr;                                          \
                    bfr[ni] = *reinterpret_cast<const short8*>(                           \
                        &Bs[buf][row * 64 + (((kc * 4 + fq) ^ (fr & 7)) * 8)]);           \
                }                                                                         \
                _Pragma("unroll")                                                         \
                for (int mi = 0; mi < 2; ++mi)                                            \
                    _Pragma("unroll")                                                     \
                    for (int ni = 0; ni < 2; ++ni)                                        \
                        acc[mi][ni] = __builtin_amdgcn_mfma_f32_16x16x32_bf16(            \
                            af[mi], bfr[ni], acc[mi][ni], 0, 0, 0);                       \
            }                                                                             \
        }

    STAGE(0, 0);
    __syncthreads();
    int cur = 0;
    #pragma unroll 1
    for (int t = 0; t < 7; ++t) {
        STAGE(cur ^ 1, (t + 1) * 64);
        COMPUTE(cur);
        __syncthreads();
        cur ^= 1;
    }
    COMPUTE(cur);
    #undef STAGE
    #undef COMPUTE

    #pragma unroll
    for (int ni = 0; ni < 2; ++ni) {
        int gcol = bn * 64 + wn + ni * 16 + fr;
        float bb = bias[gcol];
        #pragma unroll
        for (int mi = 0; mi < 2; ++mi) {
            #pragma unroll
            for (int r = 0; r < 4; ++r) {
                int grow = row0 + wm + mi * 16 + fq * 4 + r;
                if (grow < M) {
                    float t = acc[mi][ni][r] + bb;
                    t = (t > 0.f) ? t : expm1f(t);
                    H[(size_t)grow * 256 + gcol] = f2bf(t);
                }
            }
        }
    }
}

// ---------------- GEMM2 (MFMA): P = H @ B2t^T, fp32 out ----------------
__global__ __launch_bounds__(256) void gemm2_mfma(
    const unsigned short* __restrict__ Hb,
    const unsigned short* __restrict__ B2t,
    float* __restrict__ P,
    int M) {
    __shared__ unsigned short As[128][40];
    __shared__ unsigned short Bs[80][40];
    int tid = threadIdx.x;
    int row0 = blockIdx.x * 128;
    int wid = tid >> 6, lane = tid & 63;
    int wm = wid * 32;
    int fr = lane & 15, fq = lane >> 4;

    floatx4 acc[2][5] = {};

    int c0 = tid, c1 = tid + 256;
    int r0 = c0 >> 2, ko0 = (c0 & 3) * 8;
    int r1 = c1 >> 2, ko1 = (c1 & 3) * 8;
    int br0 = tid >> 2, bko0 = (tid & 3) * 8;
    int br1 = (tid + 256) >> 2, bko1 = ((tid + 256) & 3) * 8;

    for (int k0 = 0; k0 < 256; k0 += 32) {
        short8 av0 = {}, av1 = {};
        if (row0 + r0 < M)
            av0 = *reinterpret_cast<const short8*>(Hb + (size_t)(row0 + r0) * 256 + k0 + ko0);
        if (row0 + r1 < M)
            av1 = *reinterpret_cast<const short8*>(Hb + (size_t)(row0 + r1) * 256 + k0 + ko1);
        short8 bv0 = {}, bv1 = {};
        if (br0 < 80)
            bv0 = *reinterpret_cast<const short8*>(B2t + (size_t)br0 * 256 + k0 + bko0);
        if (tid < 64)
            bv1 = *reinterpret_cast<const short8*>(B2t + (size_t)br1 * 256 + k0 + bko1);
        __syncthreads();
        *reinterpret_cast<short8*>(&As[r0][ko0]) = av0;
        *reinterpret_cast<short8*>(&As[r1][ko1]) = av1;
        if (br0 < 80) *reinterpret_cast<short8*>(&Bs[br0][bko0]) = bv0;
        if (tid < 64) *reinterpret_cast<short8*>(&Bs[br1][bko1]) = bv1;
        __syncthreads();
        short8 af[2], bf[5];
        #pragma unroll
        for (int mi = 0; mi < 2; ++mi)
            af[mi] = *reinterpret_cast<const short8*>(&As[wm + mi * 16 + fr][fq * 8]);
        #pragma unroll
        for (int ni = 0; ni < 5; ++ni)
            bf[ni] = *reinterpret_cast<const short8*>(&Bs[ni * 16 + fr][fq * 8]);
        #pragma unroll
        for (int mi = 0; mi < 2; ++mi)
            #pragma unroll
            for (int ni = 0; ni < 5; ++ni)
                acc[mi][ni] = __builtin_amdgcn_mfma_f32_16x16x32_bf16(af[mi], bf[ni], acc[mi][ni], 0, 0, 0);
        __syncthreads();
    }
    #pragma unroll
    for (int mi = 0; mi < 2; ++mi) {
        #pragma unroll
        for (int r = 0; r < 4; ++r) {
            int grow = row0 + wm + mi * 16 + fq * 4 + r;
            if (grow < M) {
                #pragma unroll
                for (int ni = 0; ni < 5; ++ni)
                    P[(size_t)grow * 80 + ni * 16 + fr] = acc[mi][ni][r];
            }
        }
    }
}

// ---------------- final: out = mean_agg(P[:,0:40]) + P[:,40:80] + b2 ----------------
__global__ __launch_bounds__(256) void final_kernel(
    const float* __restrict__ P, const int* __restrict__ rowptr,
    const int* __restrict__ csr, const float* __restrict__ inv_deg,
    const float* __restrict__ b2, float* __restrict__ out, int N) {
    int node = blockIdx.x * 4 + (threadIdx.x >> 6);
    if (node >= N) return;
    int lane = threadIdx.x & 63;
    if (lane >= 40) return;
    float sum = 0.f;
    int beg = rowptr[node], end = rowptr[node + 1];
    int k = beg;
    for (; k + 4 <= end; k += 4) {
        int j0 = csr[k], j1 = csr[k + 1], j2 = csr[k + 2], j3 = csr[k + 3];
        float s0 = P[(size_t)j0 * 80 + lane];
        float s1 = P[(size_t)j1 * 80 + lane];
        float s2 = P[(size_t)j2 * 80 + lane];
        float s3 = P[(size_t)j3 * 80 + lane];
        sum += (s0 + s1) + (s2 + s3);
    }
    for (; k < end; ++k)
        sum += P[(size_t)csr[k] * 80 + lane];
    out[(size_t)node * 40 + lane] =
        sum * inv_deg[node] + P[(size_t)node * 80 + 40 + lane] + b2[lane];
}

// ---------------- launcher ----------------

extern "C" void kernel_launch(void* const* d_in, const int* in_sizes, int n_in,
                              void* d_out, int out_size, void* d_ws, size_t ws_size,
                              hipStream_t stream) {
    const float* x   = (const float*)d_in[0];
    const int*   ei  = (const int*)d_in[1];
    const float* W1l = (const float*)d_in[2];
    const float* b1  = (const float*)d_in[3];
    const float* W1r = (const float*)d_in[4];
    const float* W2l = (const float*)d_in[5];
    const float* b2  = (const float*)d_in[6];
    const float* W2r = (const float*)d_in[7];
    const float* Q   = (const float*)d_in[8];
    const int E = in_sizes[1] / 2;
    const int N = N_NODES;
    const int* src = ei;
    const int* dst = ei + E;
    const int NB = (N + 255) / 256;

    unsigned short* Abuf = (unsigned short*)d_ws;            // [M_PAD][512] bf16
    unsigned short* h    = Abuf + (size_t)M_PAD * 512;       // [M_PAD][256] bf16
    unsigned short* B1t  = h + (size_t)M_PAD * 256;          // [256][512]
    unsigned short* B2t  = B1t + 256 * 512;                  // [80][256]
    float* P       = (float*)(B2t + 80 * 256);               // [N][80]
    float* inv_deg = P + (size_t)N * 80;                     // N
    int*   deg     = (int*)(inv_deg + N);                    // N
    int*   cnt     = deg + N;                                // N
    int*   rowptr  = cnt + N;                                // N+1
    int*   blocksums = rowptr + N + 1;                       // NB
    int*   blockoff  = blocksums + NB;                       // NB
    int*   csr     = blockoff + NB;                          // E

    float* out = (float*)d_out;

    hipMemsetAsync(deg, 0, sizeof(int) * 2 * (size_t)N, stream);
    count_kernel<<<1024, 256, 0, stream>>>(dst, deg, E);
    scan1_kernel<<<NB, 256, 0, stream>>>(deg, blocksums, N);
    scan2_kernel<<<1, 256, 0, stream>>>(blocksums, blockoff, NB);
    scan3_kernel<<<NB, 256, 0, stream>>>(deg, blockoff, rowptr, inv_deg, N, E);
    fill_kernel<<<1024, 256, 0, stream>>>(src, dst, rowptr, cnt, csr, E);

    convert_x<<<2048, 256, 0, stream>>>(x, Abuf, N * 32);
    prep_B1<<<(256 * 512 + 255) / 256, 256, 0, stream>>>(W1l, W1r, B1t);
    prep_B2<<<(80 * 256 + 255) / 256, 256, 0, stream>>>(W2l, W2r, B2t);

    aggregate1<<<(N + 3) / 4, 256, 0, stream>>>(Abuf, rowptr, csr, inv_deg, Abuf, N);
    gemm1_mfma<<<dim3(M_PAD / 64, 4), 256, 0, stream>>>(Abuf, B1t, b1, h, N);
    gemm2_mfma<<<M_PAD / 128, 256, 0, stream>>>(h, B2t, P, N);
    final_kernel<<<(N + 3) / 4, 256, 0, stream>>>(P, rowptr, csr, inv_deg, b2, out, N);

    hipMemcpyAsync(out + (size_t)N * 40, Q, sizeof(float) * (size_t)in_sizes[8],
                   hipMemcpyDeviceToDevice, stream);
}

// Round 6
// 277.740 us; speedup vs baseline: 2.6430x; 1.0557x over previous
//
#include <hip/hip_runtime.h>
#include <hip/hip_bf16.h>
#include <cstddef>

#define N_NODES 50000
#define M_PAD 50048   // multiple of 128 and 64

typedef __attribute__((ext_vector_type(8))) short short8;
typedef __attribute__((ext_vector_type(4))) float floatx4;

__device__ inline unsigned short f2bf(float f) {
    union { float f; unsigned u; } v; v.f = f;
    unsigned r = v.u + 0x7fff + ((v.u >> 16) & 1);
    return (unsigned short)(r >> 16);
}
__device__ inline float bf2f(unsigned short s) {
    union { unsigned u; float f; } v; v.u = ((unsigned)s) << 16; return v.f;
}
__device__ inline float bfbits_lo(unsigned u) {
    union { unsigned u; float f; } v; v.u = u << 16; return v.f;
}
__device__ inline float bfbits_hi(unsigned u) {
    union { unsigned u; float f; } v; v.u = u & 0xffff0000u; return v.f;
}

__device__ inline void gload16(const void* g, void* l) {
    __builtin_amdgcn_global_load_lds(
        (const __attribute__((address_space(1))) unsigned int*)g,
        (__attribute__((address_space(3))) unsigned int*)l, 16, 0, 0);
}

// ---------------- CSR build ----------------

__global__ void count_kernel(const int* __restrict__ dst, int* __restrict__ deg, int E) {
    for (int e = blockIdx.x * blockDim.x + threadIdx.x; e < E; e += gridDim.x * blockDim.x)
        atomicAdd(&deg[dst[e]], 1);
}

__global__ __launch_bounds__(256) void scan1_kernel(const int* __restrict__ deg,
                                                    int* __restrict__ blocksums, int n) {
    __shared__ int s[256];
    int t = threadIdx.x;
    int i = blockIdx.x * 256 + t;
    s[t] = (i < n) ? deg[i] : 0;
    __syncthreads();
    for (int off = 128; off > 0; off >>= 1) {
        if (t < off) s[t] += s[t + off];
        __syncthreads();
    }
    if (t == 0) blocksums[blockIdx.x] = s[0];
}

__global__ __launch_bounds__(256) void scan2_kernel(const int* __restrict__ blocksums,
                                                    int* __restrict__ blockoff, int nb) {
    __shared__ int s[256];
    int t = threadIdx.x;
    s[t] = (t < nb) ? blocksums[t] : 0;
    __syncthreads();
    for (int off = 1; off < 256; off <<= 1) {
        int u = (t >= off) ? s[t - off] : 0;
        __syncthreads();
        s[t] += u;
        __syncthreads();
    }
    if (t < nb) blockoff[t] = (t == 0) ? 0 : s[t - 1];
}

__global__ __launch_bounds__(256) void scan3_kernel(const int* __restrict__ deg,
                                                    const int* __restrict__ blockoff,
                                                    int* __restrict__ rowptr,
                                                    float* __restrict__ inv_deg,
                                                    int n, int E) {
    __shared__ int s[256];
    int t = threadIdx.x;
    int i = blockIdx.x * 256 + t;
    int v = (i < n) ? deg[i] : 0;
    s[t] = v;
    __syncthreads();
    for (int off = 1; off < 256; off <<= 1) {
        int u = (t >= off) ? s[t - off] : 0;
        __syncthreads();
        s[t] += u;
        __syncthreads();
    }
    if (i < n) {
        rowptr[i] = s[t] - v + blockoff[blockIdx.x];
        inv_deg[i] = 1.0f / (float)(v > 1 ? v : 1);
    }
    if (blockIdx.x == 0 && t == 0) rowptr[n] = E;
}

__global__ void fill_kernel(const int* __restrict__ src, const int* __restrict__ dst,
                            const int* __restrict__ rowptr, int* __restrict__ cnt,
                            int* __restrict__ csr, int E) {
    for (int e = blockIdx.x * blockDim.x + threadIdx.x; e < E; e += gridDim.x * blockDim.x) {
        int d = dst[e];
        int p = rowptr[d] + atomicAdd(&cnt[d], 1);
        csr[p] = src[e];
    }
}

// ---------------- x -> bf16 into Abuf cols 256..511 ----------------
__global__ __launch_bounds__(256) void convert_x(const float* __restrict__ x,
                                                 unsigned short* __restrict__ Abuf,
                                                 int total8) {
    for (int i = blockIdx.x * blockDim.x + threadIdx.x; i < total8;
         i += gridDim.x * blockDim.x) {
        int row = i >> 5;
        int c8 = i & 31;
        const float4* xp = reinterpret_cast<const float4*>(x + (size_t)row * 256 + c8 * 8);
        float4 v0 = xp[0], v1 = xp[1];
        uint4 o;
        o.x = (unsigned)f2bf(v0.x) | ((unsigned)f2bf(v0.y) << 16);
        o.y = (unsigned)f2bf(v0.z) | ((unsigned)f2bf(v0.w) << 16);
        o.z = (unsigned)f2bf(v1.x) | ((unsigned)f2bf(v1.y) << 16);
        o.w = (unsigned)f2bf(v1.z) | ((unsigned)f2bf(v1.w) << 16);
        *reinterpret_cast<uint4*>(Abuf + (size_t)row * 512 + 256 + c8 * 8) = o;
    }
}

// ---------------- weight prep (transposed, bf16) ----------------
__global__ void prep_B1(const float* __restrict__ W1l, const float* __restrict__ W1r,
                        unsigned short* __restrict__ B1t) {
    int idx = blockIdx.x * blockDim.x + threadIdx.x;
    if (idx >= 256 * 512) return;
    int n = idx >> 9, k = idx & 511;
    float v = (k < 256) ? W1l[(size_t)k * 256 + n] : W1r[(size_t)(k - 256) * 256 + n];
    B1t[(size_t)n * 512 + k] = f2bf(v);
}
__global__ void prep_B2(const float* __restrict__ W2l, const float* __restrict__ W2r,
                        unsigned short* __restrict__ B2t) {
    int idx = blockIdx.x * blockDim.x + threadIdx.x;
    if (idx >= 80 * 256) return;
    int n = idx >> 8, k = idx & 255;
    float v = (n < 40) ? W2l[(size_t)k * 40 + n] : W2r[(size_t)k * 40 + (n - 40)];
    B2t[(size_t)n * 256 + k] = f2bf(v);
}

// ---------------- mean aggregation over bf16 features (256-d) ----------------
__global__ __launch_bounds__(256) void aggregate1(
    const unsigned short* __restrict__ Abuf, const int* __restrict__ rowptr,
    const int* __restrict__ csr, const float* __restrict__ inv_deg,
    unsigned short* __restrict__ AbufOut, int N) {
    int node = blockIdx.x * 4 + (threadIdx.x >> 6);
    if (node >= N) return;
    int lane = threadIdx.x & 63;
    float a0 = 0.f, a1 = 0.f, a2 = 0.f, a3 = 0.f;
    int beg = rowptr[node], end = rowptr[node + 1];
    int k = beg;
    for (; k + 8 <= end; k += 8) {
        uint2 v[8];
        #pragma unroll
        for (int u = 0; u < 8; ++u) {
            int j = csr[k + u];
            v[u] = *reinterpret_cast<const uint2*>(Abuf + (size_t)j * 512 + 256 + lane * 4);
        }
        #pragma unroll
        for (int u = 0; u < 8; ++u) {
            a0 += bfbits_lo(v[u].x); a1 += bfbits_hi(v[u].x);
            a2 += bfbits_lo(v[u].y); a3 += bfbits_hi(v[u].y);
        }
    }
    for (; k + 4 <= end; k += 4) {
        uint2 v[4];
        #pragma unroll
        for (int u = 0; u < 4; ++u) {
            int j = csr[k + u];
            v[u] = *reinterpret_cast<const uint2*>(Abuf + (size_t)j * 512 + 256 + lane * 4);
        }
        #pragma unroll
        for (int u = 0; u < 4; ++u) {
            a0 += bfbits_lo(v[u].x); a1 += bfbits_hi(v[u].x);
            a2 += bfbits_lo(v[u].y); a3 += bfbits_hi(v[u].y);
        }
    }
    for (; k < end; ++k) {
        int j = csr[k];
        uint2 v = *reinterpret_cast<const uint2*>(Abuf + (size_t)j * 512 + 256 + lane * 4);
        a0 += bfbits_lo(v.x); a1 += bfbits_hi(v.x);
        a2 += bfbits_lo(v.y); a3 += bfbits_hi(v.y);
    }
    float s = inv_deg[node];
    uint2 w;
    w.x = (unsigned)f2bf(a0 * s) | ((unsigned)f2bf(a1 * s) << 16);
    w.y = (unsigned)f2bf(a2 * s) | ((unsigned)f2bf(a3 * s) << 16);
    *reinterpret_cast<uint2*>(AbufOut + (size_t)node * 512 + lane * 4) = w;
}

// ---------------- GEMM1 (MFMA): h = elu(Abuf @ B1t^T + b1) ----------------
// BM=64, BN=128, BK=64; grid (M_PAD/64, 2) = 1564 blocks; LDS 48 KB -> 3 blk/CU.
// global_load_lds staging, XOR swizzle (16B chunk ^= row&7) both sides.
__global__ __launch_bounds__(256) void gemm1_mfma(
    const unsigned short* __restrict__ Abuf,   // [M_PAD][512]
    const unsigned short* __restrict__ B1t,    // [256][512]
    const float* __restrict__ bias,            // [256]
    unsigned short* __restrict__ H,            // [M_PAD][256] bf16
    int M) {
    __shared__ unsigned short As[2][64 * 64];    // 16 KB
    __shared__ unsigned short Bs[2][128 * 64];   // 32 KB
    int tid = threadIdx.x;
    int row0 = blockIdx.x * 64;
    int bn = blockIdx.y;                 // 0..1
    int wid = tid >> 6, lane = tid & 63;
    int wm = (wid >> 1) * 32;            // 0 / 32
    int wn = (wid & 1) * 64;             // 0 / 64
    int fr = lane & 15, fq = lane >> 4;

    // staging: one gload16 instr covers 8 rows x 128B; lane l -> row +(l>>3),
    // LDS chunk (l&7); global chunk (l&7)^(l>>3)  [swizzle both sides]
    int lrow8 = lane >> 3;               // 0..7
    int gco = ((lane & 7) ^ lrow8) * 8;  // pre-swizzled global elem offset
    const unsigned short* gA0 = Abuf + (size_t)(row0 + wid * 16 + 0 + lrow8) * 512 + gco;
    const unsigned short* gA1 = Abuf + (size_t)(row0 + wid * 16 + 8 + lrow8) * 512 + gco;
    const unsigned short* gB0 = B1t + (size_t)(bn * 128 + wid * 32 + 0  + lrow8) * 512 + gco;
    const unsigned short* gB1 = B1t + (size_t)(bn * 128 + wid * 32 + 8  + lrow8) * 512 + gco;
    const unsigned short* gB2 = B1t + (size_t)(bn * 128 + wid * 32 + 16 + lrow8) * 512 + gco;
    const unsigned short* gB3 = B1t + (size_t)(bn * 128 + wid * 32 + 24 + lrow8) * 512 + gco;

    floatx4 acc[2][4] = {};

    #define STAGE(buf, k0)                                       \
        gload16(gA0 + (k0), &As[buf][(wid * 16 + 0) * 64]);      \
        gload16(gA1 + (k0), &As[buf][(wid * 16 + 8) * 64]);      \
        gload16(gB0 + (k0), &Bs[buf][(wid * 32 + 0) * 64]);      \
        gload16(gB1 + (k0), &Bs[buf][(wid * 32 + 8) * 64]);      \
        gload16(gB2 + (k0), &Bs[buf][(wid * 32 + 16) * 64]);     \
        gload16(gB3 + (k0), &Bs[buf][(wid * 32 + 24) * 64]);

    // frag read: row*64 elems (128B rows); chunk (kc*4+fq)^(fr&7)
    #define COMPUTE(buf)                                                                  \
        {                                                                                 \
            _Pragma("unroll")                                                             \
            for (int kc = 0; kc < 2; ++kc) {                                              \
                short8 af[2], bfr[4];                                                     \
                _Pragma("unroll")                                                         \
                for (int mi = 0; mi < 2; ++mi) {                                          \
                    int row = wm + mi * 16 + fr;                                          \
                    af[mi] = *reinterpret_cast<const short8*>(                            \
                        &As[buf][row * 64 + (((kc * 4 + fq) ^ (fr & 7)) * 8)]);           \
                }                                                                         \
                _Pragma("unroll")                                                         \
                for (int ni = 0; ni < 4; ++ni) {                                          \
                    int row = wn + ni * 16 + fr;                                          \
                    bfr[ni] = *reinterpret_cast<const short8*>(                           \
                        &Bs[buf][row * 64 + (((kc * 4 + fq) ^ (fr & 7)) * 8)]);           \
                }                                                                         \
                _Pragma("unroll")                                                         \
                for (int mi = 0; mi < 2; ++mi)                                            \
                    _Pragma("unroll")                                                     \
                    for (int ni = 0; ni < 4; ++ni)                                        \
                        acc[mi][ni] = __builtin_amdgcn_mfma_f32_16x16x32_bf16(            \
                            af[mi], bfr[ni], acc[mi][ni], 0, 0, 0);                       \
            }                                                                             \
        }

    STAGE(0, 0);
    __syncthreads();
    int cur = 0;
    #pragma unroll 1
    for (int t = 0; t < 7; ++t) {
        STAGE(cur ^ 1, (t + 1) * 64);
        COMPUTE(cur);
        __syncthreads();
        cur ^= 1;
    }
    COMPUTE(cur);
    #undef STAGE
    #undef COMPUTE

    #pragma unroll
    for (int ni = 0; ni < 4; ++ni) {
        int gcol = bn * 128 + wn + ni * 16 + fr;
        float bb = bias[gcol];
        #pragma unroll
        for (int mi = 0; mi < 2; ++mi) {
            #pragma unroll
            for (int r = 0; r < 4; ++r) {
                int grow = row0 + wm + mi * 16 + fq * 4 + r;   // always < M_PAD
                float t = acc[mi][ni][r] + bb;
                t = (t > 0.f) ? t : expm1f(t);
                H[(size_t)grow * 256 + gcol] = f2bf(t);
            }
        }
    }
}

// ---------------- GEMM2 (MFMA): Plb = bf16(H @ W2l'), Pr = H @ W2r' + b2 ----------------
__global__ __launch_bounds__(256) void gemm2_mfma(
    const unsigned short* __restrict__ Hb,
    const unsigned short* __restrict__ B2t,
    const float* __restrict__ b2,
    unsigned short* __restrict__ Plb,   // [N][40] bf16 (aggregated part)
    float* __restrict__ Pr,             // [N][40] fp32 (self part + bias)
    int M) {
    __shared__ unsigned short As[128][40];
    __shared__ unsigned short Bs[80][40];
    int tid = threadIdx.x;
    int row0 = blockIdx.x * 128;
    int wid = tid >> 6, lane = tid & 63;
    int wm = wid * 32;
    int fr = lane & 15, fq = lane >> 4;

    floatx4 acc[2][5] = {};

    int c0 = tid, c1 = tid + 256;
    int r0 = c0 >> 2, ko0 = (c0 & 3) * 8;
    int r1 = c1 >> 2, ko1 = (c1 & 3) * 8;
    int br0 = tid >> 2, bko0 = (tid & 3) * 8;
    int br1 = (tid + 256) >> 2, bko1 = ((tid + 256) & 3) * 8;

    for (int k0 = 0; k0 < 256; k0 += 32) {
        short8 av0 = {}, av1 = {};
        if (row0 + r0 < M)
            av0 = *reinterpret_cast<const short8*>(Hb + (size_t)(row0 + r0) * 256 + k0 + ko0);
        if (row0 + r1 < M)
            av1 = *reinterpret_cast<const short8*>(Hb + (size_t)(row0 + r1) * 256 + k0 + ko1);
        short8 bv0 = {}, bv1 = {};
        if (br0 < 80)
            bv0 = *reinterpret_cast<const short8*>(B2t + (size_t)br0 * 256 + k0 + bko0);
        if (tid < 64)
            bv1 = *reinterpret_cast<const short8*>(B2t + (size_t)br1 * 256 + k0 + bko1);
        __syncthreads();
        *reinterpret_cast<short8*>(&As[r0][ko0]) = av0;
        *reinterpret_cast<short8*>(&As[r1][ko1]) = av1;
        if (br0 < 80) *reinterpret_cast<short8*>(&Bs[br0][bko0]) = bv0;
        if (tid < 64) *reinterpret_cast<short8*>(&Bs[br1][bko1]) = bv1;
        __syncthreads();
        short8 af[2], bf[5];
        #pragma unroll
        for (int mi = 0; mi < 2; ++mi)
            af[mi] = *reinterpret_cast<const short8*>(&As[wm + mi * 16 + fr][fq * 8]);
        #pragma unroll
        for (int ni = 0; ni < 5; ++ni)
            bf[ni] = *reinterpret_cast<const short8*>(&Bs[ni * 16 + fr][fq * 8]);
        #pragma unroll
        for (int mi = 0; mi < 2; ++mi)
            #pragma unroll
            for (int ni = 0; ni < 5; ++ni)
                acc[mi][ni] = __builtin_amdgcn_mfma_f32_16x16x32_bf16(af[mi], bf[ni], acc[mi][ni], 0, 0, 0);
        __syncthreads();
    }
    #pragma unroll
    for (int mi = 0; mi < 2; ++mi) {
        #pragma unroll
        for (int r = 0; r < 4; ++r) {
            int grow = row0 + wm + mi * 16 + fq * 4 + r;
            if (grow < M) {
                #pragma unroll
                for (int ni = 0; ni < 5; ++ni) {
                    int col = ni * 16 + fr;
                    float v = acc[mi][ni][r];
                    if (col < 40)
                        Plb[(size_t)grow * 40 + col] = f2bf(v);
                    else
                        Pr[(size_t)grow * 40 + (col - 40)] = v + b2[col - 40];
                }
            }
        }
    }
}

// ---------------- final: out = mean_agg(Plb) + Pr ----------------
__global__ __launch_bounds__(256) void final_kernel(
    const unsigned short* __restrict__ Plb, const float* __restrict__ Pr,
    const int* __restrict__ rowptr, const int* __restrict__ csr,
    const float* __restrict__ inv_deg, float* __restrict__ out, int N) {
    int node = blockIdx.x * 4 + (threadIdx.x >> 6);
    if (node >= N) return;
    int lane = threadIdx.x & 63;
    if (lane >= 40) return;
    float sum = 0.f;
    int beg = rowptr[node], end = rowptr[node + 1];
    int k = beg;
    for (; k + 4 <= end; k += 4) {
        int j0 = csr[k], j1 = csr[k + 1], j2 = csr[k + 2], j3 = csr[k + 3];
        float s0 = bf2f(Plb[(size_t)j0 * 40 + lane]);
        float s1 = bf2f(Plb[(size_t)j1 * 40 + lane]);
        float s2 = bf2f(Plb[(size_t)j2 * 40 + lane]);
        float s3 = bf2f(Plb[(size_t)j3 * 40 + lane]);
        sum += (s0 + s1) + (s2 + s3);
    }
    for (; k < end; ++k)
        sum += bf2f(Plb[(size_t)csr[k] * 40 + lane]);
    out[(size_t)node * 40 + lane] = sum * inv_deg[node] + Pr[(size_t)node * 40 + lane];
}

// ---------------- launcher ----------------

extern "C" void kernel_launch(void* const* d_in, const int* in_sizes, int n_in,
                              void* d_out, int out_size, void* d_ws, size_t ws_size,
                              hipStream_t stream) {
    const float* x   = (const float*)d_in[0];
    const int*   ei  = (const int*)d_in[1];
    const float* W1l = (const float*)d_in[2];
    const float* b1  = (const float*)d_in[3];
    const float* W1r = (const float*)d_in[4];
    const float* W2l = (const float*)d_in[5];
    const float* b2  = (const float*)d_in[6];
    const float* W2r = (const float*)d_in[7];
    const float* Q   = (const float*)d_in[8];
    const int E = in_sizes[1] / 2;
    const int N = N_NODES;
    const int* src = ei;
    const int* dst = ei + E;
    const int NB = (N + 255) / 256;

    unsigned short* Abuf = (unsigned short*)d_ws;            // [M_PAD][512] bf16
    unsigned short* h    = Abuf + (size_t)M_PAD * 512;       // [M_PAD][256] bf16
    unsigned short* B1t  = h + (size_t)M_PAD * 256;          // [256][512]
    unsigned short* B2t  = B1t + 256 * 512;                  // [80][256]
    unsigned short* Plb  = B2t + 80 * 256;                   // [N][40] bf16
    float* Pr      = (float*)(Plb + (size_t)N * 40 + 32);    // [N][40] fp32
    float* inv_deg = Pr + (size_t)N * 40;                    // N
    int*   deg     = (int*)(inv_deg + N);                    // N
    int*   cnt     = deg + N;                                // N
    int*   rowptr  = cnt + N;                                // N+1
    int*   blocksums = rowptr + N + 1;                       // NB
    int*   blockoff  = blocksums + NB;                       // NB
    int*   csr     = blockoff + NB;                          // E

    float* out = (float*)d_out;

    hipMemsetAsync(deg, 0, sizeof(int) * 2 * (size_t)N, stream);
    count_kernel<<<1024, 256, 0, stream>>>(dst, deg, E);
    scan1_kernel<<<NB, 256, 0, stream>>>(deg, blocksums, N);
    scan2_kernel<<<1, 256, 0, stream>>>(blocksums, blockoff, NB);
    scan3_kernel<<<NB, 256, 0, stream>>>(deg, blockoff, rowptr, inv_deg, N, E);
    fill_kernel<<<1024, 256, 0, stream>>>(src, dst, rowptr, cnt, csr, E);

    convert_x<<<2048, 256, 0, stream>>>(x, Abuf, N * 32);
    prep_B1<<<(256 * 512 + 255) / 256, 256, 0, stream>>>(W1l, W1r, B1t);
    prep_B2<<<(80 * 256 + 255) / 256, 256, 0, stream>>>(W2l, W2r, B2t);

    aggregate1<<<(N + 3) / 4, 256, 0, stream>>>(Abuf, rowptr, csr, inv_deg, Abuf, N);
    gemm1_mfma<<<dim3(M_PAD / 64, 2), 256, 0, stream>>>(Abuf, B1t, b1, h, N);
    gemm2_mfma<<<M_PAD / 128, 256, 0, stream>>>(h, B2t, b2, Plb, Pr, N);
    final_kernel<<<(N + 3) / 4, 256, 0, stream>>>(Plb, Pr, rowptr, csr, inv_deg, out, N);

    hipMemcpyAsync(out + (size_t)N * 40, Q, sizeof(float) * (size_t)in_sizes[8],
                   hipMemcpyDeviceToDevice, stream);
}

// Round 7
// 259.610 us; speedup vs baseline: 2.8276x; 1.0698x over previous
//
#include <hip/hip_runtime.h>
#include <hip/hip_bf16.h>
#include <cstddef>

#define N_NODES 50000
#define M_PAD 50048   // multiple of 128 and 64

typedef __attribute__((ext_vector_type(8))) short short8;
typedef __attribute__((ext_vector_type(4))) float floatx4;

__device__ inline unsigned short f2bf(float f) {
    union { float f; unsigned u; } v; v.f = f;
    unsigned r = v.u + 0x7fff + ((v.u >> 16) & 1);
    return (unsigned short)(r >> 16);
}
__device__ inline float bf2f(unsigned short s) {
    union { unsigned u; float f; } v; v.u = ((unsigned)s) << 16; return v.f;
}
__device__ inline float bfbits_lo(unsigned u) {
    union { unsigned u; float f; } v; v.u = u << 16; return v.f;
}
__device__ inline float bfbits_hi(unsigned u) {
    union { unsigned u; float f; } v; v.u = u & 0xffff0000u; return v.f;
}

__device__ inline void gload16(const void* g, void* l) {
    __builtin_amdgcn_global_load_lds(
        (const __attribute__((address_space(1))) unsigned int*)g,
        (__attribute__((address_space(3))) unsigned int*)l, 16, 0, 0);
}

// ---------------- CSR build ----------------

__global__ void count_kernel(const int* __restrict__ dst, int* __restrict__ deg, int E) {
    for (int e = blockIdx.x * blockDim.x + threadIdx.x; e < E; e += gridDim.x * blockDim.x)
        atomicAdd(&deg[dst[e]], 1);
}

__global__ __launch_bounds__(256) void scan1_kernel(const int* __restrict__ deg,
                                                    int* __restrict__ blocksums, int n) {
    __shared__ int s[256];
    int t = threadIdx.x;
    int i = blockIdx.x * 256 + t;
    s[t] = (i < n) ? deg[i] : 0;
    __syncthreads();
    for (int off = 128; off > 0; off >>= 1) {
        if (t < off) s[t] += s[t + off];
        __syncthreads();
    }
    if (t == 0) blocksums[blockIdx.x] = s[0];
}

__global__ __launch_bounds__(256) void scan2_kernel(const int* __restrict__ blocksums,
                                                    int* __restrict__ blockoff, int nb) {
    __shared__ int s[256];
    int t = threadIdx.x;
    s[t] = (t < nb) ? blocksums[t] : 0;
    __syncthreads();
    for (int off = 1; off < 256; off <<= 1) {
        int u = (t >= off) ? s[t - off] : 0;
        __syncthreads();
        s[t] += u;
        __syncthreads();
    }
    if (t < nb) blockoff[t] = (t == 0) ? 0 : s[t - 1];
}

__global__ __launch_bounds__(256) void scan3_kernel(const int* __restrict__ deg,
                                                    const int* __restrict__ blockoff,
                                                    int* __restrict__ rowptr,
                                                    float* __restrict__ inv_deg,
                                                    int n, int E) {
    __shared__ int s[256];
    int t = threadIdx.x;
    int i = blockIdx.x * 256 + t;
    int v = (i < n) ? deg[i] : 0;
    s[t] = v;
    __syncthreads();
    for (int off = 1; off < 256; off <<= 1) {
        int u = (t >= off) ? s[t - off] : 0;
        __syncthreads();
        s[t] += u;
        __syncthreads();
    }
    if (i < n) {
        rowptr[i] = s[t] - v + blockoff[blockIdx.x];
        inv_deg[i] = 1.0f / (float)(v > 1 ? v : 1);
    }
    if (blockIdx.x == 0 && t == 0) rowptr[n] = E;
}

__global__ void fill_kernel(const int* __restrict__ src, const int* __restrict__ dst,
                            const int* __restrict__ rowptr, int* __restrict__ cnt,
                            int* __restrict__ csr, int E) {
    for (int e = blockIdx.x * blockDim.x + threadIdx.x; e < E; e += gridDim.x * blockDim.x) {
        int d = dst[e];
        int p = rowptr[d] + atomicAdd(&cnt[d], 1);
        csr[p] = src[e];
    }
}

// ---------------- fused prep: x->bf16 (Abuf cols 256..511), B1t, B2t ----------------
// grid = 6250 (convert) + 512 (B1) + 80 (B2) = 6842 blocks
__global__ __launch_bounds__(256) void prep_kernel(
    const float* __restrict__ x,
    const float* __restrict__ W1l, const float* __restrict__ W1r,
    const float* __restrict__ W2l, const float* __restrict__ W2r,
    unsigned short* __restrict__ Abuf, unsigned short* __restrict__ B1t,
    unsigned short* __restrict__ B2t) {
    int b = blockIdx.x;
    int tid = threadIdx.x;
    if (b < 6250) {
        int i = b * 256 + tid;             // < 1,600,000 exactly
        int row = i >> 5;
        int c8 = i & 31;
        const float4* xp = reinterpret_cast<const float4*>(x + (size_t)row * 256 + c8 * 8);
        float4 v0 = xp[0], v1 = xp[1];
        uint4 o;
        o.x = (unsigned)f2bf(v0.x) | ((unsigned)f2bf(v0.y) << 16);
        o.y = (unsigned)f2bf(v0.z) | ((unsigned)f2bf(v0.w) << 16);
        o.z = (unsigned)f2bf(v1.x) | ((unsigned)f2bf(v1.y) << 16);
        o.w = (unsigned)f2bf(v1.z) | ((unsigned)f2bf(v1.w) << 16);
        *reinterpret_cast<uint4*>(Abuf + (size_t)row * 512 + 256 + c8 * 8) = o;
    } else if (b < 6250 + 512) {
        int idx = (b - 6250) * 256 + tid;  // < 131072 exactly
        int n = idx >> 9, k = idx & 511;
        float v = (k < 256) ? W1l[(size_t)k * 256 + n] : W1r[(size_t)(k - 256) * 256 + n];
        B1t[(size_t)n * 512 + k] = f2bf(v);
    } else {
        int idx = (b - 6250 - 512) * 256 + tid;  // < 20480 exactly
        int n = idx >> 8, k = idx & 255;
        float v = (n < 40) ? W2l[(size_t)k * 40 + n] : W2r[(size_t)k * 40 + (n - 40)];
        B2t[(size_t)n * 256 + k] = f2bf(v);
    }
}

// ---------------- mean aggregation (256-d) + fused Q-copy ----------------
// agg section: half-wave (32 lanes) per node, lane loads uint4 (8 bf16).
// Q section: grid-stride float4 copy into out[N*40 ..].
__global__ __launch_bounds__(256) void aggregate1_q(
    const unsigned short* __restrict__ Abuf, const int* __restrict__ rowptr,
    const int* __restrict__ csr, const float* __restrict__ inv_deg,
    unsigned short* __restrict__ AbufOut, int N, int nAggBlocks,
    const float4* __restrict__ Qsrc, float4* __restrict__ Qdst, int nQ4) {
    if ((int)blockIdx.x >= nAggBlocks) {
        int idx = (blockIdx.x - nAggBlocks) * 256 + threadIdx.x;
        int stride = (gridDim.x - nAggBlocks) * 256;
        for (int i = idx; i < nQ4; i += stride) Qdst[i] = Qsrc[i];
        return;
    }
    int wv = blockIdx.x * 4 + (threadIdx.x >> 6);
    int node = wv * 2 + ((threadIdx.x >> 5) & 1);
    if (node >= N) return;
    int lane = threadIdx.x & 31;
    float a0 = 0.f, a1 = 0.f, a2 = 0.f, a3 = 0.f;
    float a4 = 0.f, a5 = 0.f, a6 = 0.f, a7 = 0.f;
    int beg = rowptr[node], end = rowptr[node + 1];
    int k = beg;
    for (; k + 4 <= end; k += 4) {
        uint4 v[4];
        #pragma unroll
        for (int u = 0; u < 4; ++u) {
            int j = csr[k + u];
            v[u] = *reinterpret_cast<const uint4*>(Abuf + (size_t)j * 512 + 256 + lane * 8);
        }
        #pragma unroll
        for (int u = 0; u < 4; ++u) {
            a0 += bfbits_lo(v[u].x); a1 += bfbits_hi(v[u].x);
            a2 += bfbits_lo(v[u].y); a3 += bfbits_hi(v[u].y);
            a4 += bfbits_lo(v[u].z); a5 += bfbits_hi(v[u].z);
            a6 += bfbits_lo(v[u].w); a7 += bfbits_hi(v[u].w);
        }
    }
    for (; k < end; ++k) {
        int j = csr[k];
        uint4 v = *reinterpret_cast<const uint4*>(Abuf + (size_t)j * 512 + 256 + lane * 8);
        a0 += bfbits_lo(v.x); a1 += bfbits_hi(v.x);
        a2 += bfbits_lo(v.y); a3 += bfbits_hi(v.y);
        a4 += bfbits_lo(v.z); a5 += bfbits_hi(v.z);
        a6 += bfbits_lo(v.w); a7 += bfbits_hi(v.w);
    }
    float s = inv_deg[node];
    uint4 w;
    w.x = (unsigned)f2bf(a0 * s) | ((unsigned)f2bf(a1 * s) << 16);
    w.y = (unsigned)f2bf(a2 * s) | ((unsigned)f2bf(a3 * s) << 16);
    w.z = (unsigned)f2bf(a4 * s) | ((unsigned)f2bf(a5 * s) << 16);
    w.w = (unsigned)f2bf(a6 * s) | ((unsigned)f2bf(a7 * s) << 16);
    *reinterpret_cast<uint4*>(AbufOut + (size_t)node * 512 + lane * 8) = w;
}

// ---------------- GEMM1 (MFMA): h = elu(Abuf @ B1t^T + b1) ----------------
// BM=64, BN=128, BK=64; grid (M_PAD/64, 2); LDS 48 KB -> 3 blk/CU.
__global__ __launch_bounds__(256) void gemm1_mfma(
    const unsigned short* __restrict__ Abuf,   // [M_PAD][512]
    const unsigned short* __restrict__ B1t,    // [256][512]
    const float* __restrict__ bias,            // [256]
    unsigned short* __restrict__ H,            // [M_PAD][256] bf16
    int M) {
    __shared__ unsigned short As[2][64 * 64];    // 16 KB
    __shared__ unsigned short Bs[2][128 * 64];   // 32 KB
    int tid = threadIdx.x;
    int row0 = blockIdx.x * 64;
    int bn = blockIdx.y;                 // 0..1
    int wid = tid >> 6, lane = tid & 63;
    int wm = (wid >> 1) * 32;            // 0 / 32
    int wn = (wid & 1) * 64;             // 0 / 64
    int fr = lane & 15, fq = lane >> 4;

    int lrow8 = lane >> 3;               // 0..7
    int gco = ((lane & 7) ^ lrow8) * 8;  // pre-swizzled global elem offset
    const unsigned short* gA0 = Abuf + (size_t)(row0 + wid * 16 + 0 + lrow8) * 512 + gco;
    const unsigned short* gA1 = Abuf + (size_t)(row0 + wid * 16 + 8 + lrow8) * 512 + gco;
    const unsigned short* gB0 = B1t + (size_t)(bn * 128 + wid * 32 + 0  + lrow8) * 512 + gco;
    const unsigned short* gB1 = B1t + (size_t)(bn * 128 + wid * 32 + 8  + lrow8) * 512 + gco;
    const unsigned short* gB2 = B1t + (size_t)(bn * 128 + wid * 32 + 16 + lrow8) * 512 + gco;
    const unsigned short* gB3 = B1t + (size_t)(bn * 128 + wid * 32 + 24 + lrow8) * 512 + gco;

    floatx4 acc[2][4] = {};

    #define STAGE(buf, k0)                                       \
        gload16(gA0 + (k0), &As[buf][(wid * 16 + 0) * 64]);      \
        gload16(gA1 + (k0), &As[buf][(wid * 16 + 8) * 64]);      \
        gload16(gB0 + (k0), &Bs[buf][(wid * 32 + 0) * 64]);      \
        gload16(gB1 + (k0), &Bs[buf][(wid * 32 + 8) * 64]);      \
        gload16(gB2 + (k0), &Bs[buf][(wid * 32 + 16) * 64]);     \
        gload16(gB3 + (k0), &Bs[buf][(wid * 32 + 24) * 64]);

    #define COMPUTE(buf)                                                                  \
        {                                                                                 \
            _Pragma("unroll")                                                             \
            for (int kc = 0; kc < 2; ++kc) {                                              \
                short8 af[2], bfr[4];                                                     \
                _Pragma("unroll")                                                         \
                for (int mi = 0; mi < 2; ++mi) {                                          \
                    int row = wm + mi * 16 + fr;                                          \
                    af[mi] = *reinterpret_cast<const short8*>(                            \
                        &As[buf][row * 64 + (((kc * 4 + fq) ^ (fr & 7)) * 8)]);           \
                }                                                                         \
                _Pragma("unroll")                                                         \
                for (int ni = 0; ni < 4; ++ni) {                                          \
                    int row = wn + ni * 16 + fr;                                          \
                    bfr[ni] = *reinterpret_cast<const short8*>(                           \
                        &Bs[buf][row * 64 + (((kc * 4 + fq) ^ (fr & 7)) * 8)]);           \
                }                                                                         \
                _Pragma("unroll")                                                         \
                for (int mi = 0; mi < 2; ++mi)                                            \
                    _Pragma("unroll")                                                     \
                    for (int ni = 0; ni < 4; ++ni)                                        \
                        acc[mi][ni] = __builtin_amdgcn_mfma_f32_16x16x32_bf16(            \
                            af[mi], bfr[ni], acc[mi][ni], 0, 0, 0);                       \
            }                                                                             \
        }

    STAGE(0, 0);
    __syncthreads();
    int cur = 0;
    #pragma unroll 1
    for (int t = 0; t < 7; ++t) {
        STAGE(cur ^ 1, (t + 1) * 64);
        COMPUTE(cur);
        __syncthreads();
        cur ^= 1;
    }
    COMPUTE(cur);
    #undef STAGE
    #undef COMPUTE

    #pragma unroll
    for (int ni = 0; ni < 4; ++ni) {
        int gcol = bn * 128 + wn + ni * 16 + fr;
        float bb = bias[gcol];
        #pragma unroll
        for (int mi = 0; mi < 2; ++mi) {
            #pragma unroll
            for (int r = 0; r < 4; ++r) {
                int grow = row0 + wm + mi * 16 + fq * 4 + r;   // < M_PAD
                float t = acc[mi][ni][r] + bb;
                t = (t > 0.f) ? t : expm1f(t);
                H[(size_t)grow * 256 + gcol] = f2bf(t);
            }
        }
    }
}

// ---------------- GEMM2 (MFMA): Plb = bf16(H @ W2l'), Pr = H @ W2r' + b2 ----------------
// B2t (80x256, 40 KB) resident in LDS (XOR-swizzled); A staged via gload16 dbuf.
// BM=64, BK=64, 4 K-steps; wave does 16 rows x 80 cols.
__global__ __launch_bounds__(256) void gemm2_mfma(
    const unsigned short* __restrict__ Hb,   // [M_PAD][256]
    const unsigned short* __restrict__ B2t,  // [80][256]
    const float* __restrict__ b2,
    unsigned short* __restrict__ Plb,        // [N][40] bf16
    float* __restrict__ Pr,                  // [N][40] fp32
    int M) {
    __shared__ unsigned short Bsm[80 * 256];   // 40 KB
    __shared__ unsigned short As[2][64 * 64];  // 16 KB
    int tid = threadIdx.x;
    int row0 = blockIdx.x * 64;
    int wid = tid >> 6, lane = tid & 63;
    int wm = wid * 16;
    int fr = lane & 15, fq = lane >> 4;

    // fill B once: 2560 chunks of 8 elems, swizzle chunk ^= (n&7)
    for (int c = tid; c < 2560; c += 256) {
        int n = c >> 5, ci = c & 31;
        short8 v = *reinterpret_cast<const short8*>(B2t + (size_t)n * 256 + ci * 8);
        *reinterpret_cast<short8*>(&Bsm[n * 256 + ((ci ^ (n & 7)) * 8)]) = v;
    }

    int lrow8 = lane >> 3;
    int gco = ((lane & 7) ^ lrow8) * 8;
    const unsigned short* gA0 = Hb + (size_t)(row0 + wid * 16 + 0 + lrow8) * 256 + gco;
    const unsigned short* gA1 = Hb + (size_t)(row0 + wid * 16 + 8 + lrow8) * 256 + gco;

    floatx4 acc[5] = {};

    #define STAGE2(buf, k0)                                      \
        gload16(gA0 + (k0), &As[buf][(wid * 16 + 0) * 64]);      \
        gload16(gA1 + (k0), &As[buf][(wid * 16 + 8) * 64]);

    #define COMPUTE2(buf, k0)                                                             \
        {                                                                                 \
            _Pragma("unroll")                                                             \
            for (int kc = 0; kc < 2; ++kc) {                                              \
                short8 af;                                                                \
                {                                                                         \
                    int row = wm + fr;                                                    \
                    af = *reinterpret_cast<const short8*>(                                \
                        &As[buf][row * 64 + (((kc * 4 + fq) ^ (fr & 7)) * 8)]);           \
                }                                                                         \
                _Pragma("unroll")                                                         \
                for (int ni = 0; ni < 5; ++ni) {                                          \
                    int n = ni * 16 + fr;                                                 \
                    int c = ((k0) >> 3) + kc * 4 + fq;                                    \
                    short8 bfr = *reinterpret_cast<const short8*>(                        \
                        &Bsm[n * 256 + ((c ^ (n & 7)) * 8)]);                             \
                    acc[ni] = __builtin_amdgcn_mfma_f32_16x16x32_bf16(                    \
                        af, bfr, acc[ni], 0, 0, 0);                                       \
                }                                                                         \
            }                                                                             \
        }

    STAGE2(0, 0);
    __syncthreads();    // covers B-fill ds_writes and first A gload
    int cur = 0;
    #pragma unroll 1
    for (int t = 0; t < 3; ++t) {
        STAGE2(cur ^ 1, (t + 1) * 64);
        COMPUTE2(cur, t * 64);
        __syncthreads();
        cur ^= 1;
    }
    COMPUTE2(cur, 192);
    #undef STAGE2
    #undef COMPUTE2

    #pragma unroll
    for (int r = 0; r < 4; ++r) {
        int grow = row0 + wm + fq * 4 + r;
        if (grow < M) {
            #pragma unroll
            for (int ni = 0; ni < 5; ++ni) {
                int col = ni * 16 + fr;
                float v = acc[ni][r];
                if (col < 40)
                    Plb[(size_t)grow * 40 + col] = f2bf(v);
                else
                    Pr[(size_t)grow * 40 + (col - 40)] = v + b2[col - 40];
            }
        }
    }
}

// ---------------- final: out = mean_agg(Plb) + Pr ----------------
// half-wave per node; lanes 0..19 each handle 2 cols via uint gather
__global__ __launch_bounds__(256) void final_kernel(
    const unsigned short* __restrict__ Plb, const float* __restrict__ Pr,
    const int* __restrict__ rowptr, const int* __restrict__ csr,
    const float* __restrict__ inv_deg, float* __restrict__ out, int N) {
    int wv = blockIdx.x * 4 + (threadIdx.x >> 6);
    int node = wv * 2 + ((threadIdx.x >> 5) & 1);
    if (node >= N) return;
    int lane = threadIdx.x & 31;
    if (lane >= 20) return;
    float s0 = 0.f, s1 = 0.f;
    int beg = rowptr[node], end = rowptr[node + 1];
    int k = beg;
    for (; k + 4 <= end; k += 4) {
        unsigned v0 = *reinterpret_cast<const unsigned*>(Plb + (size_t)csr[k]     * 40 + lane * 2);
        unsigned v1 = *reinterpret_cast<const unsigned*>(Plb + (size_t)csr[k + 1] * 40 + lane * 2);
        unsigned v2 = *reinterpret_cast<const unsigned*>(Plb + (size_t)csr[k + 2] * 40 + lane * 2);
        unsigned v3 = *reinterpret_cast<const unsigned*>(Plb + (size_t)csr[k + 3] * 40 + lane * 2);
        s0 += bfbits_lo(v0) + bfbits_lo(v1) + bfbits_lo(v2) + bfbits_lo(v3);
        s1 += bfbits_hi(v0) + bfbits_hi(v1) + bfbits_hi(v2) + bfbits_hi(v3);
    }
    for (; k < end; ++k) {
        unsigned v = *reinterpret_cast<const unsigned*>(Plb + (size_t)csr[k] * 40 + lane * 2);
        s0 += bfbits_lo(v);
        s1 += bfbits_hi(v);
    }
    float inv = inv_deg[node];
    float2 pr = *reinterpret_cast<const float2*>(Pr + (size_t)node * 40 + lane * 2);
    float2 o;
    o.x = s0 * inv + pr.x;
    o.y = s1 * inv + pr.y;
    *reinterpret_cast<float2*>(out + (size_t)node * 40 + lane * 2) = o;
}

// ---------------- launcher ----------------

extern "C" void kernel_launch(void* const* d_in, const int* in_sizes, int n_in,
                              void* d_out, int out_size, void* d_ws, size_t ws_size,
                              hipStream_t stream) {
    const float* x   = (const float*)d_in[0];
    const int*   ei  = (const int*)d_in[1];
    const float* W1l = (const float*)d_in[2];
    const float* b1  = (const float*)d_in[3];
    const float* W1r = (const float*)d_in[4];
    const float* W2l = (const float*)d_in[5];
    const float* b2  = (const float*)d_in[6];
    const float* W2r = (const float*)d_in[7];
    const float* Q   = (const float*)d_in[8];
    const int E = in_sizes[1] / 2;
    const int N = N_NODES;
    const int* src = ei;
    const int* dst = ei + E;
    const int NB = (N + 255) / 256;

    unsigned short* Abuf = (unsigned short*)d_ws;            // [M_PAD][512] bf16
    unsigned short* h    = Abuf + (size_t)M_PAD * 512;       // [M_PAD][256] bf16
    unsigned short* B1t  = h + (size_t)M_PAD * 256;          // [256][512]
    unsigned short* B2t  = B1t + 256 * 512;                  // [80][256]
    unsigned short* Plb  = B2t + 80 * 256;                   // [N][40] bf16
    float* Pr      = (float*)(Plb + (size_t)N * 40 + 32);    // [N][40] fp32
    float* inv_deg = Pr + (size_t)N * 40;                    // N
    int*   deg     = (int*)(inv_deg + N);                    // N
    int*   cnt     = deg + N;                                // N
    int*   rowptr  = cnt + N;                                // N+1
    int*   blocksums = rowptr + N + 1;                       // NB
    int*   blockoff  = blocksums + NB;                       // NB
    int*   csr     = blockoff + NB;                          // E

    float* out = (float*)d_out;

    hipMemsetAsync(deg, 0, sizeof(int) * 2 * (size_t)N, stream);
    count_kernel<<<1024, 256, 0, stream>>>(dst, deg, E);
    scan1_kernel<<<NB, 256, 0, stream>>>(deg, blocksums, N);
    scan2_kernel<<<1, 256, 0, stream>>>(blocksums, blockoff, NB);
    scan3_kernel<<<NB, 256, 0, stream>>>(deg, blockoff, rowptr, inv_deg, N, E);
    fill_kernel<<<1024, 256, 0, stream>>>(src, dst, rowptr, cnt, csr, E);

    prep_kernel<<<6250 + 512 + 80, 256, 0, stream>>>(x, W1l, W1r, W2l, W2r,
                                                     Abuf, B1t, B2t);

    // aggregate (6250 blocks) + fused Q-copy (2048 grid-stride blocks)
    const int nAggBlocks = (N + 7) / 8;          // 6250
    const int nQ4 = in_sizes[8] / 4;             // 4,000,000 float4
    aggregate1_q<<<nAggBlocks + 2048, 256, 0, stream>>>(
        Abuf, rowptr, csr, inv_deg, Abuf, N, nAggBlocks,
        (const float4*)Q, (float4*)(out + (size_t)N * 40), nQ4);

    gemm1_mfma<<<dim3(M_PAD / 64, 2), 256, 0, stream>>>(Abuf, B1t, b1, h, N);
    gemm2_mfma<<<M_PAD / 64, 256, 0, stream>>>(h, B2t, b2, Plb, Pr, N);
    final_kernel<<<(N + 7) / 8, 256, 0, stream>>>(Plb, Pr, rowptr, csr, inv_deg, out, N);
}

// Round 8
// 255.682 us; speedup vs baseline: 2.8710x; 1.0154x over previous
//
#include <hip/hip_runtime.h>
#include <hip/hip_bf16.h>
#include <cstddef>

#define N_NODES 50000
#define M_PAD 50048   // multiple of 128 and 64

typedef __attribute__((ext_vector_type(8))) short short8;
typedef __attribute__((ext_vector_type(4))) float floatx4;

__device__ inline unsigned short f2bf(float f) {
    union { float f; unsigned u; } v; v.f = f;
    unsigned r = v.u + 0x7fff + ((v.u >> 16) & 1);
    return (unsigned short)(r >> 16);
}
__device__ inline float bfbits_lo(unsigned u) {
    union { unsigned u; float f; } v; v.u = u << 16; return v.f;
}
__device__ inline float bfbits_hi(unsigned u) {
    union { unsigned u; float f; } v; v.u = u & 0xffff0000u; return v.f;
}

__device__ inline void gload16(const void* g, void* l) {
    __builtin_amdgcn_global_load_lds(
        (const __attribute__((address_space(1))) unsigned int*)g,
        (__attribute__((address_space(3))) unsigned int*)l, 16, 0, 0);
}

// ---------------- fused prep (x->bf16, B1t, B2t) + degree count ----------------
// blocks: [0,6250) convert, [6250,6762) B1t, [6762,6842) B2t, [6842,7866) count
__global__ __launch_bounds__(256) void prep_count(
    const float* __restrict__ x,
    const float* __restrict__ W1l, const float* __restrict__ W1r,
    const float* __restrict__ W2l, const float* __restrict__ W2r,
    unsigned short* __restrict__ Abuf, unsigned short* __restrict__ B1t,
    unsigned short* __restrict__ B2t,
    const int* __restrict__ dst, int* __restrict__ deg, int E) {
    int b = blockIdx.x;
    int tid = threadIdx.x;
    if (b < 6250) {
        int i = b * 256 + tid;             // < 1,600,000 exactly
        int row = i >> 5;
        int c8 = i & 31;
        const float4* xp = reinterpret_cast<const float4*>(x + (size_t)row * 256 + c8 * 8);
        float4 v0 = xp[0], v1 = xp[1];
        uint4 o;
        o.x = (unsigned)f2bf(v0.x) | ((unsigned)f2bf(v0.y) << 16);
        o.y = (unsigned)f2bf(v0.z) | ((unsigned)f2bf(v0.w) << 16);
        o.z = (unsigned)f2bf(v1.x) | ((unsigned)f2bf(v1.y) << 16);
        o.w = (unsigned)f2bf(v1.z) | ((unsigned)f2bf(v1.w) << 16);
        *reinterpret_cast<uint4*>(Abuf + (size_t)row * 512 + 256 + c8 * 8) = o;
    } else if (b < 6250 + 512) {
        int idx = (b - 6250) * 256 + tid;  // < 131072 exactly
        int n = idx >> 9, k = idx & 511;
        float v = (k < 256) ? W1l[(size_t)k * 256 + n] : W1r[(size_t)(k - 256) * 256 + n];
        B1t[(size_t)n * 512 + k] = f2bf(v);
    } else if (b < 6842) {
        int idx = (b - 6762) * 256 + tid;  // < 20480 exactly
        int n = idx >> 8, k = idx & 255;
        float v = (n < 40) ? W2l[(size_t)k * 40 + n] : W2r[(size_t)k * 40 + (n - 40)];
        B2t[(size_t)n * 256 + k] = f2bf(v);
    } else {
        int base = (b - 6842) * 256 + tid;
        for (int e = base; e < E; e += 1024 * 256)
            atomicAdd(&deg[dst[e]], 1);
    }
}

__global__ __launch_bounds__(256) void scan1_kernel(const int* __restrict__ deg,
                                                    int* __restrict__ blocksums, int n) {
    __shared__ int s[256];
    int t = threadIdx.x;
    int i = blockIdx.x * 256 + t;
    s[t] = (i < n) ? deg[i] : 0;
    __syncthreads();
    for (int off = 128; off > 0; off >>= 1) {
        if (t < off) s[t] += s[t + off];
        __syncthreads();
    }
    if (t == 0) blocksums[blockIdx.x] = s[0];
}

__global__ __launch_bounds__(256) void scan2_kernel(const int* __restrict__ blocksums,
                                                    int* __restrict__ blockoff, int nb) {
    __shared__ int s[256];
    int t = threadIdx.x;
    s[t] = (t < nb) ? blocksums[t] : 0;
    __syncthreads();
    for (int off = 1; off < 256; off <<= 1) {
        int u = (t >= off) ? s[t - off] : 0;
        __syncthreads();
        s[t] += u;
        __syncthreads();
    }
    if (t < nb) blockoff[t] = (t == 0) ? 0 : s[t - 1];
}

__global__ __launch_bounds__(256) void scan3_kernel(const int* __restrict__ deg,
                                                    const int* __restrict__ blockoff,
                                                    int* __restrict__ rowptr,
                                                    float* __restrict__ inv_deg,
                                                    int n, int E) {
    __shared__ int s[256];
    int t = threadIdx.x;
    int i = blockIdx.x * 256 + t;
    int v = (i < n) ? deg[i] : 0;
    s[t] = v;
    __syncthreads();
    for (int off = 1; off < 256; off <<= 1) {
        int u = (t >= off) ? s[t - off] : 0;
        __syncthreads();
        s[t] += u;
        __syncthreads();
    }
    if (i < n) {
        rowptr[i] = s[t] - v + blockoff[blockIdx.x];
        inv_deg[i] = 1.0f / (float)(v > 1 ? v : 1);
    }
    if (blockIdx.x == 0 && t == 0) rowptr[n] = E;
}

// ---------------- fill CSR + fused Q-copy ----------------
// blocks [0,1024): fill; [1024,2048): Q float4 copy
__global__ void fill_q(const int* __restrict__ src, const int* __restrict__ dst,
                       const int* __restrict__ rowptr, int* __restrict__ cnt,
                       int* __restrict__ csr, int E,
                       const float4* __restrict__ Qsrc, float4* __restrict__ Qdst,
                       int nQ4) {
    if ((int)blockIdx.x >= 1024) {
        int idx = (blockIdx.x - 1024) * 256 + threadIdx.x;
        for (int i = idx; i < nQ4; i += 1024 * 256) Qdst[i] = Qsrc[i];
        return;
    }
    for (int e = blockIdx.x * blockDim.x + threadIdx.x; e < E; e += 1024 * 256) {
        int d = dst[e];
        int p = rowptr[d] + atomicAdd(&cnt[d], 1);
        csr[p] = src[e];
    }
}

// ---------------- mean aggregation (256-d): wave/node, 2 edges/iter ----------------
__global__ __launch_bounds__(256) void aggregate1(
    const unsigned short* __restrict__ Abuf, const int* __restrict__ rowptr,
    const int* __restrict__ csr, const float* __restrict__ inv_deg,
    unsigned short* __restrict__ AbufOut, int N) {
    int node = blockIdx.x * 4 + (threadIdx.x >> 6);
    if (node >= N) return;
    int lane = threadIdx.x & 63;
    int half = lane >> 5;          // 0: even edges, 1: odd edges
    int dlane = lane & 31;         // 8-dim group
    const unsigned short* base = Abuf + 256 + (size_t)dlane * 8;
    float a0 = 0.f, a1 = 0.f, a2 = 0.f, a3 = 0.f;
    float a4 = 0.f, a5 = 0.f, a6 = 0.f, a7 = 0.f;
    int beg = rowptr[node], end = rowptr[node + 1];
    int k = beg + half;
    for (; k + 7 < end; k += 8) {       // 4 edges per half per iter
        int j0 = csr[k], j1 = csr[k + 2], j2 = csr[k + 4], j3 = csr[k + 6];
        uint4 v0 = *reinterpret_cast<const uint4*>(base + (size_t)j0 * 512);
        uint4 v1 = *reinterpret_cast<const uint4*>(base + (size_t)j1 * 512);
        uint4 v2 = *reinterpret_cast<const uint4*>(base + (size_t)j2 * 512);
        uint4 v3 = *reinterpret_cast<const uint4*>(base + (size_t)j3 * 512);
        a0 += bfbits_lo(v0.x); a1 += bfbits_hi(v0.x); a2 += bfbits_lo(v0.y); a3 += bfbits_hi(v0.y);
        a4 += bfbits_lo(v0.z); a5 += bfbits_hi(v0.z); a6 += bfbits_lo(v0.w); a7 += bfbits_hi(v0.w);
        a0 += bfbits_lo(v1.x); a1 += bfbits_hi(v1.x); a2 += bfbits_lo(v1.y); a3 += bfbits_hi(v1.y);
        a4 += bfbits_lo(v1.z); a5 += bfbits_hi(v1.z); a6 += bfbits_lo(v1.w); a7 += bfbits_hi(v1.w);
        a0 += bfbits_lo(v2.x); a1 += bfbits_hi(v2.x); a2 += bfbits_lo(v2.y); a3 += bfbits_hi(v2.y);
        a4 += bfbits_lo(v2.z); a5 += bfbits_hi(v2.z); a6 += bfbits_lo(v2.w); a7 += bfbits_hi(v2.w);
        a0 += bfbits_lo(v3.x); a1 += bfbits_hi(v3.x); a2 += bfbits_lo(v3.y); a3 += bfbits_hi(v3.y);
        a4 += bfbits_lo(v3.z); a5 += bfbits_hi(v3.z); a6 += bfbits_lo(v3.w); a7 += bfbits_hi(v3.w);
    }
    for (; k < end; k += 2) {
        int j = csr[k];
        uint4 v = *reinterpret_cast<const uint4*>(base + (size_t)j * 512);
        a0 += bfbits_lo(v.x); a1 += bfbits_hi(v.x); a2 += bfbits_lo(v.y); a3 += bfbits_hi(v.y);
        a4 += bfbits_lo(v.z); a5 += bfbits_hi(v.z); a6 += bfbits_lo(v.w); a7 += bfbits_hi(v.w);
    }
    // combine the two halves (each lane pairs with lane^32, same dims)
    a0 += __shfl_xor(a0, 32, 64); a1 += __shfl_xor(a1, 32, 64);
    a2 += __shfl_xor(a2, 32, 64); a3 += __shfl_xor(a3, 32, 64);
    a4 += __shfl_xor(a4, 32, 64); a5 += __shfl_xor(a5, 32, 64);
    a6 += __shfl_xor(a6, 32, 64); a7 += __shfl_xor(a7, 32, 64);
    if (half == 0) {
        float s = inv_deg[node];
        uint4 w;
        w.x = (unsigned)f2bf(a0 * s) | ((unsigned)f2bf(a1 * s) << 16);
        w.y = (unsigned)f2bf(a2 * s) | ((unsigned)f2bf(a3 * s) << 16);
        w.z = (unsigned)f2bf(a4 * s) | ((unsigned)f2bf(a5 * s) << 16);
        w.w = (unsigned)f2bf(a6 * s) | ((unsigned)f2bf(a7 * s) << 16);
        *reinterpret_cast<uint4*>(AbufOut + (size_t)node * 512 + dlane * 8) = w;
    }
}

// ---------------- GEMM1 (MFMA): h = elu(Abuf @ B1t^T + b1) ----------------
__global__ __launch_bounds__(256) void gemm1_mfma(
    const unsigned short* __restrict__ Abuf,   // [M_PAD][512]
    const unsigned short* __restrict__ B1t,    // [256][512]
    const float* __restrict__ bias,            // [256]
    unsigned short* __restrict__ H,            // [M_PAD][256] bf16
    int M) {
    __shared__ unsigned short As[2][64 * 64];    // 16 KB
    __shared__ unsigned short Bs[2][128 * 64];   // 32 KB
    int tid = threadIdx.x;
    int row0 = blockIdx.x * 64;
    int bn = blockIdx.y;                 // 0..1
    int wid = tid >> 6, lane = tid & 63;
    int wm = (wid >> 1) * 32;            // 0 / 32
    int wn = (wid & 1) * 64;             // 0 / 64
    int fr = lane & 15, fq = lane >> 4;

    int lrow8 = lane >> 3;               // 0..7
    int gco = ((lane & 7) ^ lrow8) * 8;  // pre-swizzled global elem offset
    const unsigned short* gA0 = Abuf + (size_t)(row0 + wid * 16 + 0 + lrow8) * 512 + gco;
    const unsigned short* gA1 = Abuf + (size_t)(row0 + wid * 16 + 8 + lrow8) * 512 + gco;
    const unsigned short* gB0 = B1t + (size_t)(bn * 128 + wid * 32 + 0  + lrow8) * 512 + gco;
    const unsigned short* gB1 = B1t + (size_t)(bn * 128 + wid * 32 + 8  + lrow8) * 512 + gco;
    const unsigned short* gB2 = B1t + (size_t)(bn * 128 + wid * 32 + 16 + lrow8) * 512 + gco;
    const unsigned short* gB3 = B1t + (size_t)(bn * 128 + wid * 32 + 24 + lrow8) * 512 + gco;

    floatx4 acc[2][4] = {};

    #define STAGE(buf, k0)                                       \
        gload16(gA0 + (k0), &As[buf][(wid * 16 + 0) * 64]);      \
        gload16(gA1 + (k0), &As[buf][(wid * 16 + 8) * 64]);      \
        gload16(gB0 + (k0), &Bs[buf][(wid * 32 + 0) * 64]);      \
        gload16(gB1 + (k0), &Bs[buf][(wid * 32 + 8) * 64]);      \
        gload16(gB2 + (k0), &Bs[buf][(wid * 32 + 16) * 64]);     \
        gload16(gB3 + (k0), &Bs[buf][(wid * 32 + 24) * 64]);

    #define COMPUTE(buf)                                                                  \
        {                                                                                 \
            _Pragma("unroll")                                                             \
            for (int kc = 0; kc < 2; ++kc) {                                              \
                short8 af[2], bfr[4];                                                     \
                _Pragma("unroll")                                                         \
                for (int mi = 0; mi < 2; ++mi) {                                          \
                    int row = wm + mi * 16 + fr;                                          \
                    af[mi] = *reinterpret_cast<const short8*>(                            \
                        &As[buf][row * 64 + (((kc * 4 + fq) ^ (fr & 7)) * 8)]);           \
                }                                                                         \
                _Pragma("unroll")                                                         \
                for (int ni = 0; ni < 4; ++ni) {                                          \
                    int row = wn + ni * 16 + fr;                                          \
                    bfr[ni] = *reinterpret_cast<const short8*>(                           \
                        &Bs[buf][row * 64 + (((kc * 4 + fq) ^ (fr & 7)) * 8)]);           \
                }                                                                         \
                _Pragma("unroll")                                                         \
                for (int mi = 0; mi < 2; ++mi)                                            \
                    _Pragma("unroll")                                                     \
                    for (int ni = 0; ni < 4; ++ni)                                        \
                        acc[mi][ni] = __builtin_amdgcn_mfma_f32_16x16x32_bf16(            \
                            af[mi], bfr[ni], acc[mi][ni], 0, 0, 0);                       \
            }                                                                             \
        }

    STAGE(0, 0);
    __syncthreads();
    int cur = 0;
    #pragma unroll 1
    for (int t = 0; t < 7; ++t) {
        STAGE(cur ^ 1, (t + 1) * 64);
        COMPUTE(cur);
        __syncthreads();
        cur ^= 1;
    }
    COMPUTE(cur);
    #undef STAGE
    #undef COMPUTE

    #pragma unroll
    for (int ni = 0; ni < 4; ++ni) {
        int gcol = bn * 128 + wn + ni * 16 + fr;
        float bb = bias[gcol];
        #pragma unroll
        for (int mi = 0; mi < 2; ++mi) {
            #pragma unroll
            for (int r = 0; r < 4; ++r) {
                int grow = row0 + wm + mi * 16 + fq * 4 + r;   // < M_PAD
                float t = acc[mi][ni][r] + bb;
                t = (t > 0.f) ? t : expm1f(t);
                H[(size_t)grow * 256 + gcol] = f2bf(t);
            }
        }
    }
}

// ---------------- GEMM2 (MFMA): Plb = bf16(H @ W2l'), Pr = H @ W2r' + b2 ----------------
__global__ __launch_bounds__(256) void gemm2_mfma(
    const unsigned short* __restrict__ Hb,   // [M_PAD][256]
    const unsigned short* __restrict__ B2t,  // [80][256]
    const float* __restrict__ b2,
    unsigned short* __restrict__ Plb,        // [N][40] bf16
    float* __restrict__ Pr,                  // [N][40] fp32
    int M) {
    __shared__ unsigned short Bsm[80 * 256];   // 40 KB
    __shared__ unsigned short As[2][64 * 64];  // 16 KB
    int tid = threadIdx.x;
    int row0 = blockIdx.x * 64;
    int wid = tid >> 6, lane = tid & 63;
    int wm = wid * 16;
    int fr = lane & 15, fq = lane >> 4;

    for (int c = tid; c < 2560; c += 256) {
        int n = c >> 5, ci = c & 31;
        short8 v = *reinterpret_cast<const short8*>(B2t + (size_t)n * 256 + ci * 8);
        *reinterpret_cast<short8*>(&Bsm[n * 256 + ((ci ^ (n & 7)) * 8)]) = v;
    }

    int lrow8 = lane >> 3;
    int gco = ((lane & 7) ^ lrow8) * 8;
    const unsigned short* gA0 = Hb + (size_t)(row0 + wid * 16 + 0 + lrow8) * 256 + gco;
    const unsigned short* gA1 = Hb + (size_t)(row0 + wid * 16 + 8 + lrow8) * 256 + gco;

    floatx4 acc[5] = {};

    #define STAGE2(buf, k0)                                      \
        gload16(gA0 + (k0), &As[buf][(wid * 16 + 0) * 64]);      \
        gload16(gA1 + (k0), &As[buf][(wid * 16 + 8) * 64]);

    #define COMPUTE2(buf, k0)                                                             \
        {                                                                                 \
            _Pragma("unroll")                                                             \
            for (int kc = 0; kc < 2; ++kc) {                                              \
                short8 af;                                                                \
                {                                                                         \
                    int row = wm + fr;                                                    \
                    af = *reinterpret_cast<const short8*>(                                \
                        &As[buf][row * 64 + (((kc * 4 + fq) ^ (fr & 7)) * 8)]);           \
                }                                                                         \
                _Pragma("unroll")                                                         \
                for (int ni = 0; ni < 5; ++ni) {                                          \
                    int n = ni * 16 + fr;                                                 \
                    int c = ((k0) >> 3) + kc * 4 + fq;                                    \
                    short8 bfr = *reinterpret_cast<const short8*>(                        \
                        &Bsm[n * 256 + ((c ^ (n & 7)) * 8)]);                             \
                    acc[ni] = __builtin_amdgcn_mfma_f32_16x16x32_bf16(                    \
                        af, bfr, acc[ni], 0, 0, 0);                                       \
                }                                                                         \
            }                                                                             \
        }

    STAGE2(0, 0);
    __syncthreads();
    int cur = 0;
    #pragma unroll 1
    for (int t = 0; t < 3; ++t) {
        STAGE2(cur ^ 1, (t + 1) * 64);
        COMPUTE2(cur, t * 64);
        __syncthreads();
        cur ^= 1;
    }
    COMPUTE2(cur, 192);
    #undef STAGE2
    #undef COMPUTE2

    #pragma unroll
    for (int r = 0; r < 4; ++r) {
        int grow = row0 + wm + fq * 4 + r;
        if (grow < M) {
            #pragma unroll
            for (int ni = 0; ni < 5; ++ni) {
                int col = ni * 16 + fr;
                float v = acc[ni][r];
                if (col < 40)
                    Plb[(size_t)grow * 40 + col] = f2bf(v);
                else
                    Pr[(size_t)grow * 40 + (col - 40)] = v + b2[col - 40];
            }
        }
    }
}

// ---------------- final: out = mean_agg(Plb) + Pr ----------------
__global__ __launch_bounds__(256) void final_kernel(
    const unsigned short* __restrict__ Plb, const float* __restrict__ Pr,
    const int* __restrict__ rowptr, const int* __restrict__ csr,
    const float* __restrict__ inv_deg, float* __restrict__ out, int N) {
    int wv = blockIdx.x * 4 + (threadIdx.x >> 6);
    int node = wv * 2 + ((threadIdx.x >> 5) & 1);
    if (node >= N) return;
    int lane = threadIdx.x & 31;
    if (lane >= 20) return;
    float s0 = 0.f, s1 = 0.f;
    int beg = rowptr[node], end = rowptr[node + 1];
    int k = beg;
    for (; k + 4 <= end; k += 4) {
        unsigned v0 = *reinterpret_cast<const unsigned*>(Plb + (size_t)csr[k]     * 40 + lane * 2);
        unsigned v1 = *reinterpret_cast<const unsigned*>(Plb + (size_t)csr[k + 1] * 40 + lane * 2);
        unsigned v2 = *reinterpret_cast<const unsigned*>(Plb + (size_t)csr[k + 2] * 40 + lane * 2);
        unsigned v3 = *reinterpret_cast<const unsigned*>(Plb + (size_t)csr[k + 3] * 40 + lane * 2);
        s0 += bfbits_lo(v0) + bfbits_lo(v1) + bfbits_lo(v2) + bfbits_lo(v3);
        s1 += bfbits_hi(v0) + bfbits_hi(v1) + bfbits_hi(v2) + bfbits_hi(v3);
    }
    for (; k < end; ++k) {
        unsigned v = *reinterpret_cast<const unsigned*>(Plb + (size_t)csr[k] * 40 + lane * 2);
        s0 += bfbits_lo(v);
        s1 += bfbits_hi(v);
    }
    float inv = inv_deg[node];
    float2 pr = *reinterpret_cast<const float2*>(Pr + (size_t)node * 40 + lane * 2);
    float2 o;
    o.x = s0 * inv + pr.x;
    o.y = s1 * inv + pr.y;
    *reinterpret_cast<float2*>(out + (size_t)node * 40 + lane * 2) = o;
}

// ---------------- launcher ----------------

extern "C" void kernel_launch(void* const* d_in, const int* in_sizes, int n_in,
                              void* d_out, int out_size, void* d_ws, size_t ws_size,
                              hipStream_t stream) {
    const float* x   = (const float*)d_in[0];
    const int*   ei  = (const int*)d_in[1];
    const float* W1l = (const float*)d_in[2];
    const float* b1  = (const float*)d_in[3];
    const float* W1r = (const float*)d_in[4];
    const float* W2l = (const float*)d_in[5];
    const float* b2  = (const float*)d_in[6];
    const float* W2r = (const float*)d_in[7];
    const float* Q   = (const float*)d_in[8];
    const int E = in_sizes[1] / 2;
    const int N = N_NODES;
    const int* src = ei;
    const int* dst = ei + E;
    const int NB = (N + 255) / 256;

    unsigned short* Abuf = (unsigned short*)d_ws;            // [M_PAD][512] bf16
    unsigned short* h    = Abuf + (size_t)M_PAD * 512;       // [M_PAD][256] bf16
    unsigned short* B1t  = h + (size_t)M_PAD * 256;          // [256][512]
    unsigned short* B2t  = B1t + 256 * 512;                  // [80][256]
    unsigned short* Plb  = B2t + 80 * 256;                   // [N][40] bf16
    float* Pr      = (float*)(Plb + (size_t)N * 40 + 32);    // [N][40] fp32
    float* inv_deg = Pr + (size_t)N * 40;                    // N
    int*   deg     = (int*)(inv_deg + N);                    // N
    int*   cnt     = deg + N;                                // N
    int*   rowptr  = cnt + N;                                // N+1
    int*   blocksums = rowptr + N + 1;                       // NB
    int*   blockoff  = blocksums + NB;                       // NB
    int*   csr     = blockoff + NB;                          // E

    float* out = (float*)d_out;

    hipMemsetAsync(deg, 0, sizeof(int) * 2 * (size_t)N, stream);
    prep_count<<<6842 + 1024, 256, 0, stream>>>(x, W1l, W1r, W2l, W2r,
                                                Abuf, B1t, B2t, dst, deg, E);
    scan1_kernel<<<NB, 256, 0, stream>>>(deg, blocksums, N);
    scan2_kernel<<<1, 256, 0, stream>>>(blocksums, blockoff, NB);
    scan3_kernel<<<NB, 256, 0, stream>>>(deg, blockoff, rowptr, inv_deg, N, E);

    const int nQ4 = in_sizes[8] / 4;             // 4,000,000 float4
    fill_q<<<2048, 256, 0, stream>>>(src, dst, rowptr, cnt, csr, E,
                                     (const float4*)Q,
                                     (float4*)(out + (size_t)N * 40), nQ4);

    aggregate1<<<(N + 3) / 4, 256, 0, stream>>>(Abuf, rowptr, csr, inv_deg, Abuf, N);
    gemm1_mfma<<<dim3(M_PAD / 64, 2), 256, 0, stream>>>(Abuf, B1t, b1, h, N);
    gemm2_mfma<<<M_PAD / 64, 256, 0, stream>>>(h, B2t, b2, Plb, Pr, N);
    final_kernel<<<(N + 7) / 8, 256, 0, stream>>>(Plb, Pr, rowptr, csr, inv_deg, out, N);
}

// Round 9
// 232.744 us; speedup vs baseline: 3.1540x; 1.0986x over previous
//
#include <hip/hip_runtime.h>
#include <hip/hip_bf16.h>
#include <cstddef>

#define N_NODES 50000
#define M_PAD 50048   // multiple of 128 and 64

typedef __attribute__((ext_vector_type(8))) short short8;
typedef __attribute__((ext_vector_type(4))) float floatx4;

__device__ inline unsigned short f2bf(float f) {
    union { float f; unsigned u; } v; v.f = f;
    unsigned r = v.u + 0x7fff + ((v.u >> 16) & 1);
    return (unsigned short)(r >> 16);
}
__device__ inline float bfbits_lo(unsigned u) {
    union { unsigned u; float f; } v; v.u = u << 16; return v.f;
}
__device__ inline float bfbits_hi(unsigned u) {
    union { unsigned u; float f; } v; v.u = u & 0xffff0000u; return v.f;
}

__device__ inline void gload16(const void* g, void* l) {
    __builtin_amdgcn_global_load_lds(
        (const __attribute__((address_space(1))) unsigned int*)g,
        (__attribute__((address_space(3))) unsigned int*)l, 16, 0, 0);
}

// ---------------- fused prep (x->bf16, B1t, B2t) + degree count + edge rank ----------------
// blocks: [0,6250) convert, [6250,6762) B1t, [6762,6842) B2t, [6842,7866) count+rank
__global__ __launch_bounds__(256) void prep_count(
    const float* __restrict__ x,
    const float* __restrict__ W1l, const float* __restrict__ W1r,
    const float* __restrict__ W2l, const float* __restrict__ W2r,
    unsigned short* __restrict__ Abuf, unsigned short* __restrict__ B1t,
    unsigned short* __restrict__ B2t,
    const int* __restrict__ dst, int* __restrict__ deg, int* __restrict__ erank,
    int E) {
    int b = blockIdx.x;
    int tid = threadIdx.x;
    if (b < 6250) {
        int i = b * 256 + tid;             // < 1,600,000 exactly
        int row = i >> 5;
        int c8 = i & 31;
        const float4* xp = reinterpret_cast<const float4*>(x + (size_t)row * 256 + c8 * 8);
        float4 v0 = xp[0], v1 = xp[1];
        uint4 o;
        o.x = (unsigned)f2bf(v0.x) | ((unsigned)f2bf(v0.y) << 16);
        o.y = (unsigned)f2bf(v0.z) | ((unsigned)f2bf(v0.w) << 16);
        o.z = (unsigned)f2bf(v1.x) | ((unsigned)f2bf(v1.y) << 16);
        o.w = (unsigned)f2bf(v1.z) | ((unsigned)f2bf(v1.w) << 16);
        *reinterpret_cast<uint4*>(Abuf + (size_t)row * 512 + 256 + c8 * 8) = o;
    } else if (b < 6250 + 512) {
        int idx = (b - 6250) * 256 + tid;  // < 131072 exactly
        int n = idx >> 9, k = idx & 511;
        float v = (k < 256) ? W1l[(size_t)k * 256 + n] : W1r[(size_t)(k - 256) * 256 + n];
        B1t[(size_t)n * 512 + k] = f2bf(v);
    } else if (b < 6842) {
        int idx = (b - 6762) * 256 + tid;  // < 20480 exactly
        int n = idx >> 8, k = idx & 255;
        float v = (n < 40) ? W2l[(size_t)k * 40 + n] : W2r[(size_t)k * 40 + (n - 40)];
        B2t[(size_t)n * 256 + k] = f2bf(v);
    } else {
        int base = (b - 6842) * 256 + tid;
        for (int e = base; e < E; e += 1024 * 256)
            erank[e] = atomicAdd(&deg[dst[e]], 1);
    }
}

__global__ __launch_bounds__(256) void scan1_kernel(const int* __restrict__ deg,
                                                    int* __restrict__ blocksums, int n) {
    __shared__ int s[256];
    int t = threadIdx.x;
    int i = blockIdx.x * 256 + t;
    s[t] = (i < n) ? deg[i] : 0;
    __syncthreads();
    for (int off = 128; off > 0; off >>= 1) {
        if (t < off) s[t] += s[t + off];
        __syncthreads();
    }
    if (t == 0) blocksums[blockIdx.x] = s[0];
}

__global__ __launch_bounds__(256) void scan2_kernel(const int* __restrict__ blocksums,
                                                    int* __restrict__ blockoff, int nb) {
    __shared__ int s[256];
    int t = threadIdx.x;
    s[t] = (t < nb) ? blocksums[t] : 0;
    __syncthreads();
    for (int off = 1; off < 256; off <<= 1) {
        int u = (t >= off) ? s[t - off] : 0;
        __syncthreads();
        s[t] += u;
        __syncthreads();
    }
    if (t < nb) blockoff[t] = (t == 0) ? 0 : s[t - 1];
}

__global__ __launch_bounds__(256) void scan3_kernel(const int* __restrict__ deg,
                                                    const int* __restrict__ blockoff,
                                                    int* __restrict__ rowptr,
                                                    float* __restrict__ inv_deg,
                                                    int n, int E) {
    __shared__ int s[256];
    int t = threadIdx.x;
    int i = blockIdx.x * 256 + t;
    int v = (i < n) ? deg[i] : 0;
    s[t] = v;
    __syncthreads();
    for (int off = 1; off < 256; off <<= 1) {
        int u = (t >= off) ? s[t - off] : 0;
        __syncthreads();
        s[t] += u;
        __syncthreads();
    }
    if (i < n) {
        rowptr[i] = s[t] - v + blockoff[blockIdx.x];
        inv_deg[i] = 1.0f / (float)(v > 1 ? v : 1);
    }
    if (blockIdx.x == 0 && t == 0) rowptr[n] = E;
}

// ---------------- fill CSR (atomic-free, uses precomputed edge rank) ----------------
__global__ void fill_kernel(const int* __restrict__ src, const int* __restrict__ dst,
                            const int* __restrict__ erank, const int* __restrict__ rowptr,
                            int* __restrict__ csr, int E) {
    for (int e = blockIdx.x * blockDim.x + threadIdx.x; e < E; e += gridDim.x * blockDim.x)
        csr[rowptr[dst[e]] + erank[e]] = src[e];
}

// ---------------- mean aggregation (256-d): wave/node, 2 edges/iter ----------------
__global__ __launch_bounds__(256) void aggregate1(
    const unsigned short* __restrict__ Abuf, const int* __restrict__ rowptr,
    const int* __restrict__ csr, const float* __restrict__ inv_deg,
    unsigned short* __restrict__ AbufOut, int N) {
    int node = blockIdx.x * 4 + (threadIdx.x >> 6);
    if (node >= N) return;
    int lane = threadIdx.x & 63;
    int half = lane >> 5;          // 0: even edges, 1: odd edges
    int dlane = lane & 31;         // 8-dim group
    const unsigned short* base = Abuf + 256 + (size_t)dlane * 8;
    float a0 = 0.f, a1 = 0.f, a2 = 0.f, a3 = 0.f;
    float a4 = 0.f, a5 = 0.f, a6 = 0.f, a7 = 0.f;
    int beg = rowptr[node], end = rowptr[node + 1];
    int k = beg + half;
    for (; k + 7 < end; k += 8) {       // 4 edges per half per iter
        int j0 = csr[k], j1 = csr[k + 2], j2 = csr[k + 4], j3 = csr[k + 6];
        uint4 v0 = *reinterpret_cast<const uint4*>(base + (size_t)j0 * 512);
        uint4 v1 = *reinterpret_cast<const uint4*>(base + (size_t)j1 * 512);
        uint4 v2 = *reinterpret_cast<const uint4*>(base + (size_t)j2 * 512);
        uint4 v3 = *reinterpret_cast<const uint4*>(base + (size_t)j3 * 512);
        a0 += bfbits_lo(v0.x); a1 += bfbits_hi(v0.x); a2 += bfbits_lo(v0.y); a3 += bfbits_hi(v0.y);
        a4 += bfbits_lo(v0.z); a5 += bfbits_hi(v0.z); a6 += bfbits_lo(v0.w); a7 += bfbits_hi(v0.w);
        a0 += bfbits_lo(v1.x); a1 += bfbits_hi(v1.x); a2 += bfbits_lo(v1.y); a3 += bfbits_hi(v1.y);
        a4 += bfbits_lo(v1.z); a5 += bfbits_hi(v1.z); a6 += bfbits_lo(v1.w); a7 += bfbits_hi(v1.w);
        a0 += bfbits_lo(v2.x); a1 += bfbits_hi(v2.x); a2 += bfbits_lo(v2.y); a3 += bfbits_hi(v2.y);
        a4 += bfbits_lo(v2.z); a5 += bfbits_hi(v2.z); a6 += bfbits_lo(v2.w); a7 += bfbits_hi(v2.w);
        a0 += bfbits_lo(v3.x); a1 += bfbits_hi(v3.x); a2 += bfbits_lo(v3.y); a3 += bfbits_hi(v3.y);
        a4 += bfbits_lo(v3.z); a5 += bfbits_hi(v3.z); a6 += bfbits_lo(v3.w); a7 += bfbits_hi(v3.w);
    }
    for (; k < end; k += 2) {
        int j = csr[k];
        uint4 v = *reinterpret_cast<const uint4*>(base + (size_t)j * 512);
        a0 += bfbits_lo(v.x); a1 += bfbits_hi(v.x); a2 += bfbits_lo(v.y); a3 += bfbits_hi(v.y);
        a4 += bfbits_lo(v.z); a5 += bfbits_hi(v.z); a6 += bfbits_lo(v.w); a7 += bfbits_hi(v.w);
    }
    a0 += __shfl_xor(a0, 32, 64); a1 += __shfl_xor(a1, 32, 64);
    a2 += __shfl_xor(a2, 32, 64); a3 += __shfl_xor(a3, 32, 64);
    a4 += __shfl_xor(a4, 32, 64); a5 += __shfl_xor(a5, 32, 64);
    a6 += __shfl_xor(a6, 32, 64); a7 += __shfl_xor(a7, 32, 64);
    if (half == 0) {
        float s = inv_deg[node];
        uint4 w;
        w.x = (unsigned)f2bf(a0 * s) | ((unsigned)f2bf(a1 * s) << 16);
        w.y = (unsigned)f2bf(a2 * s) | ((unsigned)f2bf(a3 * s) << 16);
        w.z = (unsigned)f2bf(a4 * s) | ((unsigned)f2bf(a5 * s) << 16);
        w.w = (unsigned)f2bf(a6 * s) | ((unsigned)f2bf(a7 * s) << 16);
        *reinterpret_cast<uint4*>(AbufOut + (size_t)node * 512 + dlane * 8) = w;
    }
}

// ---------------- GEMM1 (MFMA) + fused Q-copy panel ----------------
// grid (M_PAD/64, 3): y=0,1 GEMM column panels; y=2 streaming Q float4 copy.
__global__ __launch_bounds__(256) void gemm1_mfma(
    const unsigned short* __restrict__ Abuf,   // [M_PAD][512]
    const unsigned short* __restrict__ B1t,    // [256][512]
    const float* __restrict__ bias,            // [256]
    unsigned short* __restrict__ H,            // [M_PAD][256] bf16
    int M,
    const float4* __restrict__ Qsrc, float4* __restrict__ Qdst, int nQ4) {
    __shared__ unsigned short As[2][64 * 64];    // 16 KB
    __shared__ unsigned short Bs[2][128 * 64];   // 32 KB
    int tid = threadIdx.x;
    int bn = blockIdx.y;                 // 0,1 = gemm; 2 = copy
    if (bn == 2) {
        int idx = blockIdx.x * 256 + tid;
        int stride = gridDim.x * 256;
        for (int i = idx; i < nQ4; i += stride) Qdst[i] = Qsrc[i];
        return;
    }
    int row0 = blockIdx.x * 64;
    int wid = tid >> 6, lane = tid & 63;
    int wm = (wid >> 1) * 32;            // 0 / 32
    int wn = (wid & 1) * 64;             // 0 / 64
    int fr = lane & 15, fq = lane >> 4;

    int lrow8 = lane >> 3;               // 0..7
    int gco = ((lane & 7) ^ lrow8) * 8;  // pre-swizzled global elem offset
    const unsigned short* gA0 = Abuf + (size_t)(row0 + wid * 16 + 0 + lrow8) * 512 + gco;
    const unsigned short* gA1 = Abuf + (size_t)(row0 + wid * 16 + 8 + lrow8) * 512 + gco;
    const unsigned short* gB0 = B1t + (size_t)(bn * 128 + wid * 32 + 0  + lrow8) * 512 + gco;
    const unsigned short* gB1 = B1t + (size_t)(bn * 128 + wid * 32 + 8  + lrow8) * 512 + gco;
    const unsigned short* gB2 = B1t + (size_t)(bn * 128 + wid * 32 + 16 + lrow8) * 512 + gco;
    const unsigned short* gB3 = B1t + (size_t)(bn * 128 + wid * 32 + 24 + lrow8) * 512 + gco;

    floatx4 acc[2][4] = {};

    #define STAGE(buf, k0)                                       \
        gload16(gA0 + (k0), &As[buf][(wid * 16 + 0) * 64]);      \
        gload16(gA1 + (k0), &As[buf][(wid * 16 + 8) * 64]);      \
        gload16(gB0 + (k0), &Bs[buf][(wid * 32 + 0) * 64]);      \
        gload16(gB1 + (k0), &Bs[buf][(wid * 32 + 8) * 64]);      \
        gload16(gB2 + (k0), &Bs[buf][(wid * 32 + 16) * 64]);     \
        gload16(gB3 + (k0), &Bs[buf][(wid * 32 + 24) * 64]);

    #define COMPUTE(buf)                                                                  \
        {                                                                                 \
            _Pragma("unroll")                                                             \
            for (int kc = 0; kc < 2; ++kc) {                                              \
                short8 af[2], bfr[4];                                                     \
                _Pragma("unroll")                                                         \
                for (int mi = 0; mi < 2; ++mi) {                                          \
                    int row = wm + mi * 16 + fr;                                          \
                    af[mi] = *reinterpret_cast<const short8*>(                            \
                        &As[buf][row * 64 + (((kc * 4 + fq) ^ (fr & 7)) * 8)]);           \
                }                                                                         \
                _Pragma("unroll")                                                         \
                for (int ni = 0; ni < 4; ++ni) {                                          \
                    int row = wn + ni * 16 + fr;                                          \
                    bfr[ni] = *reinterpret_cast<const short8*>(                           \
                        &Bs[buf][row * 64 + (((kc * 4 + fq) ^ (fr & 7)) * 8)]);           \
                }                                                                         \
                _Pragma("unroll")                                                         \
                for (int mi = 0; mi < 2; ++mi)                                            \
                    _Pragma("unroll")                                                     \
                    for (int ni = 0; ni < 4; ++ni)                                        \
                        acc[mi][ni] = __builtin_amdgcn_mfma_f32_16x16x32_bf16(            \
                            af[mi], bfr[ni], acc[mi][ni], 0, 0, 0);                       \
            }                                                                             \
        }

    STAGE(0, 0);
    __syncthreads();
    int cur = 0;
    #pragma unroll 1
    for (int t = 0; t < 7; ++t) {
        STAGE(cur ^ 1, (t + 1) * 64);
        COMPUTE(cur);
        __syncthreads();
        cur ^= 1;
    }
    COMPUTE(cur);
    #undef STAGE
    #undef COMPUTE

    #pragma unroll
    for (int ni = 0; ni < 4; ++ni) {
        int gcol = bn * 128 + wn + ni * 16 + fr;
        float bb = bias[gcol];
        #pragma unroll
        for (int mi = 0; mi < 2; ++mi) {
            #pragma unroll
            for (int r = 0; r < 4; ++r) {
                int grow = row0 + wm + mi * 16 + fq * 4 + r;   // < M_PAD
                float t = acc[mi][ni][r] + bb;
                t = (t > 0.f) ? t : expm1f(t);
                H[(size_t)grow * 256 + gcol] = f2bf(t);
            }
        }
    }
}

// ---------------- GEMM2 (MFMA): Plb = bf16(H @ W2l'), Pr = H @ W2r' + b2 ----------------
__global__ __launch_bounds__(256) void gemm2_mfma(
    const unsigned short* __restrict__ Hb,   // [M_PAD][256]
    const unsigned short* __restrict__ B2t,  // [80][256]
    const float* __restrict__ b2,
    unsigned short* __restrict__ Plb,        // [N][40] bf16
    float* __restrict__ Pr,                  // [N][40] fp32
    int M) {
    __shared__ unsigned short Bsm[80 * 256];   // 40 KB
    __shared__ unsigned short As[2][64 * 64];  // 16 KB
    int tid = threadIdx.x;
    int row0 = blockIdx.x * 64;
    int wid = tid >> 6, lane = tid & 63;
    int wm = wid * 16;
    int fr = lane & 15, fq = lane >> 4;

    for (int c = tid; c < 2560; c += 256) {
        int n = c >> 5, ci = c & 31;
        short8 v = *reinterpret_cast<const short8*>(B2t + (size_t)n * 256 + ci * 8);
        *reinterpret_cast<short8*>(&Bsm[n * 256 + ((ci ^ (n & 7)) * 8)]) = v;
    }

    int lrow8 = lane >> 3;
    int gco = ((lane & 7) ^ lrow8) * 8;
    const unsigned short* gA0 = Hb + (size_t)(row0 + wid * 16 + 0 + lrow8) * 256 + gco;
    const unsigned short* gA1 = Hb + (size_t)(row0 + wid * 16 + 8 + lrow8) * 256 + gco;

    floatx4 acc[5] = {};

    #define STAGE2(buf, k0)                                      \
        gload16(gA0 + (k0), &As[buf][(wid * 16 + 0) * 64]);      \
        gload16(gA1 + (k0), &As[buf][(wid * 16 + 8) * 64]);

    #define COMPUTE2(buf, k0)                                                             \
        {                                                                                 \
            _Pragma("unroll")                                                             \
            for (int kc = 0; kc < 2; ++kc) {                                              \
                short8 af;                                                                \
                {                                                                         \
                    int row = wm + fr;                                                    \
                    af = *reinterpret_cast<const short8*>(                                \
                        &As[buf][row * 64 + (((kc * 4 + fq) ^ (fr & 7)) * 8)]);           \
                }                                                                         \
                _Pragma("unroll")                                                         \
                for (int ni = 0; ni < 5; ++ni) {                                          \
                    int n = ni * 16 + fr;                                                 \
                    int c = ((k0) >> 3) + kc * 4 + fq;                                    \
                    short8 bfr = *reinterpret_cast<const short8*>(                        \
                        &Bsm[n * 256 + ((c ^ (n & 7)) * 8)]);                             \
                    acc[ni] = __builtin_amdgcn_mfma_f32_16x16x32_bf16(                    \
                        af, bfr, acc[ni], 0, 0, 0);                                       \
                }                                                                         \
            }                                                                             \
        }

    STAGE2(0, 0);
    __syncthreads();    // covers B-fill ds_writes and first A gload
    int cur = 0;
    #pragma unroll 1
    for (int t = 0; t < 3; ++t) {
        STAGE2(cur ^ 1, (t + 1) * 64);
        COMPUTE2(cur, t * 64);
        __syncthreads();
        cur ^= 1;
    }
    COMPUTE2(cur, 192);
    #undef STAGE2
    #undef COMPUTE2

    #pragma unroll
    for (int r = 0; r < 4; ++r) {
        int grow = row0 + wm + fq * 4 + r;
        if (grow < M) {
            #pragma unroll
            for (int ni = 0; ni < 5; ++ni) {
                int col = ni * 16 + fr;
                float v = acc[ni][r];
                if (col < 40)
                    Plb[(size_t)grow * 40 + col] = f2bf(v);
                else
                    Pr[(size_t)grow * 40 + (col - 40)] = v + b2[col - 40];
            }
        }
    }
}

// ---------------- final: out = mean_agg(Plb) + Pr ----------------
__global__ __launch_bounds__(256) void final_kernel(
    const unsigned short* __restrict__ Plb, const float* __restrict__ Pr,
    const int* __restrict__ rowptr, const int* __restrict__ csr,
    const float* __restrict__ inv_deg, float* __restrict__ out, int N) {
    int wv = blockIdx.x * 4 + (threadIdx.x >> 6);
    int node = wv * 2 + ((threadIdx.x >> 5) & 1);
    if (node >= N) return;
    int lane = threadIdx.x & 31;
    if (lane >= 20) return;
    float s0 = 0.f, s1 = 0.f;
    int beg = rowptr[node], end = rowptr[node + 1];
    int k = beg;
    for (; k + 4 <= end; k += 4) {
        unsigned v0 = *reinterpret_cast<const unsigned*>(Plb + (size_t)csr[k]     * 40 + lane * 2);
        unsigned v1 = *reinterpret_cast<const unsigned*>(Plb + (size_t)csr[k + 1] * 40 + lane * 2);
        unsigned v2 = *reinterpret_cast<const unsigned*>(Plb + (size_t)csr[k + 2] * 40 + lane * 2);
        unsigned v3 = *reinterpret_cast<const unsigned*>(Plb + (size_t)csr[k + 3] * 40 + lane * 2);
        s0 += bfbits_lo(v0) + bfbits_lo(v1) + bfbits_lo(v2) + bfbits_lo(v3);
        s1 += bfbits_hi(v0) + bfbits_hi(v1) + bfbits_hi(v2) + bfbits_hi(v3);
    }
    for (; k < end; ++k) {
        unsigned v = *reinterpret_cast<const unsigned*>(Plb + (size_t)csr[k] * 40 + lane * 2);
        s0 += bfbits_lo(v);
        s1 += bfbits_hi(v);
    }
    float inv = inv_deg[node];
    float2 pr = *reinterpret_cast<const float2*>(Pr + (size_t)node * 40 + lane * 2);
    float2 o;
    o.x = s0 * inv + pr.x;
    o.y = s1 * inv + pr.y;
    *reinterpret_cast<float2*>(out + (size_t)node * 40 + lane * 2) = o;
}

// ---------------- launcher ----------------

extern "C" void kernel_launch(void* const* d_in, const int* in_sizes, int n_in,
                              void* d_out, int out_size, void* d_ws, size_t ws_size,
                              hipStream_t stream) {
    const float* x   = (const float*)d_in[0];
    const int*   ei  = (const int*)d_in[1];
    const float* W1l = (const float*)d_in[2];
    const float* b1  = (const float*)d_in[3];
    const float* W1r = (const float*)d_in[4];
    const float* W2l = (const float*)d_in[5];
    const float* b2  = (const float*)d_in[6];
    const float* W2r = (const float*)d_in[7];
    const float* Q   = (const float*)d_in[8];
    const int E = in_sizes[1] / 2;
    const int N = N_NODES;
    const int* src = ei;
    const int* dst = ei + E;
    const int NB = (N + 255) / 256;

    unsigned short* Abuf = (unsigned short*)d_ws;            // [M_PAD][512] bf16
    unsigned short* h    = Abuf + (size_t)M_PAD * 512;       // [M_PAD][256] bf16
    unsigned short* B1t  = h + (size_t)M_PAD * 256;          // [256][512]
    unsigned short* B2t  = B1t + 256 * 512;                  // [80][256]
    unsigned short* Plb  = B2t + 80 * 256;                   // [N][40] bf16
    float* Pr      = (float*)(Plb + (size_t)N * 40 + 32);    // [N][40] fp32
    float* inv_deg = Pr + (size_t)N * 40;                    // N
    int*   deg     = (int*)(inv_deg + N);                    // N
    int*   rowptr  = deg + N;                                // N+1
    int*   blocksums = rowptr + N + 1;                       // NB
    int*   blockoff  = blocksums + NB;                       // NB
    int*   csr     = blockoff + NB;                          // E
    int*   erank   = csr + E;                                // E

    float* out = (float*)d_out;

    hipMemsetAsync(deg, 0, sizeof(int) * (size_t)N, stream);
    prep_count<<<6842 + 1024, 256, 0, stream>>>(x, W1l, W1r, W2l, W2r,
                                                Abuf, B1t, B2t, dst, deg, erank, E);
    scan1_kernel<<<NB, 256, 0, stream>>>(deg, blocksums, N);
    scan2_kernel<<<1, 256, 0, stream>>>(blocksums, blockoff, NB);
    scan3_kernel<<<NB, 256, 0, stream>>>(deg, blockoff, rowptr, inv_deg, N, E);

    fill_kernel<<<1024, 256, 0, stream>>>(src, dst, erank, rowptr, csr, E);

    aggregate1<<<(N + 3) / 4, 256, 0, stream>>>(Abuf, rowptr, csr, inv_deg, Abuf, N);

    const int nQ4 = in_sizes[8] / 4;             // 4,000,000 float4
    gemm1_mfma<<<dim3(M_PAD / 64, 3), 256, 0, stream>>>(
        Abuf, B1t, b1, h, N, (const float4*)Q, (float4*)(out + (size_t)N * 40), nQ4);

    gemm2_mfma<<<M_PAD / 64, 256, 0, stream>>>(h, B2t, b2, Plb, Pr, N);
    final_kernel<<<(N + 7) / 8, 256, 0, stream>>>(Plb, Pr, rowptr, csr, inv_deg, out, N);
}

// Round 10
// 232.374 us; speedup vs baseline: 3.1590x; 1.0016x over previous
//
#include <hip/hip_runtime.h>
#include <hip/hip_bf16.h>
#include <cstddef>

#define N_NODES 50000
#define M_PAD 50048   // multiple of 128 and 64

typedef __attribute__((ext_vector_type(8))) short short8;
typedef __attribute__((ext_vector_type(4))) float floatx4;

__device__ inline unsigned short f2bf(float f) {
    union { float f; unsigned u; } v; v.f = f;
    unsigned r = v.u + 0x7fff + ((v.u >> 16) & 1);
    return (unsigned short)(r >> 16);
}
__device__ inline float bfbits_lo(unsigned u) {
    union { unsigned u; float f; } v; v.u = u << 16; return v.f;
}
__device__ inline float bfbits_hi(unsigned u) {
    union { unsigned u; float f; } v; v.u = u & 0xffff0000u; return v.f;
}

__device__ inline void gload16(const void* g, void* l) {
    __builtin_amdgcn_global_load_lds(
        (const __attribute__((address_space(1))) unsigned int*)g,
        (__attribute__((address_space(3))) unsigned int*)l, 16, 0, 0);
}

// ---------------- fused prep (x->bf16, B1t, B2t) + count+rank + Q copy ----------------
// blocks: [0,6250) convert, [6250,6762) B1t, [6762,6842) B2t,
//         [6842,7866) count+rank, [7866,8890) Q float4 copy
__global__ __launch_bounds__(256) void prep_count(
    const float* __restrict__ x,
    const float* __restrict__ W1l, const float* __restrict__ W1r,
    const float* __restrict__ W2l, const float* __restrict__ W2r,
    unsigned short* __restrict__ Abuf, unsigned short* __restrict__ B1t,
    unsigned short* __restrict__ B2t,
    const int* __restrict__ dst, int* __restrict__ deg, int* __restrict__ erank,
    int E,
    const float4* __restrict__ Qsrc, float4* __restrict__ Qdst, int nQ4) {
    int b = blockIdx.x;
    int tid = threadIdx.x;
    if (b < 6250) {
        int i = b * 256 + tid;             // < 1,600,000 exactly
        int row = i >> 5;
        int c8 = i & 31;
        const float4* xp = reinterpret_cast<const float4*>(x + (size_t)row * 256 + c8 * 8);
        float4 v0 = xp[0], v1 = xp[1];
        uint4 o;
        o.x = (unsigned)f2bf(v0.x) | ((unsigned)f2bf(v0.y) << 16);
        o.y = (unsigned)f2bf(v0.z) | ((unsigned)f2bf(v0.w) << 16);
        o.z = (unsigned)f2bf(v1.x) | ((unsigned)f2bf(v1.y) << 16);
        o.w = (unsigned)f2bf(v1.z) | ((unsigned)f2bf(v1.w) << 16);
        *reinterpret_cast<uint4*>(Abuf + (size_t)row * 512 + 256 + c8 * 8) = o;
    } else if (b < 6250 + 512) {
        int idx = (b - 6250) * 256 + tid;  // < 131072 exactly
        int n = idx >> 9, k = idx & 511;
        float v = (k < 256) ? W1l[(size_t)k * 256 + n] : W1r[(size_t)(k - 256) * 256 + n];
        B1t[(size_t)n * 512 + k] = f2bf(v);
    } else if (b < 6842) {
        int idx = (b - 6762) * 256 + tid;  // < 20480 exactly
        int n = idx >> 8, k = idx & 255;
        float v = (n < 40) ? W2l[(size_t)k * 40 + n] : W2r[(size_t)k * 40 + (n - 40)];
        B2t[(size_t)n * 256 + k] = f2bf(v);
    } else if (b < 7866) {
        int base = (b - 6842) * 256 + tid;
        for (int e = base; e < E; e += 1024 * 256)
            erank[e] = atomicAdd(&deg[dst[e]], 1);
    } else {
        int idx = (b - 7866) * 256 + tid;
        for (int i = idx; i < nQ4; i += 1024 * 256) Qdst[i] = Qsrc[i];
    }
}

__global__ __launch_bounds__(256) void scan1_kernel(const int* __restrict__ deg,
                                                    int* __restrict__ blocksums, int n) {
    __shared__ int s[256];
    int t = threadIdx.x;
    int i = blockIdx.x * 256 + t;
    s[t] = (i < n) ? deg[i] : 0;
    __syncthreads();
    for (int off = 128; off > 0; off >>= 1) {
        if (t < off) s[t] += s[t + off];
        __syncthreads();
    }
    if (t == 0) blocksums[blockIdx.x] = s[0];
}

__global__ __launch_bounds__(256) void scan2_kernel(const int* __restrict__ blocksums,
                                                    int* __restrict__ blockoff, int nb) {
    __shared__ int s[256];
    int t = threadIdx.x;
    s[t] = (t < nb) ? blocksums[t] : 0;
    __syncthreads();
    for (int off = 1; off < 256; off <<= 1) {
        int u = (t >= off) ? s[t - off] : 0;
        __syncthreads();
        s[t] += u;
        __syncthreads();
    }
    if (t < nb) blockoff[t] = (t == 0) ? 0 : s[t - 1];
}

__global__ __launch_bounds__(256) void scan3_kernel(const int* __restrict__ deg,
                                                    const int* __restrict__ blockoff,
                                                    int* __restrict__ rowptr,
                                                    float* __restrict__ inv_deg,
                                                    int n, int E) {
    __shared__ int s[256];
    int t = threadIdx.x;
    int i = blockIdx.x * 256 + t;
    int v = (i < n) ? deg[i] : 0;
    s[t] = v;
    __syncthreads();
    for (int off = 1; off < 256; off <<= 1) {
        int u = (t >= off) ? s[t - off] : 0;
        __syncthreads();
        s[t] += u;
        __syncthreads();
    }
    if (i < n) {
        rowptr[i] = s[t] - v + blockoff[blockIdx.x];
        inv_deg[i] = 1.0f / (float)(v > 1 ? v : 1);
    }
    if (blockIdx.x == 0 && t == 0) rowptr[n] = E;
}

// ---------------- fill CSR (atomic-free) ----------------
__global__ void fill_kernel(const int* __restrict__ src, const int* __restrict__ dst,
                            const int* __restrict__ erank, const int* __restrict__ rowptr,
                            int* __restrict__ csr, int E) {
    for (int e = blockIdx.x * blockDim.x + threadIdx.x; e < E; e += gridDim.x * blockDim.x)
        csr[rowptr[dst[e]] + erank[e]] = src[e];
}

// ---------------- mean aggregation (256-d): wave/node, halves over edges ----------------
__global__ __launch_bounds__(256) void aggregate1(
    const unsigned short* __restrict__ Abuf, const int* __restrict__ rowptr,
    const int* __restrict__ csr, const float* __restrict__ inv_deg,
    unsigned short* __restrict__ AbufOut, int N) {
    int node = blockIdx.x * 4 + (threadIdx.x >> 6);
    if (node >= N) return;
    int lane = threadIdx.x & 63;
    int half = lane >> 5;          // 0: even edges, 1: odd edges
    int dlane = lane & 31;         // 8-dim group
    const unsigned short* base = Abuf + 256 + (size_t)dlane * 8;
    float a0 = 0.f, a1 = 0.f, a2 = 0.f, a3 = 0.f;
    float a4 = 0.f, a5 = 0.f, a6 = 0.f, a7 = 0.f;
    int beg = rowptr[node], end = rowptr[node + 1];
    int k = beg + half;
    for (; k + 15 < end; k += 16) {     // 8 edges per half per iter
        uint4 v[8];
        #pragma unroll
        for (int u = 0; u < 8; ++u) {
            int j = csr[k + u * 2];
            v[u] = *reinterpret_cast<const uint4*>(base + (size_t)j * 512);
        }
        #pragma unroll
        for (int u = 0; u < 8; ++u) {
            a0 += bfbits_lo(v[u].x); a1 += bfbits_hi(v[u].x);
            a2 += bfbits_lo(v[u].y); a3 += bfbits_hi(v[u].y);
            a4 += bfbits_lo(v[u].z); a5 += bfbits_hi(v[u].z);
            a6 += bfbits_lo(v[u].w); a7 += bfbits_hi(v[u].w);
        }
    }
    for (; k + 7 < end; k += 8) {       // 4 edges per half
        uint4 v[4];
        #pragma unroll
        for (int u = 0; u < 4; ++u) {
            int j = csr[k + u * 2];
            v[u] = *reinterpret_cast<const uint4*>(base + (size_t)j * 512);
        }
        #pragma unroll
        for (int u = 0; u < 4; ++u) {
            a0 += bfbits_lo(v[u].x); a1 += bfbits_hi(v[u].x);
            a2 += bfbits_lo(v[u].y); a3 += bfbits_hi(v[u].y);
            a4 += bfbits_lo(v[u].z); a5 += bfbits_hi(v[u].z);
            a6 += bfbits_lo(v[u].w); a7 += bfbits_hi(v[u].w);
        }
    }
    for (; k < end; k += 2) {
        int j = csr[k];
        uint4 v = *reinterpret_cast<const uint4*>(base + (size_t)j * 512);
        a0 += bfbits_lo(v.x); a1 += bfbits_hi(v.x); a2 += bfbits_lo(v.y); a3 += bfbits_hi(v.y);
        a4 += bfbits_lo(v.z); a5 += bfbits_hi(v.z); a6 += bfbits_lo(v.w); a7 += bfbits_hi(v.w);
    }
    a0 += __shfl_xor(a0, 32, 64); a1 += __shfl_xor(a1, 32, 64);
    a2 += __shfl_xor(a2, 32, 64); a3 += __shfl_xor(a3, 32, 64);
    a4 += __shfl_xor(a4, 32, 64); a5 += __shfl_xor(a5, 32, 64);
    a6 += __shfl_xor(a6, 32, 64); a7 += __shfl_xor(a7, 32, 64);
    if (half == 0) {
        float s = inv_deg[node];
        uint4 w;
        w.x = (unsigned)f2bf(a0 * s) | ((unsigned)f2bf(a1 * s) << 16);
        w.y = (unsigned)f2bf(a2 * s) | ((unsigned)f2bf(a3 * s) << 16);
        w.z = (unsigned)f2bf(a4 * s) | ((unsigned)f2bf(a5 * s) << 16);
        w.w = (unsigned)f2bf(a6 * s) | ((unsigned)f2bf(a7 * s) << 16);
        *reinterpret_cast<uint4*>(AbufOut + (size_t)node * 512 + dlane * 8) = w;
    }
}

// ---------------- GEMM1 (MFMA): h = elu(Abuf @ B1t^T + b1) ----------------
// BM=64, BN=128, BK=64; grid (M_PAD/64, 2); LDS 48 KB -> 3 blk/CU.
__global__ __launch_bounds__(256) void gemm1_mfma(
    const unsigned short* __restrict__ Abuf,   // [M_PAD][512]
    const unsigned short* __restrict__ B1t,    // [256][512]
    const float* __restrict__ bias,            // [256]
    unsigned short* __restrict__ H,            // [M_PAD][256] bf16
    int M) {
    __shared__ unsigned short As[2][64 * 64];    // 16 KB
    __shared__ unsigned short Bs[2][128 * 64];   // 32 KB
    int tid = threadIdx.x;
    int row0 = blockIdx.x * 64;
    int bn = blockIdx.y;                 // 0..1
    int wid = tid >> 6, lane = tid & 63;
    int wm = (wid >> 1) * 32;            // 0 / 32
    int wn = (wid & 1) * 64;             // 0 / 64
    int fr = lane & 15, fq = lane >> 4;

    int lrow8 = lane >> 3;               // 0..7
    int gco = ((lane & 7) ^ lrow8) * 8;  // pre-swizzled global elem offset
    const unsigned short* gA0 = Abuf + (size_t)(row0 + wid * 16 + 0 + lrow8) * 512 + gco;
    const unsigned short* gA1 = Abuf + (size_t)(row0 + wid * 16 + 8 + lrow8) * 512 + gco;
    const unsigned short* gB0 = B1t + (size_t)(bn * 128 + wid * 32 + 0  + lrow8) * 512 + gco;
    const unsigned short* gB1 = B1t + (size_t)(bn * 128 + wid * 32 + 8  + lrow8) * 512 + gco;
    const unsigned short* gB2 = B1t + (size_t)(bn * 128 + wid * 32 + 16 + lrow8) * 512 + gco;
    const unsigned short* gB3 = B1t + (size_t)(bn * 128 + wid * 32 + 24 + lrow8) * 512 + gco;

    floatx4 acc[2][4] = {};

    #define STAGE(buf, k0)                                       \
        gload16(gA0 + (k0), &As[buf][(wid * 16 + 0) * 64]);      \
        gload16(gA1 + (k0), &As[buf][(wid * 16 + 8) * 64]);      \
        gload16(gB0 + (k0), &Bs[buf][(wid * 32 + 0) * 64]);      \
        gload16(gB1 + (k0), &Bs[buf][(wid * 32 + 8) * 64]);      \
        gload16(gB2 + (k0), &Bs[buf][(wid * 32 + 16) * 64]);     \
        gload16(gB3 + (k0), &Bs[buf][(wid * 32 + 24) * 64]);

    #define COMPUTE(buf)                                                                  \
        {                                                                                 \
            _Pragma("unroll")                                                             \
            for (int kc = 0; kc < 2; ++kc) {                                              \
                short8 af[2], bfr[4];                                                     \
                _Pragma("unroll")                                                         \
                for (int mi = 0; mi < 2; ++mi) {                                          \
                    int row = wm + mi * 16 + fr;                                          \
                    af[mi] = *reinterpret_cast<const short8*>(                            \
                        &As[buf][row * 64 + (((kc * 4 + fq) ^ (fr & 7)) * 8)]);           \
                }                                                                         \
                _Pragma("unroll")                                                         \
                for (int ni = 0; ni < 4; ++ni) {                                          \
                    int row = wn + ni * 16 + fr;                                          \
                    bfr[ni] = *reinterpret_cast<const short8*>(                           \
                        &Bs[buf][row * 64 + (((kc * 4 + fq) ^ (fr & 7)) * 8)]);           \
                }                                                                         \
                _Pragma("unroll")                                                         \
                for (int mi = 0; mi < 2; ++mi)                                            \
                    _Pragma("unroll")                                                     \
                    for (int ni = 0; ni < 4; ++ni)                                        \
                        acc[mi][ni] = __builtin_amdgcn_mfma_f32_16x16x32_bf16(            \
                            af[mi], bfr[ni], acc[mi][ni], 0, 0, 0);                       \
            }                                                                             \
        }

    STAGE(0, 0);
    __syncthreads();
    int cur = 0;
    #pragma unroll 1
    for (int t = 0; t < 7; ++t) {
        STAGE(cur ^ 1, (t + 1) * 64);
        COMPUTE(cur);
        __syncthreads();
        cur ^= 1;
    }
    COMPUTE(cur);
    #undef STAGE
    #undef COMPUTE

    #pragma unroll
    for (int ni = 0; ni < 4; ++ni) {
        int gcol = bn * 128 + wn + ni * 16 + fr;
        float bb = bias[gcol];
        #pragma unroll
        for (int mi = 0; mi < 2; ++mi) {
            #pragma unroll
            for (int r = 0; r < 4; ++r) {
                int grow = row0 + wm + mi * 16 + fq * 4 + r;   // < M_PAD
                float t = acc[mi][ni][r] + bb;
                t = (t > 0.f) ? t : expm1f(t);
                H[(size_t)grow * 256 + gcol] = f2bf(t);
            }
        }
    }
}

// ---------------- GEMM2 (MFMA): Plb = bf16(H @ W2l'), Pr = H @ W2r' + b2 ----------------
__global__ __launch_bounds__(256) void gemm2_mfma(
    const unsigned short* __restrict__ Hb,   // [M_PAD][256]
    const unsigned short* __restrict__ B2t,  // [80][256]
    const float* __restrict__ b2,
    unsigned short* __restrict__ Plb,        // [N][40] bf16
    float* __restrict__ Pr,                  // [N][40] fp32
    int M) {
    __shared__ unsigned short Bsm[80 * 256];   // 40 KB
    __shared__ unsigned short As[2][64 * 64];  // 16 KB
    int tid = threadIdx.x;
    int row0 = blockIdx.x * 64;
    int wid = tid >> 6, lane = tid & 63;
    int wm = wid * 16;
    int fr = lane & 15, fq = lane >> 4;

    for (int c = tid; c < 2560; c += 256) {
        int n = c >> 5, ci = c & 31;
        short8 v = *reinterpret_cast<const short8*>(B2t + (size_t)n * 256 + ci * 8);
        *reinterpret_cast<short8*>(&Bsm[n * 256 + ((ci ^ (n & 7)) * 8)]) = v;
    }

    int lrow8 = lane >> 3;
    int gco = ((lane & 7) ^ lrow8) * 8;
    const unsigned short* gA0 = Hb + (size_t)(row0 + wid * 16 + 0 + lrow8) * 256 + gco;
    const unsigned short* gA1 = Hb + (size_t)(row0 + wid * 16 + 8 + lrow8) * 256 + gco;

    floatx4 acc[5] = {};

    #define STAGE2(buf, k0)                                      \
        gload16(gA0 + (k0), &As[buf][(wid * 16 + 0) * 64]);      \
        gload16(gA1 + (k0), &As[buf][(wid * 16 + 8) * 64]);

    #define COMPUTE2(buf, k0)                                                             \
        {                                                                                 \
            _Pragma("unroll")                                                             \
            for (int kc = 0; kc < 2; ++kc) {                                              \
                short8 af;                                                                \
                {                                                                         \
                    int row = wm + fr;                                                    \
                    af = *reinterpret_cast<const short8*>(                                \
                        &As[buf][row * 64 + (((kc * 4 + fq) ^ (fr & 7)) * 8)]);           \
                }                                                                         \
                _Pragma("unroll")                                                         \
                for (int ni = 0; ni < 5; ++ni) {                                          \
                    int n = ni * 16 + fr;                                                 \
                    int c = ((k0) >> 3) + kc * 4 + fq;                                    \
                    short8 bfr = *reinterpret_cast<const short8*>(                        \
                        &Bsm[n * 256 + ((c ^ (n & 7)) * 8)]);                             \
                    acc[ni] = __builtin_amdgcn_mfma_f32_16x16x32_bf16(                    \
                        af, bfr, acc[ni], 0, 0, 0);                                       \
                }                                                                         \
            }                                                                             \
        }

    STAGE2(0, 0);
    __syncthreads();    // covers B-fill ds_writes and first A gload
    int cur = 0;
    #pragma unroll 1
    for (int t = 0; t < 3; ++t) {
        STAGE2(cur ^ 1, (t + 1) * 64);
        COMPUTE2(cur, t * 64);
        __syncthreads();
        cur ^= 1;
    }
    COMPUTE2(cur, 192);
    #undef STAGE2
    #undef COMPUTE2

    #pragma unroll
    for (int r = 0; r < 4; ++r) {
        int grow = row0 + wm + fq * 4 + r;
        if (grow < M) {
            #pragma unroll
            for (int ni = 0; ni < 5; ++ni) {
                int col = ni * 16 + fr;
                float v = acc[ni][r];
                if (col < 40)
                    Plb[(size_t)grow * 40 + col] = f2bf(v);
                else
                    Pr[(size_t)grow * 40 + (col - 40)] = v + b2[col - 40];
            }
        }
    }
}

// ---------------- final: out = mean_agg(Plb) + Pr ----------------
__global__ __launch_bounds__(256) void final_kernel(
    const unsigned short* __restrict__ Plb, const float* __restrict__ Pr,
    const int* __restrict__ rowptr, const int* __restrict__ csr,
    const float* __restrict__ inv_deg, float* __restrict__ out, int N) {
    int wv = blockIdx.x * 4 + (threadIdx.x >> 6);
    int node = wv * 2 + ((threadIdx.x >> 5) & 1);
    if (node >= N) return;
    int lane = threadIdx.x & 31;
    if (lane >= 20) return;
    float s0 = 0.f, s1 = 0.f;
    int beg = rowptr[node], end = rowptr[node + 1];
    int k = beg;
    for (; k + 4 <= end; k += 4) {
        unsigned v0 = *reinterpret_cast<const unsigned*>(Plb + (size_t)csr[k]     * 40 + lane * 2);
        unsigned v1 = *reinterpret_cast<const unsigned*>(Plb + (size_t)csr[k + 1] * 40 + lane * 2);
        unsigned v2 = *reinterpret_cast<const unsigned*>(Plb + (size_t)csr[k + 2] * 40 + lane * 2);
        unsigned v3 = *reinterpret_cast<const unsigned*>(Plb + (size_t)csr[k + 3] * 40 + lane * 2);
        s0 += bfbits_lo(v0) + bfbits_lo(v1) + bfbits_lo(v2) + bfbits_lo(v3);
        s1 += bfbits_hi(v0) + bfbits_hi(v1) + bfbits_hi(v2) + bfbits_hi(v3);
    }
    for (; k < end; ++k) {
        unsigned v = *reinterpret_cast<const unsigned*>(Plb + (size_t)csr[k] * 40 + lane * 2);
        s0 += bfbits_lo(v);
        s1 += bfbits_hi(v);
    }
    float inv = inv_deg[node];
    float2 pr = *reinterpret_cast<const float2*>(Pr + (size_t)node * 40 + lane * 2);
    float2 o;
    o.x = s0 * inv + pr.x;
    o.y = s1 * inv + pr.y;
    *reinterpret_cast<float2*>(out + (size_t)node * 40 + lane * 2) = o;
}

// ---------------- launcher ----------------

extern "C" void kernel_launch(void* const* d_in, const int* in_sizes, int n_in,
                              void* d_out, int out_size, void* d_ws, size_t ws_size,
                              hipStream_t stream) {
    const float* x   = (const float*)d_in[0];
    const int*   ei  = (const int*)d_in[1];
    const float* W1l = (const float*)d_in[2];
    const float* b1  = (const float*)d_in[3];
    const float* W1r = (const float*)d_in[4];
    const float* W2l = (const float*)d_in[5];
    const float* b2  = (const float*)d_in[6];
    const float* W2r = (const float*)d_in[7];
    const float* Q   = (const float*)d_in[8];
    const int E = in_sizes[1] / 2;
    const int N = N_NODES;
    const int* src = ei;
    const int* dst = ei + E;
    const int NB = (N + 255) / 256;

    unsigned short* Abuf = (unsigned short*)d_ws;            // [M_PAD][512] bf16
    unsigned short* h    = Abuf + (size_t)M_PAD * 512;       // [M_PAD][256] bf16
    unsigned short* B1t  = h + (size_t)M_PAD * 256;          // [256][512]
    unsigned short* B2t  = B1t + 256 * 512;                  // [80][256]
    unsigned short* Plb  = B2t + 80 * 256;                   // [N][40] bf16
    float* Pr      = (float*)(Plb + (size_t)N * 40 + 32);    // [N][40] fp32
    float* inv_deg = Pr + (size_t)N * 40;                    // N
    int*   deg     = (int*)(inv_deg + N);                    // N
    int*   rowptr  = deg + N;                                // N+1
    int*   blocksums = rowptr + N + 1;                       // NB
    int*   blockoff  = blocksums + NB;                       // NB
    int*   csr     = blockoff + NB;                          // E
    int*   erank   = csr + E;                                // E

    float* out = (float*)d_out;

    const int nQ4 = in_sizes[8] / 4;             // 4,000,000 float4

    hipMemsetAsync(deg, 0, sizeof(int) * (size_t)N, stream);
    prep_count<<<6842 + 1024 + 1024, 256, 0, stream>>>(
        x, W1l, W1r, W2l, W2r, Abuf, B1t, B2t, dst, deg, erank, E,
        (const float4*)Q, (float4*)(out + (size_t)N * 40), nQ4);
    scan1_kernel<<<NB, 256, 0, stream>>>(deg, blocksums, N);
    scan2_kernel<<<1, 256, 0, stream>>>(blocksums, blockoff, NB);
    scan3_kernel<<<NB, 256, 0, stream>>>(deg, blockoff, rowptr, inv_deg, N, E);

    fill_kernel<<<1024, 256, 0, stream>>>(src, dst, erank, rowptr, csr, E);

    aggregate1<<<(N + 3) / 4, 256, 0, stream>>>(Abuf, rowptr, csr, inv_deg, Abuf, N);

    gemm1_mfma<<<dim3(M_PAD / 64, 2), 256, 0, stream>>>(Abuf, B1t, b1, h, N);
    gemm2_mfma<<<M_PAD / 64, 256, 0, stream>>>(h, B2t, b2, Plb, Pr, N);
    final_kernel<<<(N + 7) / 8, 256, 0, stream>>>(Plb, Pr, rowptr, csr, inv_deg, out, N);
}